// Round 8
// baseline (643.994 us; speedup 1.0000x reference)
//
#include <hip/hip_runtime.h>
#include <cmath>

#define N_IMG   8
#define PRE     1000
#define K_SEL   5000
#define NBIN    4096
#define TIE_CAP 4096
#define IMG_F   1344.0f
#define S_NEGINF 0x007FFFFFu
#define TILES   79             // ceil(5000/64)

__constant__ int c_W[5]   = {336,168,84,42,21};
__constant__ int c_HW[5]  = {112896,28224,7056,1764,441};
__constant__ int c_OFF[5] = {0,338688,423360,444528,449820};

__device__ __forceinline__ unsigned f2s(float f){
  unsigned u = __float_as_uint(f);
  return (u & 0x80000000u) ? ~u : (u | 0x80000000u);
}
__device__ __forceinline__ float s2f(unsigned s){
  unsigned u = (s & 0x80000000u) ? (s & 0x7FFFFFFFu) : ~s;
  return __uint_as_float(u);
}
__device__ __forceinline__ const float* sel5(int l, const float* p0,const float* p1,const float* p2,const float* p3,const float* p4){
  switch(l){case 0:return p0;case 1:return p1;case 2:return p2;case 3:return p3;default:return p4;}
}

struct BoxV { float x1,y1,x2,y2; bool valid; };

// Bit-faithful torchvision BoxCoder.decode + clip + min-size validity.
__device__ BoxV decode_box(int lvl, int t, int n, const float* dl, const float* anchors){
  int HW = c_HW[lvl], W = c_W[lvl];
  int a = t % 3, pos = t / 3;          // t = (h*W+w)*3 + a
  int h = pos / W, w = pos - h*W;
  int g = c_OFF[lvl] + t;
  const float* an = anchors + (size_t)4*(size_t)g;
  float a0=an[0], a1=an[1], a2=an[2], a3=an[3];
  float aw = __fsub_rn(a2,a0), ah = __fsub_rn(a3,a1);
  float acx = __fadd_rn(a0, __fmul_rn(0.5f,aw));
  float acy = __fadd_rn(a1, __fmul_rn(0.5f,ah));
  const float* dp = dl + ((size_t)n*12 + (size_t)a*4)*(size_t)HW + (size_t)h*W + (size_t)w;
  float dx = dp[0], dy = dp[HW], dwv = dp[2*(size_t)HW], dhv = dp[3*(size_t)HW];
  const float CLAMP = (float)4.135166556742356;  // log(1000/16)
  dwv = fminf(dwv, CLAMP); dhv = fminf(dhv, CLAMP);
  float pcx = __fadd_rn(__fmul_rn(dx,aw), acx);
  float pcy = __fadd_rn(__fmul_rn(dy,ah), acy);
  float pw = __fmul_rn((float)::exp((double)dwv), aw);
  float ph = __fmul_rn((float)::exp((double)dhv), ah);
  float hx = __fmul_rn(0.5f,pw), hy = __fmul_rn(0.5f,ph);
  BoxV b;
  b.x1 = fminf(fmaxf(__fsub_rn(pcx,hx),0.0f),IMG_F);
  b.y1 = fminf(fmaxf(__fsub_rn(pcy,hy),0.0f),IMG_F);
  b.x2 = fminf(fmaxf(__fadd_rn(pcx,hx),0.0f),IMG_F);
  b.y2 = fminf(fmaxf(__fadd_rn(pcy,hy),0.0f),IMG_F);
  b.valid = (__fsub_rn(b.x2,b.x1) >= 1e-3f) && (__fsub_rn(b.y2,b.y1) >= 1e-3f);
  return b;
}

// key = (~s_eff)<<22 | lvl<<19 | t : ascending sort == (score desc, level asc, idx asc)
__device__ unsigned long long make_key(unsigned s, int lvl, int t, int n, const float* dl, const float* anchors){
  BoxV b = decode_box(lvl,t,n,dl,anchors);
  unsigned se = b.valid ? s : S_NEGINF;     // invalid -> skey = -inf
  return ((unsigned long long)(~se) << 22) | ((unsigned long long)(unsigned)lvl << 19) | (unsigned long long)(unsigned)t;
}

// ---------------- K1: per-(image,level) 12-bit score histogram ----------------
__global__ __launch_bounds__(256) void k_hist(const float* o0,const float* o1,const float* o2,const float* o3,const float* o4,
                                              unsigned* hist){
  int grp = blockIdx.y; int n = grp/5, lvl = grp - n*5;
  const float* ob = sel5(lvl,o0,o1,o2,o3,o4);
  int HW = c_HW[lvl], M = 3*HW;
  ob += (size_t)n*(size_t)M;
  __shared__ unsigned lh[NBIN];
  for (int b = threadIdx.x; b < NBIN; b += 256) lh[b] = 0;
  __syncthreads();
  int stride = gridDim.x*256;
  for (int i = blockIdx.x*256 + threadIdx.x; i < M; i += stride){
    unsigned s = f2s(ob[i]);
    atomicAdd(&lh[s >> 20], 1u);
  }
  __syncthreads();
  unsigned* gh = hist + (size_t)grp*NBIN;
  for (int b = threadIdx.x; b < NBIN; b += 256){ unsigned v = lh[b]; if (v) atomicAdd(&gh[b], v); }
}

// ---------------- K2: find bin containing the 1000th-largest score ----------------
__global__ __launch_bounds__(256) void k_scan(const unsigned* hist, unsigned* thi){
  int grp = blockIdx.x;
  const unsigned* gh = hist + (size_t)grp*NBIN;
  __shared__ unsigned part[256];
  unsigned ssum = 0;
  int base = threadIdx.x*16;
  for (int b = base; b < base+16; ++b) ssum += gh[b];
  part[threadIdx.x] = ssum;
  __syncthreads();
  if (threadIdx.x == 0){
    int k = PRE;
    int c = 255;
    while ((int)part[c] < k){ k -= (int)part[c]; --c; }
    int b = c*16 + 15;
    while ((int)gh[b] < k){ k -= (int)gh[b]; --b; }
    thi[grp] = (unsigned)b;
  }
}

// ---------------- K3: compact >bin elements (decode+key), collect ==bin candidates ----------------
__global__ __launch_bounds__(256) void k_compact(const float* o0,const float* o1,const float* o2,const float* o3,const float* o4,
                                                 const float* d0,const float* d1,const float* d2,const float* d3,const float* d4,
                                                 const float* anchors, const unsigned* thi,
                                                 unsigned* cnt_gt, unsigned* cnt_eq,
                                                 unsigned long long* cand, unsigned long long* keys){
  int grp = blockIdx.y; int n = grp/5, lvl = grp - n*5;
  const float* ob = sel5(lvl,o0,o1,o2,o3,o4);
  const float* dl = sel5(lvl,d0,d1,d2,d3,d4);
  int HW = c_HW[lvl], M = 3*HW;
  ob += (size_t)n*(size_t)M;
  unsigned T = thi[grp];
  unsigned long long* kout = keys + (size_t)n*K_SEL + (size_t)lvl*PRE;
  int stride = gridDim.x*256;
  for (int i = blockIdx.x*256 + threadIdx.x; i < M; i += stride){
    unsigned s = f2s(ob[i]);
    unsigned sh = s >> 20;
    if (sh > T){
      unsigned pos = atomicAdd(&cnt_gt[grp], 1u);
      int a = i / HW; int rem = i - a*HW; int t = rem*3 + a;
      kout[pos] = make_key(s, lvl, t, n, dl, anchors);
    } else if (sh == T){
      unsigned e = atomicAdd(&cnt_eq[grp], 1u);
      if (e < TIE_CAP){
        int a = i / HW; int rem = i - a*HW; int t = rem*3 + a;
        cand[(size_t)grp*TIE_CAP + e] = ((unsigned long long)(~s) << 19) | (unsigned long long)(unsigned)t;
      }
    }
  }
}

template<int SZ>
__device__ void bitonic(unsigned long long* sk){
  for (int k = 2; k <= SZ; k <<= 1){
    for (int j = k >> 1; j > 0; j >>= 1){
      for (int i = threadIdx.x; i < SZ; i += blockDim.x){
        int ix = i ^ j;
        if (ix > i){
          unsigned long long va = sk[i], vb = sk[ix];
          if ((va > vb) == ((i & k) == 0)){ sk[i] = vb; sk[ix] = va; }
        }
      }
      __syncthreads();
    }
  }
}

// runtime-sized bitonic (SZ uniform across block, power of 2)
__device__ void bitonic_rt(unsigned long long* sk, int SZ){
  for (int k = 2; k <= SZ; k <<= 1){
    for (int j = k >> 1; j > 0; j >>= 1){
      for (int i = threadIdx.x; i < SZ; i += blockDim.x){
        int ix = i ^ j;
        if (ix > i){
          unsigned long long va = sk[i], vb = sk[ix];
          if ((va > vb) == ((i & k) == 0)){ sk[i] = vb; sk[ix] = va; }
        }
      }
      __syncthreads();
    }
  }
}

// ---------------- K4: exact boundary selection within the threshold bin ----------------
__global__ __launch_bounds__(256) void k_tiesel(const float* d0,const float* d1,const float* d2,const float* d3,const float* d4,
                                                const float* anchors,
                                                const unsigned* cnt_gt, const unsigned* cnt_eq,
                                                const unsigned long long* cand, unsigned long long* keys){
  int grp = blockIdx.x; int n = grp/5, lvl = grp - n*5;
  __shared__ unsigned long long sk[TIE_CAP];
  int ne = min((int)cnt_eq[grp], TIE_CAP);
  int SZ = 64; while (SZ < ne) SZ <<= 1;    // runtime pow2 >= ne (uniform)
  for (int i = threadIdx.x; i < SZ; i += 256)
    sk[i] = (i < ne) ? cand[(size_t)grp*TIE_CAP + i] : ~0ULL;
  __syncthreads();
  bitonic_rt(sk, SZ);                // ascending: (score desc, idx asc)
  int cg = (int)cnt_gt[grp];
  int need = PRE - cg;
  const float* dl = sel5(lvl,d0,d1,d2,d3,d4);
  unsigned long long* kout = keys + (size_t)n*K_SEL + (size_t)lvl*PRE + cg;
  for (int j = threadIdx.x; j < need; j += 256){
    if (j < ne){
      unsigned long long ck = sk[j];
      unsigned t = (unsigned)(ck & 0x7FFFFu);
      unsigned s = ~((unsigned)(ck >> 19));
      kout[j] = make_key(s, lvl, (int)t, n, dl, anchors);
    } else {
      kout[j] = ((unsigned long long)(~S_NEGINF) << 22); // pathological overflow: harmless invalid
    }
  }
}

// ---------------- K5a: sort each (image,level) run; decode level-space arrays ----------------
__global__ __launch_bounds__(256) void k_sortlvl(unsigned long long* keys,
                                                 const float* d0,const float* d1,const float* d2,const float* d3,const float* d4,
                                                 const float* anchors,
                                                 float4* lbox, float4* lobox, float* loarea, float* lskey){
  int grp = blockIdx.x; int n = grp/5, lvl = grp - n*5;
  __shared__ unsigned long long sk[1024];
  unsigned long long* kp = keys + (size_t)n*K_SEL + (size_t)lvl*PRE;
  for (int i = threadIdx.x; i < 1024; i += 256)
    sk[i] = (i < PRE) ? kp[i] : ~0ULL;
  __syncthreads();
  bitonic<1024>(sk);
  const float* dl = sel5(lvl,d0,d1,d2,d3,d4);
  for (int i = threadIdx.x; i < PRE; i += 256){
    unsigned long long key = sk[i];
    kp[i] = key;                          // sorted run back to global (k_rank reads it)
    int t = (int)(key & 0x7FFFFu);
    unsigned se = ~((unsigned)(key >> 22));
    BoxV b = decode_box(lvl, t, n, dl, anchors);
    size_t o = (size_t)grp*PRE + i;
    lbox[o] = make_float4(b.x1,b.y1,b.x2,b.y2);
    lskey[o] = s2f(se);                   // -inf if invalid
    float off = (float)lvl * 1345.0f;     // (IMG+1) batched-NMS offset
    float ox1 = __fadd_rn(b.x1, off), oy1 = __fadd_rn(b.y1, off);
    float ox2 = __fadd_rn(b.x2, off), oy2 = __fadd_rn(b.y2, off);
    lobox[o] = make_float4(ox1,oy1,ox2,oy2);
    loarea[o] = __fmul_rn(__fsub_rn(ox2,ox1), __fsub_rn(oy2,oy1));
  }
}

// ---------------- K5b: global rank of each level element (keys globally unique) ----------------
// rankinfo[rank] = p | (lvl<<10) | (valid<<13)
__global__ __launch_bounds__(256) void k_rank(const unsigned long long* keys, unsigned* rankinfo){
  int grp = blockIdx.x; int n = grp/5, lvl = grp - n*5;
  __shared__ unsigned long long sl[K_SEL];
  for (int i = threadIdx.x; i < K_SEL; i += 256) sl[i] = keys[(size_t)n*K_SEL + i];
  __syncthreads();
  for (int j = threadIdx.x; j < PRE; j += 256){
    unsigned long long k = sl[lvl*PRE + j];
    int rank = j;
    #pragma unroll
    for (int m = 0; m < 5; ++m){
      if (m == lvl) continue;
      const unsigned long long* s = sl + m*PRE;
      int lo = 0, hi = PRE;
      while (lo < hi){ int mid = (lo+hi) >> 1; if (s[mid] < k) lo = mid+1; else hi = mid; }
      rank += lo;
    }
    unsigned se = ~((unsigned)(k >> 22));
    unsigned info = (unsigned)j | ((unsigned)lvl << 10) | ((se != S_NEGINF) ? (1u<<13) : 0u);
    rankinfo[(size_t)n*K_SEL + rank] = info;   // exact permutation of [0,5000)
  }
}

// ---------------- K6a: per-level suppression bit-matrix, ballot-transposed ----------------
// One wave per (group, 64-wide j-block). Lane holds its own j-box in registers;
// the p-loop reads only the p-box (wave-uniform broadcast LDS reads, independent
// across iterations -> pipelined). __ballot assembles 64 bits; lanes 0/32 store.
__global__ __launch_bounds__(64) void k_ioumat_lvl(const float4* lobox, const float* loarea, unsigned* lmat){
  int grp = blockIdx.y;                  // n*5 + L
  int wblk = blockIdx.x;                 // j-block: j = wblk*64 + lane
  int lane = threadIdx.x;
  __shared__ float sx1[PRE], sy1[PRE], sx2[PRE], sy2[PRE], sar[PRE];
  for (int i = lane; i < PRE; i += 64){
    float4 bb = lobox[(size_t)grp*PRE + i];
    sx1[i]=bb.x; sy1[i]=bb.y; sx2[i]=bb.z; sy2[i]=bb.w;
    sar[i]=loarea[(size_t)grp*PRE + i];
  }
  __syncthreads();
  int j = wblk*64 + lane;
  float jx1=0.f,jy1=0.f,jx2=0.f,jy2=0.f,ja=0.f;
  if (j < PRE){
    float4 bb = lobox[(size_t)grp*PRE + j];
    jx1=bb.x; jy1=bb.y; jx2=bb.z; jy2=bb.w; ja=loarea[(size_t)grp*PRE + j];
  }
  unsigned* mg = lmat + (size_t)grp*PRE*32 + (size_t)wblk*2;
  // rows p >= wblk*64+63 have no j>p in this block -> zero
  int pmax = min(PRE, wblk*64 + 63);
  for (int p = 0; p < pmax; ++p){
    float bx1=sx1[p], by1=sy1[p], bx2=sx2[p], by2=sy2[p], ba=sar[p];  // broadcast reads
    float ltx = fmaxf(bx1, jx1), lty = fmaxf(by1, jy1);
    float rbx = fminf(bx2, jx2), rby = fminf(by2, jy2);
    float ww = fmaxf(__fsub_rn(rbx,ltx), 0.0f);
    float hh = fmaxf(__fsub_rn(rby,lty), 0.0f);
    float inter = __fmul_rn(ww,hh);
    float uni = __fsub_rn(__fadd_rn(ba, ja), inter);
    bool hit = (__fdiv_rn(inter,uni) > 0.7f) && (j > p) && (j < PRE);
    unsigned long long bal = __ballot(hit);
    if ((lane & 31) == 0)
      mg[(size_t)p*32 + (lane>>5)] = (lane == 0) ? (unsigned)bal : (unsigned)(bal >> 32);
  }
  for (int p = pmax + (lane>>1); p < PRE; p += 32)   // 32 zero-rows per iteration
    mg[(size_t)p*32 + (lane&1)] = 0u;
}

// ---------------- K6b: tile-parallel greedy scan, one wave per image ----------------
__global__ __launch_bounds__(64) void k_scan_nms4(const unsigned* rankinfo, const unsigned* lmat,
                                                  const float4* lbox, const float* lskey, float* out){
  __shared__ unsigned lrows[64][36];     // row stride 36 words: 16B-aligned, bank-rotated
  int n = blockIdx.x; int lane = threadIdx.x;
  int n5 = n*5;
  const unsigned* rin = rankinfo + (size_t)n*K_SEL;
  float* outn = out + (size_t)n*PRE*5;
  unsigned sup0=0u,sup1=0u,sup2=0u,sup3=0u,sup4=0u;
  int kept_total = 0;
  uint4 La,Lb,Lc,Ld,Le,Lf,Lg,Lh;         // staging regs: 8 x 16B = one tile's 64x128B rows
  float4 boxP; float scP = 0.f;
  unsigned infoC, infoN;
  int rsub = lane >> 3;                  // row-within-group
  int csub = (lane & 7) << 2;            // word offset of my 16B chunk

#define SLOAD(INFO) { \
    unsigned L_ = ((INFO)>>10)&7u; unsigned p_ = (INFO) & 1023u; \
    unsigned rowu_ = (((unsigned)n5 + L_)*PRE + p_) << 5; \
    unsigned rb_; \
    rb_ = __shfl(rowu_,  0 + rsub); La = *(const uint4*)(lmat + rb_ + csub); \
    rb_ = __shfl(rowu_,  8 + rsub); Lb = *(const uint4*)(lmat + rb_ + csub); \
    rb_ = __shfl(rowu_, 16 + rsub); Lc = *(const uint4*)(lmat + rb_ + csub); \
    rb_ = __shfl(rowu_, 24 + rsub); Ld = *(const uint4*)(lmat + rb_ + csub); \
    rb_ = __shfl(rowu_, 32 + rsub); Le = *(const uint4*)(lmat + rb_ + csub); \
    rb_ = __shfl(rowu_, 40 + rsub); Lf = *(const uint4*)(lmat + rb_ + csub); \
    rb_ = __shfl(rowu_, 48 + rsub); Lg = *(const uint4*)(lmat + rb_ + csub); \
    rb_ = __shfl(rowu_, 56 + rsub); Lh = *(const uint4*)(lmat + rb_ + csub); \
    size_t bi_ = (size_t)((unsigned)n5 + L_)*PRE + p_; \
    boxP = lbox[bi_]; scP = lskey[bi_]; }

#define SWRITE() { \
    *(uint4*)&lrows[ 0 + rsub][csub] = La; *(uint4*)&lrows[ 8 + rsub][csub] = Lb; \
    *(uint4*)&lrows[16 + rsub][csub] = Lc; *(uint4*)&lrows[24 + rsub][csub] = Ld; \
    *(uint4*)&lrows[32 + rsub][csub] = Le; *(uint4*)&lrows[40 + rsub][csub] = Lf; \
    *(uint4*)&lrows[48 + rsub][csub] = Lg; *(uint4*)&lrows[56 + rsub][csub] = Lh; }

#define TPROC(INFO, BOX, SC, baseexpr) { \
    int base_ = (baseexpr); \
    unsigned L_ = ((INFO)>>10)&7u; unsigned p_ = (INFO) & 1023u; \
    bool ok_ = ((((INFO)>>13)&1u) != 0u) && (base_ + lane < K_SEL); \
    int idxw_ = (int)(p_ >> 5); unsigned pb_ = p_ & 31u; \
    unsigned t0_=__shfl(sup0,idxw_), t1_=__shfl(sup1,idxw_), t2_=__shfl(sup2,idxw_), t3_=__shfl(sup3,idxw_), t4_=__shfl(sup4,idxw_); \
    unsigned sw_ = (L_==0u)?t0_:(L_==1u)?t1_:(L_==2u)?t2_:(L_==3u)?t3_:t4_; \
    bool pre_ = (!ok_) || (((sw_ >> pb_) & 1u) != 0u); \
    unsigned long long preM_ = __ballot(pre_); \
    unsigned cmlo_ = 0u, cmhi_ = 0u; \
    _Pragma("unroll") \
    for (int m_=0; m_<64; ++m_){ \
      unsigned infoM_ = __builtin_amdgcn_readlane((INFO), m_); \
      unsigned Lm_ = (infoM_>>10)&7u; \
      unsigned w_ = lrows[m_][idxw_]; \
      unsigned bit_ = ((w_ >> pb_) & 1u) & ((L_ == Lm_) ? 1u : 0u); \
      if (m_ < 32) cmlo_ |= bit_ << m_; else cmhi_ |= bit_ << (m_-32); \
    } \
    unsigned long long keptM_ = 0ull; \
    _Pragma("unroll") \
    for (int m_=0; m_<64; ++m_){ \
      unsigned long long cml_ = ((unsigned long long)__builtin_amdgcn_readlane(cmhi_, m_) << 32) \
                              |  (unsigned long long)__builtin_amdgcn_readlane(cmlo_, m_); \
      bool keep_ = (((preM_>>m_)&1ull) == 0ull) && ((cml_ & keptM_) == 0ull); \
      if (keep_) keptM_ |= (1ull<<m_); \
    } \
    unsigned myw_ = (unsigned)(lane & 31); \
    _Pragma("unroll") \
    for (int m_=0; m_<64; ++m_){ \
      if ((keptM_>>m_)&1ull){ \
        unsigned infoM_ = __builtin_amdgcn_readlane((INFO), m_); \
        unsigned Lm_ = (infoM_>>10)&7u; \
        unsigned rw_ = lrows[m_][myw_]; \
        switch(Lm_){ case 0u: sup0|=rw_; break; case 1u: sup1|=rw_; break; \
                     case 2u: sup2|=rw_; break; case 3u: sup3|=rw_; break; default: sup4|=rw_; } \
      } \
    } \
    int pos_ = kept_total + (int)__popcll(keptM_ & ((1ull<<lane)-1ull)); \
    if (((keptM_>>lane)&1ull) && pos_ < PRE){ \
      float* orow_ = outn + (size_t)pos_*5; \
      orow_[0]=(BOX).x; orow_[1]=(BOX).y; orow_[2]=(BOX).z; orow_[3]=(BOX).w; orow_[4]=(SC); \
    } \
    kept_total += (int)__popcll(keptM_); \
  }

  infoC = rin[lane];
  SLOAD(infoC);                          // tile 0 rows -> regs, box -> boxP
  SWRITE();                              // tile 0 rows -> LDS (waits its own loads once)
  float4 boxC = boxP; float scC = scP;
  infoN = rin[64 + lane];

  for (int t = 0; t < TILES; ++t){
    if (t+1 < TILES) SLOAD(infoN);       // issue next tile's loads (rows + box)
    asm volatile("s_waitcnt lgkmcnt(0)" ::: "memory");   // lrows writes visible
    TPROC(infoC, boxC, scC, t*64);
    if (kept_total >= PRE) break;
    if (t+1 < TILES){
      SWRITE();                          // waits next tile's loads (covered by TPROC)
      boxC = boxP; scC = scP;
      infoC = infoN;
      if (t+2 < TILES){
        int nx = (t+2)*64 + lane; if (nx > K_SEL-1) nx = K_SEL-1;
        infoN = rin[nx];
      }
    }
  }
#undef SLOAD
#undef SWRITE
#undef TPROC
}

// ---------------- fallback path (ws too small): round-3 kernels ----------------
__global__ __launch_bounds__(256) void k_sortimg(const unsigned long long* keys,
                                                 const float* d0,const float* d1,const float* d2,const float* d3,const float* d4,
                                                 const float* anchors,
                                                 float4* sbox, float* sskey, int* slvl){
  int n = blockIdx.x;
  __shared__ unsigned long long sk[8192];
  for (int i = threadIdx.x; i < 8192; i += 256)
    sk[i] = (i < K_SEL) ? keys[(size_t)n*K_SEL + i] : ~0ULL;
  __syncthreads();
  bitonic<8192>(sk);
  for (int r = threadIdx.x; r < K_SEL; r += 256){
    unsigned long long key = sk[r];
    int t = (int)(key & 0x7FFFFu);
    int lvl = (int)((key >> 19) & 7u);
    unsigned se = ~((unsigned)(key >> 22));
    const float* dl = sel5(lvl,d0,d1,d2,d3,d4);
    BoxV b = decode_box(lvl, t, n, dl, anchors);
    sbox[(size_t)n*K_SEL + r] = make_float4(b.x1,b.y1,b.x2,b.y2);
    sskey[(size_t)n*K_SEL + r] = s2f(se);
    slvl[(size_t)n*K_SEL + r] = lvl;
  }
}

__global__ __launch_bounds__(256) void k_nms(const float4* sbox, const float* sskey, const int* slvl, float* out){
  int n = blockIdx.x, tid = threadIdx.x;
  __shared__ float kx1[PRE], ky1[PRE], kx2[PRE], ky2[PRE], kar[PRE];
  __shared__ int klv[PRE];
  __shared__ int nv_s, flag_s;
  for (int i = tid; i < PRE*5; i += 256) out[(size_t)n*PRE*5 + i] = 0.0f;
  if (tid == 0){ nv_s = 0; flag_s = 0; }
  __syncthreads();
  int c = 0;
  for (int i = tid; i < K_SEL; i += 256)
    if (sskey[(size_t)n*K_SEL + i] != -INFINITY) ++c;
  atomicAdd(&nv_s, c);
  __syncthreads();
  int nvalid = nv_s;
  int kept = 0;
  for (int i = 0; i < nvalid; ++i){
    float4 b = sbox[(size_t)n*K_SEL + i];
    int lv = slvl[(size_t)n*K_SEL + i];
    float off = (float)lv * 1345.0f;
    float ox1 = __fadd_rn(b.x, off), oy1 = __fadd_rn(b.y, off);
    float ox2 = __fadd_rn(b.z, off), oy2 = __fadd_rn(b.w, off);
    float area = __fmul_rn(__fsub_rn(ox2,ox1), __fsub_rn(oy2,oy1));
    bool hit = false;
    for (int j = tid; j < kept; j += 256){
      if (klv[j] == lv){
        float ltx = fmaxf(kx1[j], ox1), lty = fmaxf(ky1[j], oy1);
        float rbx = fminf(kx2[j], ox2), rby = fminf(ky2[j], oy2);
        float w = fmaxf(__fsub_rn(rbx,ltx), 0.0f);
        float h = fmaxf(__fsub_rn(rby,lty), 0.0f);
        float inter = __fmul_rn(w,h);
        float uni = __fsub_rn(__fadd_rn(kar[j], area), inter);
        if (__fdiv_rn(inter,uni) > 0.7f) hit = true;
      }
    }
    if (hit) flag_s = 1;
    __syncthreads();
    int sup = flag_s;
    __syncthreads();
    if (!sup){
      if (tid == 0){
        kx1[kept]=ox1; ky1[kept]=oy1; kx2[kept]=ox2; ky2[kept]=oy2; kar[kept]=area; klv[kept]=lv;
        float* orow = out + (size_t)n*PRE*5 + (size_t)kept*5;
        orow[0]=b.x; orow[1]=b.y; orow[2]=b.z; orow[3]=b.w;
        orow[4]=sskey[(size_t)n*K_SEL + i];
      }
      ++kept;
    }
    if (tid == 0) flag_s = 0;
    __syncthreads();
    if (kept == PRE) break;
  }
}

extern "C" void kernel_launch(void* const* d_in, const int* in_sizes, int n_in,
                              void* d_out, int out_size, void* d_ws, size_t ws_size,
                              hipStream_t stream) {
  bool interleaved = (in_sizes[1] == 4*in_sizes[0]);
  const float* obj[5]; const float* dlt[5];
  for (int i = 0; i < 5; ++i){
    if (interleaved){ obj[i] = (const float*)d_in[2*i]; dlt[i] = (const float*)d_in[2*i+1]; }
    else            { obj[i] = (const float*)d_in[i];   dlt[i] = (const float*)d_in[5+i]; }
  }
  const float* anchors = (const float*)d_in[10];

  char* ws = (char*)d_ws;
  unsigned* hist            = (unsigned*)(ws);                     // 655360
  unsigned* cnt_gt          = (unsigned*)(ws + 655360);            // 160
  unsigned* cnt_eq          = (unsigned*)(ws + 655520);            // 160
  unsigned* thi             = (unsigned*)(ws + 655680);            // 160 -> counters end 655840
  unsigned long long* cand  = (unsigned long long*)(ws + 655840);  // 1310720 -> 1966560
  unsigned long long* keys  = (unsigned long long*)(ws + 1966560); // 320000 -> 2286560
  float4* lbox              = (float4*)(ws + 2286560);             // 640000 -> 2926560
  float4* lobox             = (float4*)(ws + 2926560);             // 640000 -> 3566560
  float* loarea             = (float*)(ws + 3566560);              // 160000 -> 3726560
  float* lskey              = (float*)(ws + 3726560);              // 160000 -> 3886560
  unsigned* rankinfo        = (unsigned*)(ws + 3886560);           // 160000 -> 4046560
  unsigned* lmat            = (unsigned*)(ws + 4046560);           // 5120000 -> 9166560
  float4* sbox              = (float4*)(ws + 9166560);             // fallback: 640000 -> 9806560
  float* sskey              = (float*)(ws + 9806560);              // 160000 -> 9966560
  int* slvl                 = (int*)(ws + 9966560);                // 160000 -> 10126560
  const size_t NEED = 10126560;

  hipMemsetAsync(ws, 0, 655840, stream);   // hist + counters

  dim3 gScan(8, 40);
  k_hist<<<gScan, 256, 0, stream>>>(obj[0],obj[1],obj[2],obj[3],obj[4], hist);
  k_scan<<<40, 256, 0, stream>>>(hist, thi);
  k_compact<<<gScan, 256, 0, stream>>>(obj[0],obj[1],obj[2],obj[3],obj[4],
                                       dlt[0],dlt[1],dlt[2],dlt[3],dlt[4],
                                       anchors, thi, cnt_gt, cnt_eq, cand, keys);
  k_tiesel<<<40, 256, 0, stream>>>(dlt[0],dlt[1],dlt[2],dlt[3],dlt[4], anchors,
                                   cnt_gt, cnt_eq, cand, keys);
  if (ws_size >= NEED){
    k_sortlvl<<<40, 256, 0, stream>>>(keys, dlt[0],dlt[1],dlt[2],dlt[3],dlt[4], anchors,
                                      lbox, lobox, loarea, lskey);
    k_rank<<<40, 256, 0, stream>>>(keys, rankinfo);
    k_ioumat_lvl<<<dim3(16, 40), 64, 0, stream>>>(lobox, loarea, lmat);
    hipMemsetAsync(d_out, 0, (size_t)out_size*sizeof(float), stream);
    k_scan_nms4<<<8, 64, 0, stream>>>(rankinfo, lmat, lbox, lskey, (float*)d_out);
  } else {
    k_sortimg<<<8, 256, 0, stream>>>(keys, dlt[0],dlt[1],dlt[2],dlt[3],dlt[4], anchors,
                                     sbox, sskey, slvl);
    k_nms<<<8, 256, 0, stream>>>(sbox, sskey, slvl, (float*)d_out);
  }
}

// Round 9
// 642.054 us; speedup vs baseline: 1.0030x; 1.0030x over previous
//
#include <hip/hip_runtime.h>
#include <cmath>

#define N_IMG   8
#define PRE     1000
#define K_SEL   5000
#define NBIN    4096
#define TIE_CAP 4096
#define IMG_F   1344.0f
#define S_NEGINF 0x007FFFFFu
#define TILES   79             // ceil(5000/64)
#define GRPW    32000          // words per grp in lmat: 16 wblk x 1000 p x 2

__constant__ int c_W[5]   = {336,168,84,42,21};
__constant__ int c_HW[5]  = {112896,28224,7056,1764,441};
__constant__ int c_OFF[5] = {0,338688,423360,444528,449820};

__device__ __forceinline__ unsigned f2s(float f){
  unsigned u = __float_as_uint(f);
  return (u & 0x80000000u) ? ~u : (u | 0x80000000u);
}
__device__ __forceinline__ float s2f(unsigned s){
  unsigned u = (s & 0x80000000u) ? (s & 0x7FFFFFFFu) : ~s;
  return __uint_as_float(u);
}
__device__ __forceinline__ const float* sel5(int l, const float* p0,const float* p1,const float* p2,const float* p3,const float* p4){
  switch(l){case 0:return p0;case 1:return p1;case 2:return p2;case 3:return p3;default:return p4;}
}

struct BoxV { float x1,y1,x2,y2; bool valid; };

// Bit-faithful torchvision BoxCoder.decode + clip + min-size validity.
__device__ BoxV decode_box(int lvl, int t, int n, const float* dl, const float* anchors){
  int HW = c_HW[lvl], W = c_W[lvl];
  int a = t % 3, pos = t / 3;          // t = (h*W+w)*3 + a
  int h = pos / W, w = pos - h*W;
  int g = c_OFF[lvl] + t;
  const float* an = anchors + (size_t)4*(size_t)g;
  float a0=an[0], a1=an[1], a2=an[2], a3=an[3];
  float aw = __fsub_rn(a2,a0), ah = __fsub_rn(a3,a1);
  float acx = __fadd_rn(a0, __fmul_rn(0.5f,aw));
  float acy = __fadd_rn(a1, __fmul_rn(0.5f,ah));
  const float* dp = dl + ((size_t)n*12 + (size_t)a*4)*(size_t)HW + (size_t)h*W + (size_t)w;
  float dx = dp[0], dy = dp[HW], dwv = dp[2*(size_t)HW], dhv = dp[3*(size_t)HW];
  const float CLAMP = (float)4.135166556742356;  // log(1000/16)
  dwv = fminf(dwv, CLAMP); dhv = fminf(dhv, CLAMP);
  float pcx = __fadd_rn(__fmul_rn(dx,aw), acx);
  float pcy = __fadd_rn(__fmul_rn(dy,ah), acy);
  float pw = __fmul_rn((float)::exp((double)dwv), aw);
  float ph = __fmul_rn((float)::exp((double)dhv), ah);
  float hx = __fmul_rn(0.5f,pw), hy = __fmul_rn(0.5f,ph);
  BoxV b;
  b.x1 = fminf(fmaxf(__fsub_rn(pcx,hx),0.0f),IMG_F);
  b.y1 = fminf(fmaxf(__fsub_rn(pcy,hy),0.0f),IMG_F);
  b.x2 = fminf(fmaxf(__fadd_rn(pcx,hx),0.0f),IMG_F);
  b.y2 = fminf(fmaxf(__fadd_rn(pcy,hy),0.0f),IMG_F);
  b.valid = (__fsub_rn(b.x2,b.x1) >= 1e-3f) && (__fsub_rn(b.y2,b.y1) >= 1e-3f);
  return b;
}

// key = (~s_eff)<<22 | lvl<<19 | t : ascending sort == (score desc, level asc, idx asc)
__device__ unsigned long long make_key(unsigned s, int lvl, int t, int n, const float* dl, const float* anchors){
  BoxV b = decode_box(lvl,t,n,dl,anchors);
  unsigned se = b.valid ? s : S_NEGINF;     // invalid -> skey = -inf
  return ((unsigned long long)(~se) << 22) | ((unsigned long long)(unsigned)lvl << 19) | (unsigned long long)(unsigned)t;
}

// ---------------- K1: per-(image,level) 12-bit score histogram ----------------
__global__ __launch_bounds__(256) void k_hist(const float* o0,const float* o1,const float* o2,const float* o3,const float* o4,
                                              unsigned* hist){
  int grp = blockIdx.y; int n = grp/5, lvl = grp - n*5;
  const float* ob = sel5(lvl,o0,o1,o2,o3,o4);
  int HW = c_HW[lvl], M = 3*HW;
  ob += (size_t)n*(size_t)M;
  __shared__ unsigned lh[NBIN];
  for (int b = threadIdx.x; b < NBIN; b += 256) lh[b] = 0;
  __syncthreads();
  int stride = gridDim.x*256;
  for (int i = blockIdx.x*256 + threadIdx.x; i < M; i += stride){
    unsigned s = f2s(ob[i]);
    atomicAdd(&lh[s >> 20], 1u);
  }
  __syncthreads();
  unsigned* gh = hist + (size_t)grp*NBIN;
  for (int b = threadIdx.x; b < NBIN; b += 256){ unsigned v = lh[b]; if (v) atomicAdd(&gh[b], v); }
}

// ---------------- K2: find bin containing the 1000th-largest score ----------------
__global__ __launch_bounds__(256) void k_scan(const unsigned* hist, unsigned* thi){
  int grp = blockIdx.x;
  const unsigned* gh = hist + (size_t)grp*NBIN;
  __shared__ unsigned part[256];
  unsigned ssum = 0;
  int base = threadIdx.x*16;
  for (int b = base; b < base+16; ++b) ssum += gh[b];
  part[threadIdx.x] = ssum;
  __syncthreads();
  if (threadIdx.x == 0){
    int k = PRE;
    int c = 255;
    while ((int)part[c] < k){ k -= (int)part[c]; --c; }
    int b = c*16 + 15;
    while ((int)gh[b] < k){ k -= (int)gh[b]; --b; }
    thi[grp] = (unsigned)b;
  }
}

// ---------------- K3: compact >bin elements (decode+key), collect ==bin candidates ----------------
__global__ __launch_bounds__(256) void k_compact(const float* o0,const float* o1,const float* o2,const float* o3,const float* o4,
                                                 const float* d0,const float* d1,const float* d2,const float* d3,const float* d4,
                                                 const float* anchors, const unsigned* thi,
                                                 unsigned* cnt_gt, unsigned* cnt_eq,
                                                 unsigned long long* cand, unsigned long long* keys){
  int grp = blockIdx.y; int n = grp/5, lvl = grp - n*5;
  const float* ob = sel5(lvl,o0,o1,o2,o3,o4);
  const float* dl = sel5(lvl,d0,d1,d2,d3,d4);
  int HW = c_HW[lvl], M = 3*HW;
  ob += (size_t)n*(size_t)M;
  unsigned T = thi[grp];
  unsigned long long* kout = keys + (size_t)n*K_SEL + (size_t)lvl*PRE;
  int stride = gridDim.x*256;
  for (int i = blockIdx.x*256 + threadIdx.x; i < M; i += stride){
    unsigned s = f2s(ob[i]);
    unsigned sh = s >> 20;
    if (sh > T){
      unsigned pos = atomicAdd(&cnt_gt[grp], 1u);
      int a = i / HW; int rem = i - a*HW; int t = rem*3 + a;
      kout[pos] = make_key(s, lvl, t, n, dl, anchors);
    } else if (sh == T){
      unsigned e = atomicAdd(&cnt_eq[grp], 1u);
      if (e < TIE_CAP){
        int a = i / HW; int rem = i - a*HW; int t = rem*3 + a;
        cand[(size_t)grp*TIE_CAP + e] = ((unsigned long long)(~s) << 19) | (unsigned long long)(unsigned)t;
      }
    }
  }
}

template<int SZ>
__device__ void bitonic(unsigned long long* sk){
  for (int k = 2; k <= SZ; k <<= 1){
    for (int j = k >> 1; j > 0; j >>= 1){
      for (int i = threadIdx.x; i < SZ; i += blockDim.x){
        int ix = i ^ j;
        if (ix > i){
          unsigned long long va = sk[i], vb = sk[ix];
          if ((va > vb) == ((i & k) == 0)){ sk[i] = vb; sk[ix] = va; }
        }
      }
      __syncthreads();
    }
  }
}

// runtime-sized bitonic (SZ uniform across block, power of 2)
__device__ void bitonic_rt(unsigned long long* sk, int SZ){
  for (int k = 2; k <= SZ; k <<= 1){
    for (int j = k >> 1; j > 0; j >>= 1){
      for (int i = threadIdx.x; i < SZ; i += blockDim.x){
        int ix = i ^ j;
        if (ix > i){
          unsigned long long va = sk[i], vb = sk[ix];
          if ((va > vb) == ((i & k) == 0)){ sk[i] = vb; sk[ix] = va; }
        }
      }
      __syncthreads();
    }
  }
}

// ---------------- K4: exact boundary selection within the threshold bin ----------------
__global__ __launch_bounds__(256) void k_tiesel(const float* d0,const float* d1,const float* d2,const float* d3,const float* d4,
                                                const float* anchors,
                                                const unsigned* cnt_gt, const unsigned* cnt_eq,
                                                const unsigned long long* cand, unsigned long long* keys){
  int grp = blockIdx.x; int n = grp/5, lvl = grp - n*5;
  __shared__ unsigned long long sk[TIE_CAP];
  int ne = min((int)cnt_eq[grp], TIE_CAP);
  int SZ = 64; while (SZ < ne) SZ <<= 1;    // runtime pow2 >= ne (uniform)
  for (int i = threadIdx.x; i < SZ; i += 256)
    sk[i] = (i < ne) ? cand[(size_t)grp*TIE_CAP + i] : ~0ULL;
  __syncthreads();
  bitonic_rt(sk, SZ);                // ascending: (score desc, idx asc)
  int cg = (int)cnt_gt[grp];
  int need = PRE - cg;
  const float* dl = sel5(lvl,d0,d1,d2,d3,d4);
  unsigned long long* kout = keys + (size_t)n*K_SEL + (size_t)lvl*PRE + cg;
  for (int j = threadIdx.x; j < need; j += 256){
    if (j < ne){
      unsigned long long ck = sk[j];
      unsigned t = (unsigned)(ck & 0x7FFFFu);
      unsigned s = ~((unsigned)(ck >> 19));
      kout[j] = make_key(s, lvl, (int)t, n, dl, anchors);
    } else {
      kout[j] = ((unsigned long long)(~S_NEGINF) << 22); // pathological overflow: harmless invalid
    }
  }
}

// ---------------- K5a: sort each (image,level) run; decode level-space arrays ----------------
__global__ __launch_bounds__(256) void k_sortlvl(unsigned long long* keys,
                                                 const float* d0,const float* d1,const float* d2,const float* d3,const float* d4,
                                                 const float* anchors,
                                                 float4* lbox, float4* lobox, float* loarea, float* lskey){
  int grp = blockIdx.x; int n = grp/5, lvl = grp - n*5;
  __shared__ unsigned long long sk[1024];
  unsigned long long* kp = keys + (size_t)n*K_SEL + (size_t)lvl*PRE;
  for (int i = threadIdx.x; i < 1024; i += 256)
    sk[i] = (i < PRE) ? kp[i] : ~0ULL;
  __syncthreads();
  bitonic<1024>(sk);
  const float* dl = sel5(lvl,d0,d1,d2,d3,d4);
  for (int i = threadIdx.x; i < PRE; i += 256){
    unsigned long long key = sk[i];
    kp[i] = key;                          // sorted run back to global (k_rank reads it)
    int t = (int)(key & 0x7FFFFu);
    unsigned se = ~((unsigned)(key >> 22));
    BoxV b = decode_box(lvl, t, n, dl, anchors);
    size_t o = (size_t)grp*PRE + i;
    lbox[o] = make_float4(b.x1,b.y1,b.x2,b.y2);
    lskey[o] = s2f(se);                   // -inf if invalid
    float off = (float)lvl * 1345.0f;     // (IMG+1) batched-NMS offset
    float ox1 = __fadd_rn(b.x1, off), oy1 = __fadd_rn(b.y1, off);
    float ox2 = __fadd_rn(b.x2, off), oy2 = __fadd_rn(b.y2, off);
    lobox[o] = make_float4(ox1,oy1,ox2,oy2);
    loarea[o] = __fmul_rn(__fsub_rn(ox2,ox1), __fsub_rn(oy2,oy1));
  }
}

// ---------------- K5b: global rank of each level element (keys globally unique) ----------------
// rankinfo[rank] = p | (lvl<<10) | (valid<<13)
__global__ __launch_bounds__(256) void k_rank(const unsigned long long* keys, unsigned* rankinfo){
  int grp = blockIdx.x; int n = grp/5, lvl = grp - n*5;
  __shared__ unsigned long long sl[K_SEL];
  for (int i = threadIdx.x; i < K_SEL; i += 256) sl[i] = keys[(size_t)n*K_SEL + i];
  __syncthreads();
  for (int j = threadIdx.x; j < PRE; j += 256){
    unsigned long long k = sl[lvl*PRE + j];
    int rank = j;
    #pragma unroll
    for (int m = 0; m < 5; ++m){
      if (m == lvl) continue;
      const unsigned long long* s = sl + m*PRE;
      int lo = 0, hi = PRE;
      while (lo < hi){ int mid = (lo+hi) >> 1; if (s[mid] < k) lo = mid+1; else hi = mid; }
      rank += lo;
    }
    unsigned se = ~((unsigned)(k >> 22));
    unsigned info = (unsigned)j | ((unsigned)lvl << 10) | ((se != S_NEGINF) ? (1u<<13) : 0u);
    rankinfo[(size_t)n*K_SEL + rank] = info;   // exact permutation of [0,5000)
  }
}

// ---------------- K6a: per-level suppression bit-matrix, ballot + column layout ----------------
// lmat[grp][wblk][p][d]: word (wblk*2+d) of row p. One wave per (grp, wblk):
// lane's j-box in registers, p-loop does broadcast LDS reads (independent -> pipelined),
// ballot assembles 64 bits, lanes 0/32 store 8B into the wave's PRIVATE contiguous
// 8KB region -> full-line L2 write coalescing (fixes round-8's 5x write amplification).
__global__ __launch_bounds__(64) void k_ioumat_lvl(const float4* lobox, const float* loarea, unsigned* lmat){
  int grp = blockIdx.y;                  // n*5 + L
  int wblk = blockIdx.x;                 // j-block: j = wblk*64 + lane
  int lane = threadIdx.x;
  __shared__ float sx1[PRE], sy1[PRE], sx2[PRE], sy2[PRE], sar[PRE];
  for (int i = lane; i < PRE; i += 64){
    float4 bb = lobox[(size_t)grp*PRE + i];
    sx1[i]=bb.x; sy1[i]=bb.y; sx2[i]=bb.z; sy2[i]=bb.w;
    sar[i]=loarea[(size_t)grp*PRE + i];
  }
  __syncthreads();
  int j = wblk*64 + lane;
  float jx1=0.f,jy1=0.f,jx2=0.f,jy2=0.f,ja=0.f;
  if (j < PRE){
    float4 bb = lobox[(size_t)grp*PRE + j];
    jx1=bb.x; jy1=bb.y; jx2=bb.z; jy2=bb.w; ja=loarea[(size_t)grp*PRE + j];
  }
  unsigned* mg = lmat + (size_t)grp*GRPW + (size_t)wblk*2*PRE;
  int pmax = min(PRE, wblk*64 + 63);     // rows p >= pmax have no j>p in this block
  for (int p = 0; p < pmax; ++p){
    float bx1=sx1[p], by1=sy1[p], bx2=sx2[p], by2=sy2[p], ba=sar[p];  // broadcast reads
    float ltx = fmaxf(bx1, jx1), lty = fmaxf(by1, jy1);
    float rbx = fminf(bx2, jx2), rby = fminf(by2, jy2);
    float ww = fmaxf(__fsub_rn(rbx,ltx), 0.0f);
    float hh = fmaxf(__fsub_rn(rby,lty), 0.0f);
    float inter = __fmul_rn(ww,hh);
    float uni = __fsub_rn(__fadd_rn(ba, ja), inter);
    bool hit = (__fdiv_rn(inter,uni) > 0.7f) && (j > p) && (j < PRE);
    unsigned long long bal = __ballot(hit);
    if ((lane & 31) == 0)
      mg[p*2 + (lane>>5)] = (lane == 0) ? (unsigned)bal : (unsigned)(bal >> 32);
  }
  for (int q = pmax*2 + lane; q < 2*PRE; q += 64) mg[q] = 0u;   // contiguous zero-fill
}

// ---------------- K6b: tile-parallel greedy scan, one wave per image ----------------
__global__ __launch_bounds__(64) void k_scan_nms4(const unsigned* rankinfo, const unsigned* lmat,
                                                  const float4* lbox, const float* lskey, float* out){
  __shared__ unsigned lrows[64][36];     // row-major tile; stride 36 words
  int n = blockIdx.x; int lane = threadIdx.x;
  int n5 = n*5;
  const unsigned* rin = rankinfo + (size_t)n*K_SEL;
  float* outn = out + (size_t)n*PRE*5;
  unsigned sup0=0u,sup1=0u,sup2=0u,sup3=0u,sup4=0u;
  int kept_total = 0;
  uint2 Pa,Pb,Pc,Pd,Pe,Pf,Pg,Ph,Pi,Pj,Pk,Pl,Pm,Pn,Po,Pp;  // 16x8B staging
  float4 boxP; float scP = 0.f;
  unsigned infoC, infoN;
  int rgrp = lane >> 4;                  // 0..3: row subgroup
  unsigned wboff = (unsigned)(lane & 15) * (2u*PRE);  // my wblk's column segment
  int wb2 = (lane & 15) << 1;            // word index within row

  // candidate (L,p) -> base word offset of its row's column entries: grp*GRPW + p*2
#define SLOAD(INFO) { \
    unsigned L_ = ((INFO)>>10)&7u; unsigned p_ = (INFO) & 1023u; \
    unsigned rowu_ = ((unsigned)n5 + L_)*GRPW + p_*2u; \
    unsigned rb_; \
    rb_ = __shfl(rowu_,  0 + rgrp); Pa = *(const uint2*)(lmat + rb_ + wboff); \
    rb_ = __shfl(rowu_,  4 + rgrp); Pb = *(const uint2*)(lmat + rb_ + wboff); \
    rb_ = __shfl(rowu_,  8 + rgrp); Pc = *(const uint2*)(lmat + rb_ + wboff); \
    rb_ = __shfl(rowu_, 12 + rgrp); Pd = *(const uint2*)(lmat + rb_ + wboff); \
    rb_ = __shfl(rowu_, 16 + rgrp); Pe = *(const uint2*)(lmat + rb_ + wboff); \
    rb_ = __shfl(rowu_, 20 + rgrp); Pf = *(const uint2*)(lmat + rb_ + wboff); \
    rb_ = __shfl(rowu_, 24 + rgrp); Pg = *(const uint2*)(lmat + rb_ + wboff); \
    rb_ = __shfl(rowu_, 28 + rgrp); Ph = *(const uint2*)(lmat + rb_ + wboff); \
    rb_ = __shfl(rowu_, 32 + rgrp); Pi = *(const uint2*)(lmat + rb_ + wboff); \
    rb_ = __shfl(rowu_, 36 + rgrp); Pj = *(const uint2*)(lmat + rb_ + wboff); \
    rb_ = __shfl(rowu_, 40 + rgrp); Pk = *(const uint2*)(lmat + rb_ + wboff); \
    rb_ = __shfl(rowu_, 44 + rgrp); Pl = *(const uint2*)(lmat + rb_ + wboff); \
    rb_ = __shfl(rowu_, 48 + rgrp); Pm = *(const uint2*)(lmat + rb_ + wboff); \
    rb_ = __shfl(rowu_, 52 + rgrp); Pn = *(const uint2*)(lmat + rb_ + wboff); \
    rb_ = __shfl(rowu_, 56 + rgrp); Po = *(const uint2*)(lmat + rb_ + wboff); \
    rb_ = __shfl(rowu_, 60 + rgrp); Pp = *(const uint2*)(lmat + rb_ + wboff); \
    size_t bi_ = (size_t)((unsigned)n5 + L_)*PRE + p_; \
    boxP = lbox[bi_]; scP = lskey[bi_]; }

#define SWRITE() { \
    *(uint2*)&lrows[ 0 + rgrp][wb2] = Pa; *(uint2*)&lrows[ 4 + rgrp][wb2] = Pb; \
    *(uint2*)&lrows[ 8 + rgrp][wb2] = Pc; *(uint2*)&lrows[12 + rgrp][wb2] = Pd; \
    *(uint2*)&lrows[16 + rgrp][wb2] = Pe; *(uint2*)&lrows[20 + rgrp][wb2] = Pf; \
    *(uint2*)&lrows[24 + rgrp][wb2] = Pg; *(uint2*)&lrows[28 + rgrp][wb2] = Ph; \
    *(uint2*)&lrows[32 + rgrp][wb2] = Pi; *(uint2*)&lrows[36 + rgrp][wb2] = Pj; \
    *(uint2*)&lrows[40 + rgrp][wb2] = Pk; *(uint2*)&lrows[44 + rgrp][wb2] = Pl; \
    *(uint2*)&lrows[48 + rgrp][wb2] = Pm; *(uint2*)&lrows[52 + rgrp][wb2] = Pn; \
    *(uint2*)&lrows[56 + rgrp][wb2] = Po; *(uint2*)&lrows[60 + rgrp][wb2] = Pp; }

#define TPROC(INFO, BOX, SC, baseexpr) { \
    int base_ = (baseexpr); \
    unsigned L_ = ((INFO)>>10)&7u; unsigned p_ = (INFO) & 1023u; \
    bool ok_ = ((((INFO)>>13)&1u) != 0u) && (base_ + lane < K_SEL); \
    int idxw_ = (int)(p_ >> 5); unsigned pb_ = p_ & 31u; \
    unsigned t0_=__shfl(sup0,idxw_), t1_=__shfl(sup1,idxw_), t2_=__shfl(sup2,idxw_), t3_=__shfl(sup3,idxw_), t4_=__shfl(sup4,idxw_); \
    unsigned sw_ = (L_==0u)?t0_:(L_==1u)?t1_:(L_==2u)?t2_:(L_==3u)?t3_:t4_; \
    bool pre_ = (!ok_) || (((sw_ >> pb_) & 1u) != 0u); \
    unsigned long long preM_ = __ballot(pre_); \
    unsigned cmlo_ = 0u, cmhi_ = 0u; \
    _Pragma("unroll") \
    for (int m_=0; m_<64; ++m_){ \
      unsigned infoM_ = __builtin_amdgcn_readlane((INFO), m_); \
      unsigned Lm_ = (infoM_>>10)&7u; \
      unsigned w_ = lrows[m_][idxw_]; \
      unsigned bit_ = ((w_ >> pb_) & 1u) & ((L_ == Lm_) ? 1u : 0u); \
      if (m_ < 32) cmlo_ |= bit_ << m_; else cmhi_ |= bit_ << (m_-32); \
    } \
    unsigned long long keptM_ = 0ull; \
    _Pragma("unroll") \
    for (int m_=0; m_<64; ++m_){ \
      unsigned long long cml_ = ((unsigned long long)__builtin_amdgcn_readlane(cmhi_, m_) << 32) \
                              |  (unsigned long long)__builtin_amdgcn_readlane(cmlo_, m_); \
      bool keep_ = (((preM_>>m_)&1ull) == 0ull) && ((cml_ & keptM_) == 0ull); \
      if (keep_) keptM_ |= (1ull<<m_); \
    } \
    unsigned myw_ = (unsigned)(lane & 31); \
    _Pragma("unroll") \
    for (int m_=0; m_<64; ++m_){ \
      if ((keptM_>>m_)&1ull){ \
        unsigned infoM_ = __builtin_amdgcn_readlane((INFO), m_); \
        unsigned Lm_ = (infoM_>>10)&7u; \
        unsigned rw_ = lrows[m_][myw_]; \
        switch(Lm_){ case 0u: sup0|=rw_; break; case 1u: sup1|=rw_; break; \
                     case 2u: sup2|=rw_; break; case 3u: sup3|=rw_; break; default: sup4|=rw_; } \
      } \
    } \
    int pos_ = kept_total + (int)__popcll(keptM_ & ((1ull<<lane)-1ull)); \
    if (((keptM_>>lane)&1ull) && pos_ < PRE){ \
      float* orow_ = outn + (size_t)pos_*5; \
      orow_[0]=(BOX).x; orow_[1]=(BOX).y; orow_[2]=(BOX).z; orow_[3]=(BOX).w; orow_[4]=(SC); \
    } \
    kept_total += (int)__popcll(keptM_); \
  }

  infoC = rin[lane];
  SLOAD(infoC);                          // tile 0 rows -> regs, box -> boxP
  SWRITE();                              // tile 0 rows -> LDS
  float4 boxC = boxP; float scC = scP;
  infoN = rin[64 + lane];

  for (int t = 0; t < TILES; ++t){
    if (t+1 < TILES) SLOAD(infoN);       // issue next tile's loads (rows + box)
    asm volatile("s_waitcnt lgkmcnt(0)" ::: "memory");   // lrows writes visible
    TPROC(infoC, boxC, scC, t*64);
    if (kept_total >= PRE) break;
    if (t+1 < TILES){
      SWRITE();                          // waits next tile's loads (covered by TPROC)
      boxC = boxP; scC = scP;
      infoC = infoN;
      if (t+2 < TILES){
        int nx = (t+2)*64 + lane; if (nx > K_SEL-1) nx = K_SEL-1;
        infoN = rin[nx];
      }
    }
  }
#undef SLOAD
#undef SWRITE
#undef TPROC
}

// ---------------- fallback path (ws too small): round-3 kernels ----------------
__global__ __launch_bounds__(256) void k_sortimg(const unsigned long long* keys,
                                                 const float* d0,const float* d1,const float* d2,const float* d3,const float* d4,
                                                 const float* anchors,
                                                 float4* sbox, float* sskey, int* slvl){
  int n = blockIdx.x;
  __shared__ unsigned long long sk[8192];
  for (int i = threadIdx.x; i < 8192; i += 256)
    sk[i] = (i < K_SEL) ? keys[(size_t)n*K_SEL + i] : ~0ULL;
  __syncthreads();
  bitonic<8192>(sk);
  for (int r = threadIdx.x; r < K_SEL; r += 256){
    unsigned long long key = sk[r];
    int t = (int)(key & 0x7FFFFu);
    int lvl = (int)((key >> 19) & 7u);
    unsigned se = ~((unsigned)(key >> 22));
    const float* dl = sel5(lvl,d0,d1,d2,d3,d4);
    BoxV b = decode_box(lvl, t, n, dl, anchors);
    sbox[(size_t)n*K_SEL + r] = make_float4(b.x1,b.y1,b.x2,b.y2);
    sskey[(size_t)n*K_SEL + r] = s2f(se);
    slvl[(size_t)n*K_SEL + r] = lvl;
  }
}

__global__ __launch_bounds__(256) void k_nms(const float4* sbox, const float* sskey, const int* slvl, float* out){
  int n = blockIdx.x, tid = threadIdx.x;
  __shared__ float kx1[PRE], ky1[PRE], kx2[PRE], ky2[PRE], kar[PRE];
  __shared__ int klv[PRE];
  __shared__ int nv_s, flag_s;
  for (int i = tid; i < PRE*5; i += 256) out[(size_t)n*PRE*5 + i] = 0.0f;
  if (tid == 0){ nv_s = 0; flag_s = 0; }
  __syncthreads();
  int c = 0;
  for (int i = tid; i < K_SEL; i += 256)
    if (sskey[(size_t)n*K_SEL + i] != -INFINITY) ++c;
  atomicAdd(&nv_s, c);
  __syncthreads();
  int nvalid = nv_s;
  int kept = 0;
  for (int i = 0; i < nvalid; ++i){
    float4 b = sbox[(size_t)n*K_SEL + i];
    int lv = slvl[(size_t)n*K_SEL + i];
    float off = (float)lv * 1345.0f;
    float ox1 = __fadd_rn(b.x, off), oy1 = __fadd_rn(b.y, off);
    float ox2 = __fadd_rn(b.z, off), oy2 = __fadd_rn(b.w, off);
    float area = __fmul_rn(__fsub_rn(ox2,ox1), __fsub_rn(oy2,oy1));
    bool hit = false;
    for (int j = tid; j < kept; j += 256){
      if (klv[j] == lv){
        float ltx = fmaxf(kx1[j], ox1), lty = fmaxf(ky1[j], oy1);
        float rbx = fminf(kx2[j], ox2), rby = fminf(ky2[j], oy2);
        float w = fmaxf(__fsub_rn(rbx,ltx), 0.0f);
        float h = fmaxf(__fsub_rn(rby,lty), 0.0f);
        float inter = __fmul_rn(w,h);
        float uni = __fsub_rn(__fadd_rn(kar[j], area), inter);
        if (__fdiv_rn(inter,uni) > 0.7f) hit = true;
      }
    }
    if (hit) flag_s = 1;
    __syncthreads();
    int sup = flag_s;
    __syncthreads();
    if (!sup){
      if (tid == 0){
        kx1[kept]=ox1; ky1[kept]=oy1; kx2[kept]=ox2; ky2[kept]=oy2; kar[kept]=area; klv[kept]=lv;
        float* orow = out + (size_t)n*PRE*5 + (size_t)kept*5;
        orow[0]=b.x; orow[1]=b.y; orow[2]=b.z; orow[3]=b.w;
        orow[4]=sskey[(size_t)n*K_SEL + i];
      }
      ++kept;
    }
    if (tid == 0) flag_s = 0;
    __syncthreads();
    if (kept == PRE) break;
  }
}

extern "C" void kernel_launch(void* const* d_in, const int* in_sizes, int n_in,
                              void* d_out, int out_size, void* d_ws, size_t ws_size,
                              hipStream_t stream) {
  bool interleaved = (in_sizes[1] == 4*in_sizes[0]);
  const float* obj[5]; const float* dlt[5];
  for (int i = 0; i < 5; ++i){
    if (interleaved){ obj[i] = (const float*)d_in[2*i]; dlt[i] = (const float*)d_in[2*i+1]; }
    else            { obj[i] = (const float*)d_in[i];   dlt[i] = (const float*)d_in[5+i]; }
  }
  const float* anchors = (const float*)d_in[10];

  char* ws = (char*)d_ws;
  unsigned* hist            = (unsigned*)(ws);                     // 655360
  unsigned* cnt_gt          = (unsigned*)(ws + 655360);            // 160
  unsigned* cnt_eq          = (unsigned*)(ws + 655520);            // 160
  unsigned* thi             = (unsigned*)(ws + 655680);            // 160 -> counters end 655840
  unsigned long long* cand  = (unsigned long long*)(ws + 655840);  // 1310720 -> 1966560
  unsigned long long* keys  = (unsigned long long*)(ws + 1966560); // 320000 -> 2286560
  float4* lbox              = (float4*)(ws + 2286560);             // 640000 -> 2926560
  float4* lobox             = (float4*)(ws + 2926560);             // 640000 -> 3566560
  float* loarea             = (float*)(ws + 3566560);              // 160000 -> 3726560
  float* lskey              = (float*)(ws + 3726560);              // 160000 -> 3886560
  unsigned* rankinfo        = (unsigned*)(ws + 3886560);           // 160000 -> 4046560
  unsigned* lmat            = (unsigned*)(ws + 4046560);           // 5120000 -> 9166560
  float4* sbox              = (float4*)(ws + 9166560);             // fallback: 640000 -> 9806560
  float* sskey              = (float*)(ws + 9806560);              // 160000 -> 9966560
  int* slvl                 = (int*)(ws + 9966560);                // 160000 -> 10126560
  const size_t NEED = 10126560;

  hipMemsetAsync(ws, 0, 655840, stream);   // hist + counters

  dim3 gScan(8, 40);
  k_hist<<<gScan, 256, 0, stream>>>(obj[0],obj[1],obj[2],obj[3],obj[4], hist);
  k_scan<<<40, 256, 0, stream>>>(hist, thi);
  k_compact<<<gScan, 256, 0, stream>>>(obj[0],obj[1],obj[2],obj[3],obj[4],
                                       dlt[0],dlt[1],dlt[2],dlt[3],dlt[4],
                                       anchors, thi, cnt_gt, cnt_eq, cand, keys);
  k_tiesel<<<40, 256, 0, stream>>>(dlt[0],dlt[1],dlt[2],dlt[3],dlt[4], anchors,
                                   cnt_gt, cnt_eq, cand, keys);
  if (ws_size >= NEED){
    k_sortlvl<<<40, 256, 0, stream>>>(keys, dlt[0],dlt[1],dlt[2],dlt[3],dlt[4], anchors,
                                      lbox, lobox, loarea, lskey);
    k_rank<<<40, 256, 0, stream>>>(keys, rankinfo);
    k_ioumat_lvl<<<dim3(16, 40), 64, 0, stream>>>(lobox, loarea, lmat);
    hipMemsetAsync(d_out, 0, (size_t)out_size*sizeof(float), stream);
    k_scan_nms4<<<8, 64, 0, stream>>>(rankinfo, lmat, lbox, lskey, (float*)d_out);
  } else {
    k_sortimg<<<8, 256, 0, stream>>>(keys, dlt[0],dlt[1],dlt[2],dlt[3],dlt[4], anchors,
                                     sbox, sskey, slvl);
    k_nms<<<8, 256, 0, stream>>>(sbox, sskey, slvl, (float*)d_out);
  }
}

// Round 10
// 531.601 us; speedup vs baseline: 1.2114x; 1.2078x over previous
//
#include <hip/hip_runtime.h>
#include <cmath>

#define N_IMG   8
#define PRE     1000
#define K_SEL   5000
#define NBIN    4096
#define TIE_CAP 4096
#define IMG_F   1344.0f
#define S_NEGINF 0x007FFFFFu
#define TILES   79             // ceil(5000/64)
#define GRPW    32000          // words per grp in lmat: 16 wblk x 1000 p x 2

__constant__ int c_W[5]   = {336,168,84,42,21};
__constant__ int c_HW[5]  = {112896,28224,7056,1764,441};
__constant__ int c_OFF[5] = {0,338688,423360,444528,449820};

__device__ __forceinline__ unsigned f2s(float f){
  unsigned u = __float_as_uint(f);
  return (u & 0x80000000u) ? ~u : (u | 0x80000000u);
}
__device__ __forceinline__ float s2f(unsigned s){
  unsigned u = (s & 0x80000000u) ? (s & 0x7FFFFFFFu) : ~s;
  return __uint_as_float(u);
}
__device__ __forceinline__ const float* sel5(int l, const float* p0,const float* p1,const float* p2,const float* p3,const float* p4){
  switch(l){case 0:return p0;case 1:return p1;case 2:return p2;case 3:return p3;default:return p4;}
}

struct BoxV { float x1,y1,x2,y2; bool valid; };

// Bit-faithful torchvision BoxCoder.decode + clip + min-size validity.
__device__ BoxV decode_box(int lvl, int t, int n, const float* dl, const float* anchors){
  int HW = c_HW[lvl], W = c_W[lvl];
  int a = t % 3, pos = t / 3;          // t = (h*W+w)*3 + a
  int h = pos / W, w = pos - h*W;
  int g = c_OFF[lvl] + t;
  const float* an = anchors + (size_t)4*(size_t)g;
  float a0=an[0], a1=an[1], a2=an[2], a3=an[3];
  float aw = __fsub_rn(a2,a0), ah = __fsub_rn(a3,a1);
  float acx = __fadd_rn(a0, __fmul_rn(0.5f,aw));
  float acy = __fadd_rn(a1, __fmul_rn(0.5f,ah));
  const float* dp = dl + ((size_t)n*12 + (size_t)a*4)*(size_t)HW + (size_t)h*W + (size_t)w;
  float dx = dp[0], dy = dp[HW], dwv = dp[2*(size_t)HW], dhv = dp[3*(size_t)HW];
  const float CLAMP = (float)4.135166556742356;  // log(1000/16)
  dwv = fminf(dwv, CLAMP); dhv = fminf(dhv, CLAMP);
  float pcx = __fadd_rn(__fmul_rn(dx,aw), acx);
  float pcy = __fadd_rn(__fmul_rn(dy,ah), acy);
  float pw = __fmul_rn((float)::exp((double)dwv), aw);
  float ph = __fmul_rn((float)::exp((double)dhv), ah);
  float hx = __fmul_rn(0.5f,pw), hy = __fmul_rn(0.5f,ph);
  BoxV b;
  b.x1 = fminf(fmaxf(__fsub_rn(pcx,hx),0.0f),IMG_F);
  b.y1 = fminf(fmaxf(__fsub_rn(pcy,hy),0.0f),IMG_F);
  b.x2 = fminf(fmaxf(__fadd_rn(pcx,hx),0.0f),IMG_F);
  b.y2 = fminf(fmaxf(__fadd_rn(pcy,hy),0.0f),IMG_F);
  b.valid = (__fsub_rn(b.x2,b.x1) >= 1e-3f) && (__fsub_rn(b.y2,b.y1) >= 1e-3f);
  return b;
}

// key = (~s_eff)<<22 | lvl<<19 | t : ascending sort == (score desc, level asc, idx asc)
__device__ unsigned long long make_key(unsigned s, int lvl, int t, int n, const float* dl, const float* anchors){
  BoxV b = decode_box(lvl,t,n,dl,anchors);
  unsigned se = b.valid ? s : S_NEGINF;     // invalid -> skey = -inf
  return ((unsigned long long)(~se) << 22) | ((unsigned long long)(unsigned)lvl << 19) | (unsigned long long)(unsigned)t;
}

// ---------------- K1: per-(image,level) 12-bit score histogram ----------------
__global__ __launch_bounds__(256) void k_hist(const float* o0,const float* o1,const float* o2,const float* o3,const float* o4,
                                              unsigned* hist){
  int grp = blockIdx.y; int n = grp/5, lvl = grp - n*5;
  const float* ob = sel5(lvl,o0,o1,o2,o3,o4);
  int HW = c_HW[lvl], M = 3*HW;
  ob += (size_t)n*(size_t)M;
  __shared__ unsigned lh[NBIN];
  for (int b = threadIdx.x; b < NBIN; b += 256) lh[b] = 0;
  __syncthreads();
  int stride = gridDim.x*256;
  for (int i = blockIdx.x*256 + threadIdx.x; i < M; i += stride){
    unsigned s = f2s(ob[i]);
    atomicAdd(&lh[s >> 20], 1u);
  }
  __syncthreads();
  unsigned* gh = hist + (size_t)grp*NBIN;
  for (int b = threadIdx.x; b < NBIN; b += 256){ unsigned v = lh[b]; if (v) atomicAdd(&gh[b], v); }
}

// ---------------- K2: find bin containing the 1000th-largest score ----------------
__global__ __launch_bounds__(256) void k_scan(const unsigned* hist, unsigned* thi){
  int grp = blockIdx.x;
  const unsigned* gh = hist + (size_t)grp*NBIN;
  __shared__ unsigned part[256];
  unsigned ssum = 0;
  int base = threadIdx.x*16;
  for (int b = base; b < base+16; ++b) ssum += gh[b];
  part[threadIdx.x] = ssum;
  __syncthreads();
  if (threadIdx.x == 0){
    int k = PRE;
    int c = 255;
    while ((int)part[c] < k){ k -= (int)part[c]; --c; }
    int b = c*16 + 15;
    while ((int)gh[b] < k){ k -= (int)gh[b]; --b; }
    thi[grp] = (unsigned)b;
  }
}

// ---------------- K3: compact >bin elements (decode+key), collect ==bin candidates ----------------
__global__ __launch_bounds__(256) void k_compact(const float* o0,const float* o1,const float* o2,const float* o3,const float* o4,
                                                 const float* d0,const float* d1,const float* d2,const float* d3,const float* d4,
                                                 const float* anchors, const unsigned* thi,
                                                 unsigned* cnt_gt, unsigned* cnt_eq,
                                                 unsigned long long* cand, unsigned long long* keys){
  int grp = blockIdx.y; int n = grp/5, lvl = grp - n*5;
  const float* ob = sel5(lvl,o0,o1,o2,o3,o4);
  const float* dl = sel5(lvl,d0,d1,d2,d3,d4);
  int HW = c_HW[lvl], M = 3*HW;
  ob += (size_t)n*(size_t)M;
  unsigned T = thi[grp];
  unsigned long long* kout = keys + (size_t)n*K_SEL + (size_t)lvl*PRE;
  int stride = gridDim.x*256;
  for (int i = blockIdx.x*256 + threadIdx.x; i < M; i += stride){
    unsigned s = f2s(ob[i]);
    unsigned sh = s >> 20;
    if (sh > T){
      unsigned pos = atomicAdd(&cnt_gt[grp], 1u);
      int a = i / HW; int rem = i - a*HW; int t = rem*3 + a;
      kout[pos] = make_key(s, lvl, t, n, dl, anchors);
    } else if (sh == T){
      unsigned e = atomicAdd(&cnt_eq[grp], 1u);
      if (e < TIE_CAP){
        int a = i / HW; int rem = i - a*HW; int t = rem*3 + a;
        cand[(size_t)grp*TIE_CAP + e] = ((unsigned long long)(~s) << 19) | (unsigned long long)(unsigned)t;
      }
    }
  }
}

template<int SZ>
__device__ void bitonic(unsigned long long* sk){
  for (int k = 2; k <= SZ; k <<= 1){
    for (int j = k >> 1; j > 0; j >>= 1){
      for (int i = threadIdx.x; i < SZ; i += blockDim.x){
        int ix = i ^ j;
        if (ix > i){
          unsigned long long va = sk[i], vb = sk[ix];
          if ((va > vb) == ((i & k) == 0)){ sk[i] = vb; sk[ix] = va; }
        }
      }
      __syncthreads();
    }
  }
}

// runtime-sized bitonic (SZ uniform across block, power of 2)
__device__ void bitonic_rt(unsigned long long* sk, int SZ){
  for (int k = 2; k <= SZ; k <<= 1){
    for (int j = k >> 1; j > 0; j >>= 1){
      for (int i = threadIdx.x; i < SZ; i += blockDim.x){
        int ix = i ^ j;
        if (ix > i){
          unsigned long long va = sk[i], vb = sk[ix];
          if ((va > vb) == ((i & k) == 0)){ sk[i] = vb; sk[ix] = va; }
        }
      }
      __syncthreads();
    }
  }
}

// ---------------- K4: exact boundary selection within the threshold bin ----------------
__global__ __launch_bounds__(256) void k_tiesel(const float* d0,const float* d1,const float* d2,const float* d3,const float* d4,
                                                const float* anchors,
                                                const unsigned* cnt_gt, const unsigned* cnt_eq,
                                                const unsigned long long* cand, unsigned long long* keys){
  int grp = blockIdx.x; int n = grp/5, lvl = grp - n*5;
  __shared__ unsigned long long sk[TIE_CAP];
  int ne = min((int)cnt_eq[grp], TIE_CAP);
  int SZ = 64; while (SZ < ne) SZ <<= 1;    // runtime pow2 >= ne (uniform)
  for (int i = threadIdx.x; i < SZ; i += 256)
    sk[i] = (i < ne) ? cand[(size_t)grp*TIE_CAP + i] : ~0ULL;
  __syncthreads();
  bitonic_rt(sk, SZ);                // ascending: (score desc, idx asc)
  int cg = (int)cnt_gt[grp];
  int need = PRE - cg;
  const float* dl = sel5(lvl,d0,d1,d2,d3,d4);
  unsigned long long* kout = keys + (size_t)n*K_SEL + (size_t)lvl*PRE + cg;
  for (int j = threadIdx.x; j < need; j += 256){
    if (j < ne){
      unsigned long long ck = sk[j];
      unsigned t = (unsigned)(ck & 0x7FFFFu);
      unsigned s = ~((unsigned)(ck >> 19));
      kout[j] = make_key(s, lvl, (int)t, n, dl, anchors);
    } else {
      kout[j] = ((unsigned long long)(~S_NEGINF) << 22); // pathological overflow: harmless invalid
    }
  }
}

// ---------------- K5a: sort each (image,level) run; decode level-space arrays ----------------
__global__ __launch_bounds__(256) void k_sortlvl(unsigned long long* keys,
                                                 const float* d0,const float* d1,const float* d2,const float* d3,const float* d4,
                                                 const float* anchors,
                                                 float4* lbox, float4* lobox, float* loarea, float* lskey){
  int grp = blockIdx.x; int n = grp/5, lvl = grp - n*5;
  __shared__ unsigned long long sk[1024];
  unsigned long long* kp = keys + (size_t)n*K_SEL + (size_t)lvl*PRE;
  for (int i = threadIdx.x; i < 1024; i += 256)
    sk[i] = (i < PRE) ? kp[i] : ~0ULL;
  __syncthreads();
  bitonic<1024>(sk);
  const float* dl = sel5(lvl,d0,d1,d2,d3,d4);
  for (int i = threadIdx.x; i < PRE; i += 256){
    unsigned long long key = sk[i];
    kp[i] = key;                          // sorted run back to global (k_rank reads it)
    int t = (int)(key & 0x7FFFFu);
    unsigned se = ~((unsigned)(key >> 22));
    BoxV b = decode_box(lvl, t, n, dl, anchors);
    size_t o = (size_t)grp*PRE + i;
    lbox[o] = make_float4(b.x1,b.y1,b.x2,b.y2);
    lskey[o] = s2f(se);                   // -inf if invalid
    float off = (float)lvl * 1345.0f;     // (IMG+1) batched-NMS offset
    float ox1 = __fadd_rn(b.x1, off), oy1 = __fadd_rn(b.y1, off);
    float ox2 = __fadd_rn(b.x2, off), oy2 = __fadd_rn(b.y2, off);
    lobox[o] = make_float4(ox1,oy1,ox2,oy2);
    loarea[o] = __fmul_rn(__fsub_rn(ox2,ox1), __fsub_rn(oy2,oy1));
  }
}

// ---------------- K5b: global rank of each level element (keys globally unique) ----------------
// rankinfo[rank] = p | (lvl<<10) | (valid<<13)
__global__ __launch_bounds__(256) void k_rank(const unsigned long long* keys, unsigned* rankinfo){
  int grp = blockIdx.x; int n = grp/5, lvl = grp - n*5;
  __shared__ unsigned long long sl[K_SEL];
  for (int i = threadIdx.x; i < K_SEL; i += 256) sl[i] = keys[(size_t)n*K_SEL + i];
  __syncthreads();
  for (int j = threadIdx.x; j < PRE; j += 256){
    unsigned long long k = sl[lvl*PRE + j];
    int rank = j;
    #pragma unroll
    for (int m = 0; m < 5; ++m){
      if (m == lvl) continue;
      const unsigned long long* s = sl + m*PRE;
      int lo = 0, hi = PRE;
      while (lo < hi){ int mid = (lo+hi) >> 1; if (s[mid] < k) lo = mid+1; else hi = mid; }
      rank += lo;
    }
    unsigned se = ~((unsigned)(k >> 22));
    unsigned info = (unsigned)j | ((unsigned)lvl << 10) | ((se != S_NEGINF) ? (1u<<13) : 0u);
    rankinfo[(size_t)n*K_SEL + rank] = info;   // exact permutation of [0,5000)
  }
}

// ---------------- K6a: suppression bit-matrix, ballot + column layout, 4 waves/block ----------------
// Grid (16 wblk, 40 grp) x 256 threads. Wave q of a block handles p-quarter
// [q*250, q*250+250): 2560 waves (~10/CU) and a 4x-unrolled p-loop with hoisted
// LDS broadcast reads -> latency pipelined (fixes round-9's 410-cycle/iter chain).
__global__ __launch_bounds__(256) void k_ioumat_lvl(const float4* lobox, const float* loarea, unsigned* lmat){
  int grp = blockIdx.y;                  // n*5 + L
  int wblk = blockIdx.x;                 // j-block: j = wblk*64 + lane
  int tid = threadIdx.x;
  int lane = tid & 63, q = tid >> 6;
  __shared__ float sx1[PRE], sy1[PRE], sx2[PRE], sy2[PRE], sar[PRE];
  for (int i = tid; i < PRE; i += 256){
    float4 bb = lobox[(size_t)grp*PRE + i];
    sx1[i]=bb.x; sy1[i]=bb.y; sx2[i]=bb.z; sy2[i]=bb.w;
    sar[i]=loarea[(size_t)grp*PRE + i];
  }
  __syncthreads();
  int j = wblk*64 + lane;
  float jx1=0.f,jy1=0.f,jx2=0.f,jy2=0.f,ja=0.f;
  if (j < PRE){
    float4 bb = lobox[(size_t)grp*PRE + j];
    jx1=bb.x; jy1=bb.y; jx2=bb.z; jy2=bb.w; ja=loarea[(size_t)grp*PRE + j];
  }
  unsigned* mg = lmat + (size_t)grp*GRPW + (size_t)wblk*2*PRE;
  int pmax = min(PRE, wblk*64 + 63);     // rows p >= pmax: no j>p in this block
  int q0 = q*250, q1 = q0 + 250;
  int pm = min(q1, pmax);

#define IOU_HIT(P, OUT) { \
    float bx1=sx1[P], by1=sy1[P], bx2=sx2[P], by2=sy2[P], ba=sar[P]; \
    float ltx = fmaxf(bx1, jx1), lty = fmaxf(by1, jy1); \
    float rbx = fminf(bx2, jx2), rby = fminf(by2, jy2); \
    float ww = fmaxf(__fsub_rn(rbx,ltx), 0.0f); \
    float hh = fmaxf(__fsub_rn(rby,lty), 0.0f); \
    float inter = __fmul_rn(ww,hh); \
    float uni = __fsub_rn(__fadd_rn(ba, ja), inter); \
    OUT = (__fdiv_rn(inter,uni) > 0.7f) && (j > (P)) && (j < PRE); }

  int p = q0;
  for (; p + 4 <= pm; p += 4){
    bool h0,h1,h2,h3;
    IOU_HIT(p,   h0);
    IOU_HIT(p+1, h1);
    IOU_HIT(p+2, h2);
    IOU_HIT(p+3, h3);
    unsigned long long b0 = __ballot(h0), b1 = __ballot(h1);
    unsigned long long b2 = __ballot(h2), b3 = __ballot(h3);
    if ((lane & 31) == 0){
      int d = lane >> 5;
      mg[(p  )*2 + d] = (lane==0) ? (unsigned)b0 : (unsigned)(b0>>32);
      mg[(p+1)*2 + d] = (lane==0) ? (unsigned)b1 : (unsigned)(b1>>32);
      mg[(p+2)*2 + d] = (lane==0) ? (unsigned)b2 : (unsigned)(b2>>32);
      mg[(p+3)*2 + d] = (lane==0) ? (unsigned)b3 : (unsigned)(b3>>32);
    }
  }
  for (; p < pm; ++p){
    bool h; IOU_HIT(p, h);
    unsigned long long bal = __ballot(h);
    if ((lane & 31) == 0)
      mg[p*2 + (lane>>5)] = (lane==0) ? (unsigned)bal : (unsigned)(bal>>32);
  }
#undef IOU_HIT
  int zs = (pm > q0 ? pm : q0);
  for (int w = zs*2 + lane; w < q1*2; w += 64) mg[w] = 0u;   // contiguous zero-fill
}

// ---------------- K6b: tile-parallel greedy scan, one wave per image ----------------
__global__ __launch_bounds__(64) void k_scan_nms4(const unsigned* rankinfo, const unsigned* lmat,
                                                  const float4* lbox, const float* lskey, float* out){
  __shared__ unsigned lrows[64][36];     // row-major tile; stride 36 words
  int n = blockIdx.x; int lane = threadIdx.x;
  int n5 = n*5;
  const unsigned* rin = rankinfo + (size_t)n*K_SEL;
  float* outn = out + (size_t)n*PRE*5;
  unsigned sup0=0u,sup1=0u,sup2=0u,sup3=0u,sup4=0u;
  int kept_total = 0;
  uint2 Pa,Pb,Pc,Pd,Pe,Pf,Pg,Ph,Pi,Pj,Pk,Pl,Pm,Pn,Po,Pp;  // 16x8B staging
  float4 boxP; float scP = 0.f;
  unsigned infoC, infoN;
  int rgrp = lane >> 4;                  // 0..3: row subgroup
  unsigned wboff = (unsigned)(lane & 15) * (2u*PRE);  // my wblk's column segment
  int wb2 = (lane & 15) << 1;            // word index within row

  // candidate (L,p) -> base word offset of its row's column entries: grp*GRPW + p*2
#define SLOAD(INFO) { \
    unsigned L_ = ((INFO)>>10)&7u; unsigned p_ = (INFO) & 1023u; \
    unsigned rowu_ = ((unsigned)n5 + L_)*GRPW + p_*2u; \
    unsigned rb_; \
    rb_ = __shfl(rowu_,  0 + rgrp); Pa = *(const uint2*)(lmat + rb_ + wboff); \
    rb_ = __shfl(rowu_,  4 + rgrp); Pb = *(const uint2*)(lmat + rb_ + wboff); \
    rb_ = __shfl(rowu_,  8 + rgrp); Pc = *(const uint2*)(lmat + rb_ + wboff); \
    rb_ = __shfl(rowu_, 12 + rgrp); Pd = *(const uint2*)(lmat + rb_ + wboff); \
    rb_ = __shfl(rowu_, 16 + rgrp); Pe = *(const uint2*)(lmat + rb_ + wboff); \
    rb_ = __shfl(rowu_, 20 + rgrp); Pf = *(const uint2*)(lmat + rb_ + wboff); \
    rb_ = __shfl(rowu_, 24 + rgrp); Pg = *(const uint2*)(lmat + rb_ + wboff); \
    rb_ = __shfl(rowu_, 28 + rgrp); Ph = *(const uint2*)(lmat + rb_ + wboff); \
    rb_ = __shfl(rowu_, 32 + rgrp); Pi = *(const uint2*)(lmat + rb_ + wboff); \
    rb_ = __shfl(rowu_, 36 + rgrp); Pj = *(const uint2*)(lmat + rb_ + wboff); \
    rb_ = __shfl(rowu_, 40 + rgrp); Pk = *(const uint2*)(lmat + rb_ + wboff); \
    rb_ = __shfl(rowu_, 44 + rgrp); Pl = *(const uint2*)(lmat + rb_ + wboff); \
    rb_ = __shfl(rowu_, 48 + rgrp); Pm = *(const uint2*)(lmat + rb_ + wboff); \
    rb_ = __shfl(rowu_, 52 + rgrp); Pn = *(const uint2*)(lmat + rb_ + wboff); \
    rb_ = __shfl(rowu_, 56 + rgrp); Po = *(const uint2*)(lmat + rb_ + wboff); \
    rb_ = __shfl(rowu_, 60 + rgrp); Pp = *(const uint2*)(lmat + rb_ + wboff); \
    size_t bi_ = (size_t)((unsigned)n5 + L_)*PRE + p_; \
    boxP = lbox[bi_]; scP = lskey[bi_]; }

#define SWRITE() { \
    *(uint2*)&lrows[ 0 + rgrp][wb2] = Pa; *(uint2*)&lrows[ 4 + rgrp][wb2] = Pb; \
    *(uint2*)&lrows[ 8 + rgrp][wb2] = Pc; *(uint2*)&lrows[12 + rgrp][wb2] = Pd; \
    *(uint2*)&lrows[16 + rgrp][wb2] = Pe; *(uint2*)&lrows[20 + rgrp][wb2] = Pf; \
    *(uint2*)&lrows[24 + rgrp][wb2] = Pg; *(uint2*)&lrows[28 + rgrp][wb2] = Ph; \
    *(uint2*)&lrows[32 + rgrp][wb2] = Pi; *(uint2*)&lrows[36 + rgrp][wb2] = Pj; \
    *(uint2*)&lrows[40 + rgrp][wb2] = Pk; *(uint2*)&lrows[44 + rgrp][wb2] = Pl; \
    *(uint2*)&lrows[48 + rgrp][wb2] = Pm; *(uint2*)&lrows[52 + rgrp][wb2] = Pn; \
    *(uint2*)&lrows[56 + rgrp][wb2] = Po; *(uint2*)&lrows[60 + rgrp][wb2] = Pp; }

#define TPROC(INFO, BOX, SC, baseexpr) { \
    int base_ = (baseexpr); \
    unsigned L_ = ((INFO)>>10)&7u; unsigned p_ = (INFO) & 1023u; \
    bool ok_ = ((((INFO)>>13)&1u) != 0u) && (base_ + lane < K_SEL); \
    int idxw_ = (int)(p_ >> 5); unsigned pb_ = p_ & 31u; \
    unsigned t0_=__shfl(sup0,idxw_), t1_=__shfl(sup1,idxw_), t2_=__shfl(sup2,idxw_), t3_=__shfl(sup3,idxw_), t4_=__shfl(sup4,idxw_); \
    unsigned sw_ = (L_==0u)?t0_:(L_==1u)?t1_:(L_==2u)?t2_:(L_==3u)?t3_:t4_; \
    bool pre_ = (!ok_) || (((sw_ >> pb_) & 1u) != 0u); \
    unsigned long long preM_ = __ballot(pre_); \
    unsigned cmlo_ = 0u, cmhi_ = 0u; \
    _Pragma("unroll") \
    for (int m_=0; m_<64; ++m_){ \
      unsigned infoM_ = __builtin_amdgcn_readlane((INFO), m_); \
      unsigned Lm_ = (infoM_>>10)&7u; \
      unsigned w_ = lrows[m_][idxw_]; \
      unsigned bit_ = ((w_ >> pb_) & 1u) & ((L_ == Lm_) ? 1u : 0u); \
      if (m_ < 32) cmlo_ |= bit_ << m_; else cmhi_ |= bit_ << (m_-32); \
    } \
    unsigned long long keptM_ = 0ull; \
    _Pragma("unroll") \
    for (int m_=0; m_<64; ++m_){ \
      unsigned long long cml_ = ((unsigned long long)__builtin_amdgcn_readlane(cmhi_, m_) << 32) \
                              |  (unsigned long long)__builtin_amdgcn_readlane(cmlo_, m_); \
      bool keep_ = (((preM_>>m_)&1ull) == 0ull) && ((cml_ & keptM_) == 0ull); \
      if (keep_) keptM_ |= (1ull<<m_); \
    } \
    unsigned myw_ = (unsigned)(lane & 31); \
    _Pragma("unroll") \
    for (int m_=0; m_<64; ++m_){ \
      if ((keptM_>>m_)&1ull){ \
        unsigned infoM_ = __builtin_amdgcn_readlane((INFO), m_); \
        unsigned Lm_ = (infoM_>>10)&7u; \
        unsigned rw_ = lrows[m_][myw_]; \
        switch(Lm_){ case 0u: sup0|=rw_; break; case 1u: sup1|=rw_; break; \
                     case 2u: sup2|=rw_; break; case 3u: sup3|=rw_; break; default: sup4|=rw_; } \
      } \
    } \
    int pos_ = kept_total + (int)__popcll(keptM_ & ((1ull<<lane)-1ull)); \
    if (((keptM_>>lane)&1ull) && pos_ < PRE){ \
      float* orow_ = outn + (size_t)pos_*5; \
      orow_[0]=(BOX).x; orow_[1]=(BOX).y; orow_[2]=(BOX).z; orow_[3]=(BOX).w; orow_[4]=(SC); \
    } \
    kept_total += (int)__popcll(keptM_); \
  }

  infoC = rin[lane];
  SLOAD(infoC);                          // tile 0 rows -> regs, box -> boxP
  SWRITE();                              // tile 0 rows -> LDS
  float4 boxC = boxP; float scC = scP;
  infoN = rin[64 + lane];

  for (int t = 0; t < TILES; ++t){
    if (t+1 < TILES) SLOAD(infoN);       // issue next tile's loads (rows + box)
    asm volatile("s_waitcnt lgkmcnt(0)" ::: "memory");   // lrows writes visible
    TPROC(infoC, boxC, scC, t*64);
    if (kept_total >= PRE) break;
    if (t+1 < TILES){
      SWRITE();                          // waits next tile's loads (covered by TPROC)
      boxC = boxP; scC = scP;
      infoC = infoN;
      if (t+2 < TILES){
        int nx = (t+2)*64 + lane; if (nx > K_SEL-1) nx = K_SEL-1;
        infoN = rin[nx];
      }
    }
  }
#undef SLOAD
#undef SWRITE
#undef TPROC
}

// ---------------- fallback path (ws too small): round-3 kernels ----------------
__global__ __launch_bounds__(256) void k_sortimg(const unsigned long long* keys,
                                                 const float* d0,const float* d1,const float* d2,const float* d3,const float* d4,
                                                 const float* anchors,
                                                 float4* sbox, float* sskey, int* slvl){
  int n = blockIdx.x;
  __shared__ unsigned long long sk[8192];
  for (int i = threadIdx.x; i < 8192; i += 256)
    sk[i] = (i < K_SEL) ? keys[(size_t)n*K_SEL + i] : ~0ULL;
  __syncthreads();
  bitonic<8192>(sk);
  for (int r = threadIdx.x; r < K_SEL; r += 256){
    unsigned long long key = sk[r];
    int t = (int)(key & 0x7FFFFu);
    int lvl = (int)((key >> 19) & 7u);
    unsigned se = ~((unsigned)(key >> 22));
    const float* dl = sel5(lvl,d0,d1,d2,d3,d4);
    BoxV b = decode_box(lvl, t, n, dl, anchors);
    sbox[(size_t)n*K_SEL + r] = make_float4(b.x1,b.y1,b.x2,b.y2);
    sskey[(size_t)n*K_SEL + r] = s2f(se);
    slvl[(size_t)n*K_SEL + r] = lvl;
  }
}

__global__ __launch_bounds__(256) void k_nms(const float4* sbox, const float* sskey, const int* slvl, float* out){
  int n = blockIdx.x, tid = threadIdx.x;
  __shared__ float kx1[PRE], ky1[PRE], kx2[PRE], ky2[PRE], kar[PRE];
  __shared__ int klv[PRE];
  __shared__ int nv_s, flag_s;
  for (int i = tid; i < PRE*5; i += 256) out[(size_t)n*PRE*5 + i] = 0.0f;
  if (tid == 0){ nv_s = 0; flag_s = 0; }
  __syncthreads();
  int c = 0;
  for (int i = tid; i < K_SEL; i += 256)
    if (sskey[(size_t)n*K_SEL + i] != -INFINITY) ++c;
  atomicAdd(&nv_s, c);
  __syncthreads();
  int nvalid = nv_s;
  int kept = 0;
  for (int i = 0; i < nvalid; ++i){
    float4 b = sbox[(size_t)n*K_SEL + i];
    int lv = slvl[(size_t)n*K_SEL + i];
    float off = (float)lv * 1345.0f;
    float ox1 = __fadd_rn(b.x, off), oy1 = __fadd_rn(b.y, off);
    float ox2 = __fadd_rn(b.z, off), oy2 = __fadd_rn(b.w, off);
    float area = __fmul_rn(__fsub_rn(ox2,ox1), __fsub_rn(oy2,oy1));
    bool hit = false;
    for (int j = tid; j < kept; j += 256){
      if (klv[j] == lv){
        float ltx = fmaxf(kx1[j], ox1), lty = fmaxf(ky1[j], oy1);
        float rbx = fminf(kx2[j], ox2), rby = fminf(ky2[j], oy2);
        float w = fmaxf(__fsub_rn(rbx,ltx), 0.0f);
        float h = fmaxf(__fsub_rn(rby,lty), 0.0f);
        float inter = __fmul_rn(w,h);
        float uni = __fsub_rn(__fadd_rn(kar[j], area), inter);
        if (__fdiv_rn(inter,uni) > 0.7f) hit = true;
      }
    }
    if (hit) flag_s = 1;
    __syncthreads();
    int sup = flag_s;
    __syncthreads();
    if (!sup){
      if (tid == 0){
        kx1[kept]=ox1; ky1[kept]=oy1; kx2[kept]=ox2; ky2[kept]=oy2; kar[kept]=area; klv[kept]=lv;
        float* orow = out + (size_t)n*PRE*5 + (size_t)kept*5;
        orow[0]=b.x; orow[1]=b.y; orow[2]=b.z; orow[3]=b.w;
        orow[4]=sskey[(size_t)n*K_SEL + i];
      }
      ++kept;
    }
    if (tid == 0) flag_s = 0;
    __syncthreads();
    if (kept == PRE) break;
  }
}

extern "C" void kernel_launch(void* const* d_in, const int* in_sizes, int n_in,
                              void* d_out, int out_size, void* d_ws, size_t ws_size,
                              hipStream_t stream) {
  bool interleaved = (in_sizes[1] == 4*in_sizes[0]);
  const float* obj[5]; const float* dlt[5];
  for (int i = 0; i < 5; ++i){
    if (interleaved){ obj[i] = (const float*)d_in[2*i]; dlt[i] = (const float*)d_in[2*i+1]; }
    else            { obj[i] = (const float*)d_in[i];   dlt[i] = (const float*)d_in[5+i]; }
  }
  const float* anchors = (const float*)d_in[10];

  char* ws = (char*)d_ws;
  unsigned* hist            = (unsigned*)(ws);                     // 655360
  unsigned* cnt_gt          = (unsigned*)(ws + 655360);            // 160
  unsigned* cnt_eq          = (unsigned*)(ws + 655520);            // 160
  unsigned* thi             = (unsigned*)(ws + 655680);            // 160 -> counters end 655840
  unsigned long long* cand  = (unsigned long long*)(ws + 655840);  // 1310720 -> 1966560
  unsigned long long* keys  = (unsigned long long*)(ws + 1966560); // 320000 -> 2286560
  float4* lbox              = (float4*)(ws + 2286560);             // 640000 -> 2926560
  float4* lobox             = (float4*)(ws + 2926560);             // 640000 -> 3566560
  float* loarea             = (float*)(ws + 3566560);              // 160000 -> 3726560
  float* lskey              = (float*)(ws + 3726560);              // 160000 -> 3886560
  unsigned* rankinfo        = (unsigned*)(ws + 3886560);           // 160000 -> 4046560
  unsigned* lmat            = (unsigned*)(ws + 4046560);           // 5120000 -> 9166560
  float4* sbox              = (float4*)(ws + 9166560);             // fallback: 640000 -> 9806560
  float* sskey              = (float*)(ws + 9806560);              // 160000 -> 9966560
  int* slvl                 = (int*)(ws + 9966560);                // 160000 -> 10126560
  const size_t NEED = 10126560;

  hipMemsetAsync(ws, 0, 655840, stream);   // hist + counters

  dim3 gScan(8, 40);
  k_hist<<<gScan, 256, 0, stream>>>(obj[0],obj[1],obj[2],obj[3],obj[4], hist);
  k_scan<<<40, 256, 0, stream>>>(hist, thi);
  k_compact<<<gScan, 256, 0, stream>>>(obj[0],obj[1],obj[2],obj[3],obj[4],
                                       dlt[0],dlt[1],dlt[2],dlt[3],dlt[4],
                                       anchors, thi, cnt_gt, cnt_eq, cand, keys);
  k_tiesel<<<40, 256, 0, stream>>>(dlt[0],dlt[1],dlt[2],dlt[3],dlt[4], anchors,
                                   cnt_gt, cnt_eq, cand, keys);
  if (ws_size >= NEED){
    k_sortlvl<<<40, 256, 0, stream>>>(keys, dlt[0],dlt[1],dlt[2],dlt[3],dlt[4], anchors,
                                      lbox, lobox, loarea, lskey);
    k_rank<<<40, 256, 0, stream>>>(keys, rankinfo);
    k_ioumat_lvl<<<dim3(16, 40), 256, 0, stream>>>(lobox, loarea, lmat);
    hipMemsetAsync(d_out, 0, (size_t)out_size*sizeof(float), stream);
    k_scan_nms4<<<8, 64, 0, stream>>>(rankinfo, lmat, lbox, lskey, (float*)d_out);
  } else {
    k_sortimg<<<8, 256, 0, stream>>>(keys, dlt[0],dlt[1],dlt[2],dlt[3],dlt[4], anchors,
                                     sbox, sskey, slvl);
    k_nms<<<8, 256, 0, stream>>>(sbox, sskey, slvl, (float*)d_out);
  }
}

// Round 11
// 418.038 us; speedup vs baseline: 1.5405x; 1.2717x over previous
//
#include <hip/hip_runtime.h>
#include <cmath>

#define N_IMG   8
#define PRE     1000
#define K_SEL   5000
#define NBIN    4096
#define TIE_CAP 4096
#define IMG_F   1344.0f
#define S_NEGINF 0x007FFFFFu
#define TILES   79             // ceil(5000/64)
#define GRPW    32000          // words per grp in lmat: 16 wblk x 1000 p x 2

__constant__ int c_W[5]   = {336,168,84,42,21};
__constant__ int c_HW[5]  = {112896,28224,7056,1764,441};
__constant__ int c_OFF[5] = {0,338688,423360,444528,449820};

__device__ __forceinline__ unsigned f2s(float f){
  unsigned u = __float_as_uint(f);
  return (u & 0x80000000u) ? ~u : (u | 0x80000000u);
}
__device__ __forceinline__ float s2f(unsigned s){
  unsigned u = (s & 0x80000000u) ? (s & 0x7FFFFFFFu) : ~s;
  return __uint_as_float(u);
}
__device__ __forceinline__ const float* sel5(int l, const float* p0,const float* p1,const float* p2,const float* p3,const float* p4){
  switch(l){case 0:return p0;case 1:return p1;case 2:return p2;case 3:return p3;default:return p4;}
}

struct BoxV { float x1,y1,x2,y2; bool valid; };

// Bit-faithful torchvision BoxCoder.decode + clip + min-size validity.
__device__ BoxV decode_box(int lvl, int t, int n, const float* dl, const float* anchors){
  int HW = c_HW[lvl], W = c_W[lvl];
  int a = t % 3, pos = t / 3;          // t = (h*W+w)*3 + a
  int h = pos / W, w = pos - h*W;
  int g = c_OFF[lvl] + t;
  const float* an = anchors + (size_t)4*(size_t)g;
  float a0=an[0], a1=an[1], a2=an[2], a3=an[3];
  float aw = __fsub_rn(a2,a0), ah = __fsub_rn(a3,a1);
  float acx = __fadd_rn(a0, __fmul_rn(0.5f,aw));
  float acy = __fadd_rn(a1, __fmul_rn(0.5f,ah));
  const float* dp = dl + ((size_t)n*12 + (size_t)a*4)*(size_t)HW + (size_t)h*W + (size_t)w;
  float dx = dp[0], dy = dp[HW], dwv = dp[2*(size_t)HW], dhv = dp[3*(size_t)HW];
  const float CLAMP = (float)4.135166556742356;  // log(1000/16)
  dwv = fminf(dwv, CLAMP); dhv = fminf(dhv, CLAMP);
  float pcx = __fadd_rn(__fmul_rn(dx,aw), acx);
  float pcy = __fadd_rn(__fmul_rn(dy,ah), acy);
  float pw = __fmul_rn((float)::exp((double)dwv), aw);
  float ph = __fmul_rn((float)::exp((double)dhv), ah);
  float hx = __fmul_rn(0.5f,pw), hy = __fmul_rn(0.5f,ph);
  BoxV b;
  b.x1 = fminf(fmaxf(__fsub_rn(pcx,hx),0.0f),IMG_F);
  b.y1 = fminf(fmaxf(__fsub_rn(pcy,hy),0.0f),IMG_F);
  b.x2 = fminf(fmaxf(__fadd_rn(pcx,hx),0.0f),IMG_F);
  b.y2 = fminf(fmaxf(__fadd_rn(pcy,hy),0.0f),IMG_F);
  b.valid = (__fsub_rn(b.x2,b.x1) >= 1e-3f) && (__fsub_rn(b.y2,b.y1) >= 1e-3f);
  return b;
}

// key = (~s_eff)<<22 | lvl<<19 | t : ascending sort == (score desc, level asc, idx asc)
__device__ unsigned long long make_key(unsigned s, int lvl, int t, int n, const float* dl, const float* anchors){
  BoxV b = decode_box(lvl,t,n,dl,anchors);
  unsigned se = b.valid ? s : S_NEGINF;     // invalid -> skey = -inf
  return ((unsigned long long)(~se) << 22) | ((unsigned long long)(unsigned)lvl << 19) | (unsigned long long)(unsigned)t;
}

// ---------------- K1: per-(image,level) 12-bit score histogram ----------------
__global__ __launch_bounds__(256) void k_hist(const float* o0,const float* o1,const float* o2,const float* o3,const float* o4,
                                              unsigned* hist){
  int grp = blockIdx.y; int n = grp/5, lvl = grp - n*5;
  const float* ob = sel5(lvl,o0,o1,o2,o3,o4);
  int HW = c_HW[lvl], M = 3*HW;
  ob += (size_t)n*(size_t)M;
  __shared__ unsigned lh[NBIN];
  for (int b = threadIdx.x; b < NBIN; b += 256) lh[b] = 0;
  __syncthreads();
  int stride = gridDim.x*256;
  for (int i = blockIdx.x*256 + threadIdx.x; i < M; i += stride){
    unsigned s = f2s(ob[i]);
    atomicAdd(&lh[s >> 20], 1u);
  }
  __syncthreads();
  unsigned* gh = hist + (size_t)grp*NBIN;
  for (int b = threadIdx.x; b < NBIN; b += 256){ unsigned v = lh[b]; if (v) atomicAdd(&gh[b], v); }
}

// ---------------- K2: find bin containing the 1000th-largest score ----------------
__global__ __launch_bounds__(256) void k_scan(const unsigned* hist, unsigned* thi){
  int grp = blockIdx.x;
  const unsigned* gh = hist + (size_t)grp*NBIN;
  __shared__ unsigned part[256];
  unsigned ssum = 0;
  int base = threadIdx.x*16;
  for (int b = base; b < base+16; ++b) ssum += gh[b];
  part[threadIdx.x] = ssum;
  __syncthreads();
  if (threadIdx.x == 0){
    int k = PRE;
    int c = 255;
    while ((int)part[c] < k){ k -= (int)part[c]; --c; }
    int b = c*16 + 15;
    while ((int)gh[b] < k){ k -= (int)gh[b]; --b; }
    thi[grp] = (unsigned)b;
  }
}

// ---------------- K3: compact >bin elements (decode+key), collect ==bin candidates ----------------
__global__ __launch_bounds__(256) void k_compact(const float* o0,const float* o1,const float* o2,const float* o3,const float* o4,
                                                 const float* d0,const float* d1,const float* d2,const float* d3,const float* d4,
                                                 const float* anchors, const unsigned* thi,
                                                 unsigned* cnt_gt, unsigned* cnt_eq,
                                                 unsigned long long* cand, unsigned long long* keys){
  int grp = blockIdx.y; int n = grp/5, lvl = grp - n*5;
  const float* ob = sel5(lvl,o0,o1,o2,o3,o4);
  const float* dl = sel5(lvl,d0,d1,d2,d3,d4);
  int HW = c_HW[lvl], M = 3*HW;
  ob += (size_t)n*(size_t)M;
  unsigned T = thi[grp];
  unsigned long long* kout = keys + (size_t)n*K_SEL + (size_t)lvl*PRE;
  int stride = gridDim.x*256;
  for (int i = blockIdx.x*256 + threadIdx.x; i < M; i += stride){
    unsigned s = f2s(ob[i]);
    unsigned sh = s >> 20;
    if (sh > T){
      unsigned pos = atomicAdd(&cnt_gt[grp], 1u);
      int a = i / HW; int rem = i - a*HW; int t = rem*3 + a;
      kout[pos] = make_key(s, lvl, t, n, dl, anchors);
    } else if (sh == T){
      unsigned e = atomicAdd(&cnt_eq[grp], 1u);
      if (e < TIE_CAP){
        int a = i / HW; int rem = i - a*HW; int t = rem*3 + a;
        cand[(size_t)grp*TIE_CAP + e] = ((unsigned long long)(~s) << 19) | (unsigned long long)(unsigned)t;
      }
    }
  }
}

template<int SZ>
__device__ void bitonic(unsigned long long* sk){
  for (int k = 2; k <= SZ; k <<= 1){
    for (int j = k >> 1; j > 0; j >>= 1){
      for (int i = threadIdx.x; i < SZ; i += blockDim.x){
        int ix = i ^ j;
        if (ix > i){
          unsigned long long va = sk[i], vb = sk[ix];
          if ((va > vb) == ((i & k) == 0)){ sk[i] = vb; sk[ix] = va; }
        }
      }
      __syncthreads();
    }
  }
}

// runtime-sized bitonic (SZ uniform across block, power of 2)
__device__ void bitonic_rt(unsigned long long* sk, int SZ){
  for (int k = 2; k <= SZ; k <<= 1){
    for (int j = k >> 1; j > 0; j >>= 1){
      for (int i = threadIdx.x; i < SZ; i += blockDim.x){
        int ix = i ^ j;
        if (ix > i){
          unsigned long long va = sk[i], vb = sk[ix];
          if ((va > vb) == ((i & k) == 0)){ sk[i] = vb; sk[ix] = va; }
        }
      }
      __syncthreads();
    }
  }
}

// ---------------- K4: exact boundary selection within the threshold bin ----------------
__global__ __launch_bounds__(256) void k_tiesel(const float* d0,const float* d1,const float* d2,const float* d3,const float* d4,
                                                const float* anchors,
                                                const unsigned* cnt_gt, const unsigned* cnt_eq,
                                                const unsigned long long* cand, unsigned long long* keys){
  int grp = blockIdx.x; int n = grp/5, lvl = grp - n*5;
  __shared__ unsigned long long sk[TIE_CAP];
  int ne = min((int)cnt_eq[grp], TIE_CAP);
  int SZ = 64; while (SZ < ne) SZ <<= 1;    // runtime pow2 >= ne (uniform)
  for (int i = threadIdx.x; i < SZ; i += 256)
    sk[i] = (i < ne) ? cand[(size_t)grp*TIE_CAP + i] : ~0ULL;
  __syncthreads();
  bitonic_rt(sk, SZ);                // ascending: (score desc, idx asc)
  int cg = (int)cnt_gt[grp];
  int need = PRE - cg;
  const float* dl = sel5(lvl,d0,d1,d2,d3,d4);
  unsigned long long* kout = keys + (size_t)n*K_SEL + (size_t)lvl*PRE + cg;
  for (int j = threadIdx.x; j < need; j += 256){
    if (j < ne){
      unsigned long long ck = sk[j];
      unsigned t = (unsigned)(ck & 0x7FFFFu);
      unsigned s = ~((unsigned)(ck >> 19));
      kout[j] = make_key(s, lvl, (int)t, n, dl, anchors);
    } else {
      kout[j] = ((unsigned long long)(~S_NEGINF) << 22); // pathological overflow: harmless invalid
    }
  }
}

// ---------------- K5a: sort each (image,level) run; decode level-space arrays ----------------
__global__ __launch_bounds__(256) void k_sortlvl(unsigned long long* keys,
                                                 const float* d0,const float* d1,const float* d2,const float* d3,const float* d4,
                                                 const float* anchors,
                                                 float4* lbox, float4* lobox, float* loarea, float* lskey){
  int grp = blockIdx.x; int n = grp/5, lvl = grp - n*5;
  __shared__ unsigned long long sk[1024];
  unsigned long long* kp = keys + (size_t)n*K_SEL + (size_t)lvl*PRE;
  for (int i = threadIdx.x; i < 1024; i += 256)
    sk[i] = (i < PRE) ? kp[i] : ~0ULL;
  __syncthreads();
  bitonic<1024>(sk);
  const float* dl = sel5(lvl,d0,d1,d2,d3,d4);
  for (int i = threadIdx.x; i < PRE; i += 256){
    unsigned long long key = sk[i];
    kp[i] = key;                          // sorted run back to global (k_rank reads it)
    int t = (int)(key & 0x7FFFFu);
    unsigned se = ~((unsigned)(key >> 22));
    BoxV b = decode_box(lvl, t, n, dl, anchors);
    size_t o = (size_t)grp*PRE + i;
    lbox[o] = make_float4(b.x1,b.y1,b.x2,b.y2);
    lskey[o] = s2f(se);                   // -inf if invalid
    float off = (float)lvl * 1345.0f;     // (IMG+1) batched-NMS offset
    float ox1 = __fadd_rn(b.x1, off), oy1 = __fadd_rn(b.y1, off);
    float ox2 = __fadd_rn(b.x2, off), oy2 = __fadd_rn(b.y2, off);
    lobox[o] = make_float4(ox1,oy1,ox2,oy2);
    loarea[o] = __fmul_rn(__fsub_rn(ox2,ox1), __fsub_rn(oy2,oy1));
  }
}

// ---------------- K5b: global rank of each level element (keys globally unique) ----------------
// rankinfo[rank] = p | (lvl<<10) | (valid<<13)
__global__ __launch_bounds__(256) void k_rank(const unsigned long long* keys, unsigned* rankinfo){
  int grp = blockIdx.x; int n = grp/5, lvl = grp - n*5;
  __shared__ unsigned long long sl[K_SEL];
  for (int i = threadIdx.x; i < K_SEL; i += 256) sl[i] = keys[(size_t)n*K_SEL + i];
  __syncthreads();
  for (int j = threadIdx.x; j < PRE; j += 256){
    unsigned long long k = sl[lvl*PRE + j];
    int rank = j;
    #pragma unroll
    for (int m = 0; m < 5; ++m){
      if (m == lvl) continue;
      const unsigned long long* s = sl + m*PRE;
      int lo = 0, hi = PRE;
      while (lo < hi){ int mid = (lo+hi) >> 1; if (s[mid] < k) lo = mid+1; else hi = mid; }
      rank += lo;
    }
    unsigned se = ~((unsigned)(k >> 22));
    unsigned info = (unsigned)j | ((unsigned)lvl << 10) | ((se != S_NEGINF) ? (1u<<13) : 0u);
    rankinfo[(size_t)n*K_SEL + rank] = info;   // exact permutation of [0,5000)
  }
}

// ---------------- K6a: suppression bit-matrix, ballot + column layout, 4 waves/block ----------------
__global__ __launch_bounds__(256) void k_ioumat_lvl(const float4* lobox, const float* loarea, unsigned* lmat){
  int grp = blockIdx.y;                  // n*5 + L
  int wblk = blockIdx.x;                 // j-block: j = wblk*64 + lane
  int tid = threadIdx.x;
  int lane = tid & 63, q = tid >> 6;
  __shared__ float sx1[PRE], sy1[PRE], sx2[PRE], sy2[PRE], sar[PRE];
  for (int i = tid; i < PRE; i += 256){
    float4 bb = lobox[(size_t)grp*PRE + i];
    sx1[i]=bb.x; sy1[i]=bb.y; sx2[i]=bb.z; sy2[i]=bb.w;
    sar[i]=loarea[(size_t)grp*PRE + i];
  }
  __syncthreads();
  int j = wblk*64 + lane;
  float jx1=0.f,jy1=0.f,jx2=0.f,jy2=0.f,ja=0.f;
  if (j < PRE){
    float4 bb = lobox[(size_t)grp*PRE + j];
    jx1=bb.x; jy1=bb.y; jx2=bb.z; jy2=bb.w; ja=loarea[(size_t)grp*PRE + j];
  }
  unsigned* mg = lmat + (size_t)grp*GRPW + (size_t)wblk*2*PRE;
  int pmax = min(PRE, wblk*64 + 63);     // rows p >= pmax: no j>p in this block
  int q0 = q*250, q1 = q0 + 250;
  int pm = min(q1, pmax);

#define IOU_HIT(P, OUT) { \
    float bx1=sx1[P], by1=sy1[P], bx2=sx2[P], by2=sy2[P], ba=sar[P]; \
    float ltx = fmaxf(bx1, jx1), lty = fmaxf(by1, jy1); \
    float rbx = fminf(bx2, jx2), rby = fminf(by2, jy2); \
    float ww = fmaxf(__fsub_rn(rbx,ltx), 0.0f); \
    float hh = fmaxf(__fsub_rn(rby,lty), 0.0f); \
    float inter = __fmul_rn(ww,hh); \
    float uni = __fsub_rn(__fadd_rn(ba, ja), inter); \
    OUT = (__fdiv_rn(inter,uni) > 0.7f) && (j > (P)) && (j < PRE); }

  int p = q0;
  for (; p + 4 <= pm; p += 4){
    bool h0,h1,h2,h3;
    IOU_HIT(p,   h0);
    IOU_HIT(p+1, h1);
    IOU_HIT(p+2, h2);
    IOU_HIT(p+3, h3);
    unsigned long long b0 = __ballot(h0), b1 = __ballot(h1);
    unsigned long long b2 = __ballot(h2), b3 = __ballot(h3);
    if ((lane & 31) == 0){
      int d = lane >> 5;
      mg[(p  )*2 + d] = (lane==0) ? (unsigned)b0 : (unsigned)(b0>>32);
      mg[(p+1)*2 + d] = (lane==0) ? (unsigned)b1 : (unsigned)(b1>>32);
      mg[(p+2)*2 + d] = (lane==0) ? (unsigned)b2 : (unsigned)(b2>>32);
      mg[(p+3)*2 + d] = (lane==0) ? (unsigned)b3 : (unsigned)(b3>>32);
    }
  }
  for (; p < pm; ++p){
    bool h; IOU_HIT(p, h);
    unsigned long long bal = __ballot(h);
    if ((lane & 31) == 0)
      mg[p*2 + (lane>>5)] = (lane==0) ? (unsigned)bal : (unsigned)(bal>>32);
  }
#undef IOU_HIT
  int zs = (pm > q0 ? pm : q0);
  for (int w = zs*2 + lane; w < q1*2; w += 64) mg[w] = 0u;   // contiguous zero-fill
}

// ---------------- K6b: tile-parallel greedy scan, latency-batched TPROC ----------------
// Loop1: 4x16 named-temp batched ds_reads (forces 16 in flight). Loop2: parallel
// greedy rounds (ballots), exact sequential-greedy equivalent since conflict edges
// only point rank-upward. Loop3: sup state in LDS; kept lanes OR their OWN row via
// lane-rotated atomicOr (bank-conflict-free, no branchy gathers).
__global__ __launch_bounds__(64) void k_scan_nms5(const unsigned* rankinfo, const unsigned* lmat,
                                                  const float4* lbox, const float* lskey, float* out){
  __shared__ unsigned lrows[64][36];     // row-major tile; stride 36 words
  __shared__ unsigned lsup[160];         // 5 levels x 32 words suppression state
  int n = blockIdx.x; int lane = threadIdx.x;
  int n5 = n*5;
  const unsigned* rin = rankinfo + (size_t)n*K_SEL;
  float* outn = out + (size_t)n*PRE*5;
  for (int i = lane; i < 160; i += 64) lsup[i] = 0u;
  int kept_total = 0;
  uint2 Pa,Pb,Pc,Pd,Pe,Pf,Pg,Ph,Pi,Pj,Pk,Pl,Pm,Pn,Po,Pp;  // 16x8B staging
  float4 boxP; float scP = 0.f;
  unsigned infoC, infoN;
  int rgrp = lane >> 4;                  // 0..3: row subgroup
  unsigned wboff = (unsigned)(lane & 15) * (2u*PRE);  // my wblk's column segment
  int wb2 = (lane & 15) << 1;            // word index within row

#define SLOAD(INFO) { \
    unsigned L_ = ((INFO)>>10)&7u; unsigned p_ = (INFO) & 1023u; \
    unsigned rowu_ = ((unsigned)n5 + L_)*GRPW + p_*2u; \
    unsigned rb_; \
    rb_ = __shfl(rowu_,  0 + rgrp); Pa = *(const uint2*)(lmat + rb_ + wboff); \
    rb_ = __shfl(rowu_,  4 + rgrp); Pb = *(const uint2*)(lmat + rb_ + wboff); \
    rb_ = __shfl(rowu_,  8 + rgrp); Pc = *(const uint2*)(lmat + rb_ + wboff); \
    rb_ = __shfl(rowu_, 12 + rgrp); Pd = *(const uint2*)(lmat + rb_ + wboff); \
    rb_ = __shfl(rowu_, 16 + rgrp); Pe = *(const uint2*)(lmat + rb_ + wboff); \
    rb_ = __shfl(rowu_, 20 + rgrp); Pf = *(const uint2*)(lmat + rb_ + wboff); \
    rb_ = __shfl(rowu_, 24 + rgrp); Pg = *(const uint2*)(lmat + rb_ + wboff); \
    rb_ = __shfl(rowu_, 28 + rgrp); Ph = *(const uint2*)(lmat + rb_ + wboff); \
    rb_ = __shfl(rowu_, 32 + rgrp); Pi = *(const uint2*)(lmat + rb_ + wboff); \
    rb_ = __shfl(rowu_, 36 + rgrp); Pj = *(const uint2*)(lmat + rb_ + wboff); \
    rb_ = __shfl(rowu_, 40 + rgrp); Pk = *(const uint2*)(lmat + rb_ + wboff); \
    rb_ = __shfl(rowu_, 44 + rgrp); Pl = *(const uint2*)(lmat + rb_ + wboff); \
    rb_ = __shfl(rowu_, 48 + rgrp); Pm = *(const uint2*)(lmat + rb_ + wboff); \
    rb_ = __shfl(rowu_, 52 + rgrp); Pn = *(const uint2*)(lmat + rb_ + wboff); \
    rb_ = __shfl(rowu_, 56 + rgrp); Po = *(const uint2*)(lmat + rb_ + wboff); \
    rb_ = __shfl(rowu_, 60 + rgrp); Pp = *(const uint2*)(lmat + rb_ + wboff); \
    size_t bi_ = (size_t)((unsigned)n5 + L_)*PRE + p_; \
    boxP = lbox[bi_]; scP = lskey[bi_]; }

#define SWRITE() { \
    *(uint2*)&lrows[ 0 + rgrp][wb2] = Pa; *(uint2*)&lrows[ 4 + rgrp][wb2] = Pb; \
    *(uint2*)&lrows[ 8 + rgrp][wb2] = Pc; *(uint2*)&lrows[12 + rgrp][wb2] = Pd; \
    *(uint2*)&lrows[16 + rgrp][wb2] = Pe; *(uint2*)&lrows[20 + rgrp][wb2] = Pf; \
    *(uint2*)&lrows[24 + rgrp][wb2] = Pg; *(uint2*)&lrows[28 + rgrp][wb2] = Ph; \
    *(uint2*)&lrows[32 + rgrp][wb2] = Pi; *(uint2*)&lrows[36 + rgrp][wb2] = Pj; \
    *(uint2*)&lrows[40 + rgrp][wb2] = Pk; *(uint2*)&lrows[44 + rgrp][wb2] = Pl; \
    *(uint2*)&lrows[48 + rgrp][wb2] = Pm; *(uint2*)&lrows[52 + rgrp][wb2] = Pn; \
    *(uint2*)&lrows[56 + rgrp][wb2] = Po; *(uint2*)&lrows[60 + rgrp][wb2] = Pp; }

#define GRP16(B, ACC, SH) { \
    unsigned q0_=lrows[(B)+ 0][idxw_], q1_=lrows[(B)+ 1][idxw_], \
             q2_=lrows[(B)+ 2][idxw_], q3_=lrows[(B)+ 3][idxw_], \
             q4_=lrows[(B)+ 4][idxw_], q5_=lrows[(B)+ 5][idxw_], \
             q6_=lrows[(B)+ 6][idxw_], q7_=lrows[(B)+ 7][idxw_], \
             q8_=lrows[(B)+ 8][idxw_], q9_=lrows[(B)+ 9][idxw_], \
             qa_=lrows[(B)+10][idxw_], qb_=lrows[(B)+11][idxw_], \
             qc_=lrows[(B)+12][idxw_], qd_=lrows[(B)+13][idxw_], \
             qe_=lrows[(B)+14][idxw_], qf_=lrows[(B)+15][idxw_]; \
    ACC |= (((q0_>>pb_)&1u)<<((SH)+ 0)) | (((q1_>>pb_)&1u)<<((SH)+ 1)) \
         | (((q2_>>pb_)&1u)<<((SH)+ 2)) | (((q3_>>pb_)&1u)<<((SH)+ 3)) \
         | (((q4_>>pb_)&1u)<<((SH)+ 4)) | (((q5_>>pb_)&1u)<<((SH)+ 5)) \
         | (((q6_>>pb_)&1u)<<((SH)+ 6)) | (((q7_>>pb_)&1u)<<((SH)+ 7)) \
         | (((q8_>>pb_)&1u)<<((SH)+ 8)) | (((q9_>>pb_)&1u)<<((SH)+ 9)) \
         | (((qa_>>pb_)&1u)<<((SH)+10)) | (((qb_>>pb_)&1u)<<((SH)+11)) \
         | (((qc_>>pb_)&1u)<<((SH)+12)) | (((qd_>>pb_)&1u)<<((SH)+13)) \
         | (((qe_>>pb_)&1u)<<((SH)+14)) | (((qf_>>pb_)&1u)<<((SH)+15)); }

#define TPROC(INFO, BOX, SC, baseexpr) { \
    int base_ = (baseexpr); \
    unsigned L_ = ((INFO)>>10)&7u; unsigned p_ = (INFO) & 1023u; \
    int idxw_ = (int)(p_ >> 5); unsigned pb_ = p_ & 31u; \
    unsigned long long lb0_=__ballot(L_==0u), lb1_=__ballot(L_==1u), \
                       lb2_=__ballot(L_==2u), lb3_=__ballot(L_==3u), lb4_=__ballot(L_==4u); \
    unsigned long long myLvl_ = (L_==0u)?lb0_:(L_==1u)?lb1_:(L_==2u)?lb2_:(L_==3u)?lb3_:lb4_; \
    unsigned sw_ = lsup[L_*32u + (unsigned)idxw_]; \
    bool ok_ = ((((INFO)>>13)&1u)!=0u) && (base_ + lane < K_SEL) && (((sw_>>pb_)&1u)==0u); \
    unsigned long long cand_ = __ballot(ok_); \
    unsigned alo_ = 0u, ahi_ = 0u; \
    GRP16( 0, alo_,  0); GRP16(16, alo_, 16); \
    GRP16(32, ahi_,  0); GRP16(48, ahi_, 16); \
    unsigned long long cm_ = ((((unsigned long long)ahi_)<<32)|(unsigned long long)alo_) & myLvl_; \
    unsigned long long keptM_ = 0ull; \
    while (cand_){ \
      bool safe_ = (((cand_>>lane)&1ull)!=0ull) && ((cm_ & cand_)==0ull); \
      unsigned long long nk_ = __ballot(safe_); \
      keptM_ |= nk_; \
      bool dead_ = (((cand_>>lane)&1ull)!=0ull) && ((cm_ & nk_)!=0ull); \
      cand_ &= ~(nk_ | __ballot(dead_)); \
    } \
    if (((keptM_>>lane)&1ull)!=0ull){ \
      unsigned sb_ = L_*32u; \
      _Pragma("unroll") \
      for (int k_ = 0; k_ < 32; ++k_){ \
        unsigned w_ = (unsigned)((k_+lane)&31); \
        atomicOr(&lsup[sb_+w_], lrows[lane][w_]); \
      } \
    } \
    int pos_ = kept_total + (int)__popcll(keptM_ & ((1ull<<lane)-1ull)); \
    if ((((keptM_>>lane)&1ull)!=0ull) && pos_ < PRE){ \
      float* orow_ = outn + (size_t)pos_*5; \
      orow_[0]=(BOX).x; orow_[1]=(BOX).y; orow_[2]=(BOX).z; orow_[3]=(BOX).w; orow_[4]=(SC); \
    } \
    kept_total += (int)__popcll(keptM_); \
    asm volatile("s_waitcnt lgkmcnt(0)" ::: "memory"); \
  }

  infoC = rin[lane];
  SLOAD(infoC);                          // tile 0 rows -> regs, box -> boxP
  SWRITE();                              // tile 0 rows -> LDS
  float4 boxC = boxP; float scC = scP;
  infoN = rin[64 + lane];

  for (int t = 0; t < TILES; ++t){
    if (t+1 < TILES) SLOAD(infoN);       // issue next tile's loads (rows + box)
    asm volatile("s_waitcnt lgkmcnt(0)" ::: "memory");   // lrows writes visible
    TPROC(infoC, boxC, scC, t*64);
    if (kept_total >= PRE) break;
    if (t+1 < TILES){
      SWRITE();                          // waits next tile's loads (covered by TPROC)
      boxC = boxP; scC = scP;
      infoC = infoN;
      if (t+2 < TILES){
        int nx = (t+2)*64 + lane; if (nx > K_SEL-1) nx = K_SEL-1;
        infoN = rin[nx];
      }
    }
  }
#undef SLOAD
#undef SWRITE
#undef GRP16
#undef TPROC
}

// ---------------- fallback path (ws too small): round-3 kernels ----------------
__global__ __launch_bounds__(256) void k_sortimg(const unsigned long long* keys,
                                                 const float* d0,const float* d1,const float* d2,const float* d3,const float* d4,
                                                 const float* anchors,
                                                 float4* sbox, float* sskey, int* slvl){
  int n = blockIdx.x;
  __shared__ unsigned long long sk[8192];
  for (int i = threadIdx.x; i < 8192; i += 256)
    sk[i] = (i < K_SEL) ? keys[(size_t)n*K_SEL + i] : ~0ULL;
  __syncthreads();
  bitonic<8192>(sk);
  for (int r = threadIdx.x; r < K_SEL; r += 256){
    unsigned long long key = sk[r];
    int t = (int)(key & 0x7FFFFu);
    int lvl = (int)((key >> 19) & 7u);
    unsigned se = ~((unsigned)(key >> 22));
    const float* dl = sel5(lvl,d0,d1,d2,d3,d4);
    BoxV b = decode_box(lvl, t, n, dl, anchors);
    sbox[(size_t)n*K_SEL + r] = make_float4(b.x1,b.y1,b.x2,b.y2);
    sskey[(size_t)n*K_SEL + r] = s2f(se);
    slvl[(size_t)n*K_SEL + r] = lvl;
  }
}

__global__ __launch_bounds__(256) void k_nms(const float4* sbox, const float* sskey, const int* slvl, float* out){
  int n = blockIdx.x, tid = threadIdx.x;
  __shared__ float kx1[PRE], ky1[PRE], kx2[PRE], ky2[PRE], kar[PRE];
  __shared__ int klv[PRE];
  __shared__ int nv_s, flag_s;
  for (int i = tid; i < PRE*5; i += 256) out[(size_t)n*PRE*5 + i] = 0.0f;
  if (tid == 0){ nv_s = 0; flag_s = 0; }
  __syncthreads();
  int c = 0;
  for (int i = tid; i < K_SEL; i += 256)
    if (sskey[(size_t)n*K_SEL + i] != -INFINITY) ++c;
  atomicAdd(&nv_s, c);
  __syncthreads();
  int nvalid = nv_s;
  int kept = 0;
  for (int i = 0; i < nvalid; ++i){
    float4 b = sbox[(size_t)n*K_SEL + i];
    int lv = slvl[(size_t)n*K_SEL + i];
    float off = (float)lv * 1345.0f;
    float ox1 = __fadd_rn(b.x, off), oy1 = __fadd_rn(b.y, off);
    float ox2 = __fadd_rn(b.z, off), oy2 = __fadd_rn(b.w, off);
    float area = __fmul_rn(__fsub_rn(ox2,ox1), __fsub_rn(oy2,oy1));
    bool hit = false;
    for (int j = tid; j < kept; j += 256){
      if (klv[j] == lv){
        float ltx = fmaxf(kx1[j], ox1), lty = fmaxf(ky1[j], oy1);
        float rbx = fminf(kx2[j], ox2), rby = fminf(ky2[j], oy2);
        float w = fmaxf(__fsub_rn(rbx,ltx), 0.0f);
        float h = fmaxf(__fsub_rn(rby,lty), 0.0f);
        float inter = __fmul_rn(w,h);
        float uni = __fsub_rn(__fadd_rn(kar[j], area), inter);
        if (__fdiv_rn(inter,uni) > 0.7f) hit = true;
      }
    }
    if (hit) flag_s = 1;
    __syncthreads();
    int sup = flag_s;
    __syncthreads();
    if (!sup){
      if (tid == 0){
        kx1[kept]=ox1; ky1[kept]=oy1; kx2[kept]=ox2; ky2[kept]=oy2; kar[kept]=area; klv[kept]=lv;
        float* orow = out + (size_t)n*PRE*5 + (size_t)kept*5;
        orow[0]=b.x; orow[1]=b.y; orow[2]=b.z; orow[3]=b.w;
        orow[4]=sskey[(size_t)n*K_SEL + i];
      }
      ++kept;
    }
    if (tid == 0) flag_s = 0;
    __syncthreads();
    if (kept == PRE) break;
  }
}

extern "C" void kernel_launch(void* const* d_in, const int* in_sizes, int n_in,
                              void* d_out, int out_size, void* d_ws, size_t ws_size,
                              hipStream_t stream) {
  bool interleaved = (in_sizes[1] == 4*in_sizes[0]);
  const float* obj[5]; const float* dlt[5];
  for (int i = 0; i < 5; ++i){
    if (interleaved){ obj[i] = (const float*)d_in[2*i]; dlt[i] = (const float*)d_in[2*i+1]; }
    else            { obj[i] = (const float*)d_in[i];   dlt[i] = (const float*)d_in[5+i]; }
  }
  const float* anchors = (const float*)d_in[10];

  char* ws = (char*)d_ws;
  unsigned* hist            = (unsigned*)(ws);                     // 655360
  unsigned* cnt_gt          = (unsigned*)(ws + 655360);            // 160
  unsigned* cnt_eq          = (unsigned*)(ws + 655520);            // 160
  unsigned* thi             = (unsigned*)(ws + 655680);            // 160 -> counters end 655840
  unsigned long long* cand  = (unsigned long long*)(ws + 655840);  // 1310720 -> 1966560
  unsigned long long* keys  = (unsigned long long*)(ws + 1966560); // 320000 -> 2286560
  float4* lbox              = (float4*)(ws + 2286560);             // 640000 -> 2926560
  float4* lobox             = (float4*)(ws + 2926560);             // 640000 -> 3566560
  float* loarea             = (float*)(ws + 3566560);              // 160000 -> 3726560
  float* lskey              = (float*)(ws + 3726560);              // 160000 -> 3886560
  unsigned* rankinfo        = (unsigned*)(ws + 3886560);           // 160000 -> 4046560
  unsigned* lmat            = (unsigned*)(ws + 4046560);           // 5120000 -> 9166560
  float4* sbox              = (float4*)(ws + 9166560);             // fallback: 640000 -> 9806560
  float* sskey              = (float*)(ws + 9806560);              // 160000 -> 9966560
  int* slvl                 = (int*)(ws + 9966560);                // 160000 -> 10126560
  const size_t NEED = 10126560;

  hipMemsetAsync(ws, 0, 655840, stream);   // hist + counters

  dim3 gScan(8, 40);
  k_hist<<<gScan, 256, 0, stream>>>(obj[0],obj[1],obj[2],obj[3],obj[4], hist);
  k_scan<<<40, 256, 0, stream>>>(hist, thi);
  k_compact<<<gScan, 256, 0, stream>>>(obj[0],obj[1],obj[2],obj[3],obj[4],
                                       dlt[0],dlt[1],dlt[2],dlt[3],dlt[4],
                                       anchors, thi, cnt_gt, cnt_eq, cand, keys);
  k_tiesel<<<40, 256, 0, stream>>>(dlt[0],dlt[1],dlt[2],dlt[3],dlt[4], anchors,
                                   cnt_gt, cnt_eq, cand, keys);
  if (ws_size >= NEED){
    k_sortlvl<<<40, 256, 0, stream>>>(keys, dlt[0],dlt[1],dlt[2],dlt[3],dlt[4], anchors,
                                      lbox, lobox, loarea, lskey);
    k_rank<<<40, 256, 0, stream>>>(keys, rankinfo);
    k_ioumat_lvl<<<dim3(16, 40), 256, 0, stream>>>(lobox, loarea, lmat);
    hipMemsetAsync(d_out, 0, (size_t)out_size*sizeof(float), stream);
    k_scan_nms5<<<8, 64, 0, stream>>>(rankinfo, lmat, lbox, lskey, (float*)d_out);
  } else {
    k_sortimg<<<8, 256, 0, stream>>>(keys, dlt[0],dlt[1],dlt[2],dlt[3],dlt[4], anchors,
                                     sbox, sskey, slvl);
    k_nms<<<8, 256, 0, stream>>>(sbox, sskey, slvl, (float*)d_out);
  }
}

// Round 12
// 360.171 us; speedup vs baseline: 1.7880x; 1.1607x over previous
//
#include <hip/hip_runtime.h>
#include <cmath>

#define N_IMG   8
#define PRE     1000
#define K_SEL   5000
#define NBIN    4096
#define TIE_CAP 4096
#define IMG_F   1344.0f
#define S_NEGINF 0x007FFFFFu
#define TILES   79             // ceil(5000/64)
#define GRPW    32000          // words per grp in lmat: 16 wblk x 1000 p x 2
#define CHUNK   8192           // elements per block in k_hist/k_compact

__constant__ int c_W[5]   = {336,168,84,42,21};
__constant__ int c_HW[5]  = {112896,28224,7056,1764,441};
__constant__ int c_OFF[5] = {0,338688,423360,444528,449820};

__device__ __forceinline__ unsigned f2s(float f){
  unsigned u = __float_as_uint(f);
  return (u & 0x80000000u) ? ~u : (u | 0x80000000u);
}
__device__ __forceinline__ float s2f(unsigned s){
  unsigned u = (s & 0x80000000u) ? (s & 0x7FFFFFFFu) : ~s;
  return __uint_as_float(u);
}
__device__ __forceinline__ const float* sel5(int l, const float* p0,const float* p1,const float* p2,const float* p3,const float* p4){
  switch(l){case 0:return p0;case 1:return p1;case 2:return p2;case 3:return p3;default:return p4;}
}

struct BoxV { float x1,y1,x2,y2; bool valid; };

// Bit-faithful torchvision BoxCoder.decode + clip + min-size validity.
__device__ BoxV decode_box(int lvl, int t, int n, const float* dl, const float* anchors){
  int HW = c_HW[lvl], W = c_W[lvl];
  int a = t % 3, pos = t / 3;          // t = (h*W+w)*3 + a
  int h = pos / W, w = pos - h*W;
  int g = c_OFF[lvl] + t;
  const float* an = anchors + (size_t)4*(size_t)g;
  float a0=an[0], a1=an[1], a2=an[2], a3=an[3];
  float aw = __fsub_rn(a2,a0), ah = __fsub_rn(a3,a1);
  float acx = __fadd_rn(a0, __fmul_rn(0.5f,aw));
  float acy = __fadd_rn(a1, __fmul_rn(0.5f,ah));
  const float* dp = dl + ((size_t)n*12 + (size_t)a*4)*(size_t)HW + (size_t)h*W + (size_t)w;
  float dx = dp[0], dy = dp[HW], dwv = dp[2*(size_t)HW], dhv = dp[3*(size_t)HW];
  const float CLAMP = (float)4.135166556742356;  // log(1000/16)
  dwv = fminf(dwv, CLAMP); dhv = fminf(dhv, CLAMP);
  float pcx = __fadd_rn(__fmul_rn(dx,aw), acx);
  float pcy = __fadd_rn(__fmul_rn(dy,ah), acy);
  float pw = __fmul_rn((float)::exp((double)dwv), aw);
  float ph = __fmul_rn((float)::exp((double)dhv), ah);
  float hx = __fmul_rn(0.5f,pw), hy = __fmul_rn(0.5f,ph);
  BoxV b;
  b.x1 = fminf(fmaxf(__fsub_rn(pcx,hx),0.0f),IMG_F);
  b.y1 = fminf(fmaxf(__fsub_rn(pcy,hy),0.0f),IMG_F);
  b.x2 = fminf(fmaxf(__fadd_rn(pcx,hx),0.0f),IMG_F);
  b.y2 = fminf(fmaxf(__fadd_rn(pcy,hy),0.0f),IMG_F);
  b.valid = (__fsub_rn(b.x2,b.x1) >= 1e-3f) && (__fsub_rn(b.y2,b.y1) >= 1e-3f);
  return b;
}

// key = (~s_eff)<<22 | lvl<<19 | t : ascending sort == (score desc, level asc, idx asc)
__device__ unsigned long long make_key(unsigned s, int lvl, int t, int n, const float* dl, const float* anchors){
  BoxV b = decode_box(lvl,t,n,dl,anchors);
  unsigned se = b.valid ? s : S_NEGINF;     // invalid -> skey = -inf
  return ((unsigned long long)(~se) << 22) | ((unsigned long long)(unsigned)lvl << 19) | (unsigned long long)(unsigned)t;
}

// ---------------- K1: per-(image,level) 12-bit score histogram (chunked grid) ----------------
__global__ __launch_bounds__(256) void k_hist(const float* o0,const float* o1,const float* o2,const float* o3,const float* o4,
                                              unsigned* hist){
  int grp = blockIdx.y; int n = grp/5, lvl = grp - n*5;
  int HW = c_HW[lvl], M = 3*HW;
  int base = blockIdx.x * CHUNK;
  if (base >= M) return;                 // idle block for short levels
  int end = min(base + CHUNK, M);
  const float* ob = sel5(lvl,o0,o1,o2,o3,o4) + (size_t)n*(size_t)M;
  __shared__ unsigned lh[NBIN];
  for (int b = threadIdx.x; b < NBIN; b += 256) lh[b] = 0;
  __syncthreads();
  for (int i = base + threadIdx.x; i < end; i += 256){
    unsigned s = f2s(ob[i]);
    atomicAdd(&lh[s >> 20], 1u);
  }
  __syncthreads();
  unsigned* gh = hist + (size_t)grp*NBIN;
  for (int b = threadIdx.x; b < NBIN; b += 256){ unsigned v = lh[b]; if (v) atomicAdd(&gh[b], v); }
}

// ---------------- K2: find bin containing the 1000th-largest score ----------------
__global__ __launch_bounds__(256) void k_scan(const unsigned* hist, unsigned* thi){
  int grp = blockIdx.x;
  const unsigned* gh = hist + (size_t)grp*NBIN;
  __shared__ unsigned part[256];
  unsigned ssum = 0;
  int base = threadIdx.x*16;
  for (int b = base; b < base+16; ++b) ssum += gh[b];
  part[threadIdx.x] = ssum;
  __syncthreads();
  if (threadIdx.x == 0){
    int k = PRE;
    int c = 255;
    while ((int)part[c] < k){ k -= (int)part[c]; --c; }
    int b = c*16 + 15;
    while ((int)gh[b] < k){ k -= (int)gh[b]; --b; }
    thi[grp] = (unsigned)b;
  }
}

// ---------------- K3: compact >bin elements (chunked grid) ----------------
__global__ __launch_bounds__(256) void k_compact(const float* o0,const float* o1,const float* o2,const float* o3,const float* o4,
                                                 const float* d0,const float* d1,const float* d2,const float* d3,const float* d4,
                                                 const float* anchors, const unsigned* thi,
                                                 unsigned* cnt_gt, unsigned* cnt_eq,
                                                 unsigned long long* cand, unsigned long long* keys){
  int grp = blockIdx.y; int n = grp/5, lvl = grp - n*5;
  int HW = c_HW[lvl], M = 3*HW;
  int base = blockIdx.x * CHUNK;
  if (base >= M) return;
  int end = min(base + CHUNK, M);
  const float* ob = sel5(lvl,o0,o1,o2,o3,o4) + (size_t)n*(size_t)M;
  const float* dl = sel5(lvl,d0,d1,d2,d3,d4);
  unsigned T = thi[grp];
  unsigned long long* kout = keys + (size_t)n*K_SEL + (size_t)lvl*PRE;
  for (int i = base + threadIdx.x; i < end; i += 256){
    unsigned s = f2s(ob[i]);
    unsigned sh = s >> 20;
    if (sh > T){
      unsigned pos = atomicAdd(&cnt_gt[grp], 1u);
      int a = i / HW; int rem = i - a*HW; int t = rem*3 + a;
      kout[pos] = make_key(s, lvl, t, n, dl, anchors);
    } else if (sh == T){
      unsigned e = atomicAdd(&cnt_eq[grp], 1u);
      if (e < TIE_CAP){
        int a = i / HW; int rem = i - a*HW; int t = rem*3 + a;
        cand[(size_t)grp*TIE_CAP + e] = ((unsigned long long)(~s) << 19) | (unsigned long long)(unsigned)t;
      }
    }
  }
}

template<int SZ>
__device__ void bitonic(unsigned long long* sk){
  for (int k = 2; k <= SZ; k <<= 1){
    for (int j = k >> 1; j > 0; j >>= 1){
      for (int i = threadIdx.x; i < SZ; i += blockDim.x){
        int ix = i ^ j;
        if (ix > i){
          unsigned long long va = sk[i], vb = sk[ix];
          if ((va > vb) == ((i & k) == 0)){ sk[i] = vb; sk[ix] = va; }
        }
      }
      __syncthreads();
    }
  }
}

// runtime-sized bitonic (SZ uniform across block, power of 2)
__device__ void bitonic_rt(unsigned long long* sk, int SZ){
  for (int k = 2; k <= SZ; k <<= 1){
    for (int j = k >> 1; j > 0; j >>= 1){
      for (int i = threadIdx.x; i < SZ; i += blockDim.x){
        int ix = i ^ j;
        if (ix > i){
          unsigned long long va = sk[i], vb = sk[ix];
          if ((va > vb) == ((i & k) == 0)){ sk[i] = vb; sk[ix] = va; }
        }
      }
      __syncthreads();
    }
  }
}

// ---------------- K4: exact boundary selection within the threshold bin ----------------
__global__ __launch_bounds__(256) void k_tiesel(const float* d0,const float* d1,const float* d2,const float* d3,const float* d4,
                                                const float* anchors,
                                                const unsigned* cnt_gt, const unsigned* cnt_eq,
                                                const unsigned long long* cand, unsigned long long* keys){
  int grp = blockIdx.x; int n = grp/5, lvl = grp - n*5;
  __shared__ unsigned long long sk[TIE_CAP];
  int ne = min((int)cnt_eq[grp], TIE_CAP);
  int SZ = 64; while (SZ < ne) SZ <<= 1;    // runtime pow2 >= ne (uniform)
  for (int i = threadIdx.x; i < SZ; i += 256)
    sk[i] = (i < ne) ? cand[(size_t)grp*TIE_CAP + i] : ~0ULL;
  __syncthreads();
  bitonic_rt(sk, SZ);                // ascending: (score desc, idx asc)
  int cg = (int)cnt_gt[grp];
  int need = PRE - cg;
  const float* dl = sel5(lvl,d0,d1,d2,d3,d4);
  unsigned long long* kout = keys + (size_t)n*K_SEL + (size_t)lvl*PRE + cg;
  for (int j = threadIdx.x; j < need; j += 256){
    if (j < ne){
      unsigned long long ck = sk[j];
      unsigned t = (unsigned)(ck & 0x7FFFFu);
      unsigned s = ~((unsigned)(ck >> 19));
      kout[j] = make_key(s, lvl, (int)t, n, dl, anchors);
    } else {
      kout[j] = ((unsigned long long)(~S_NEGINF) << 22); // pathological overflow: harmless invalid
    }
  }
}

// ---------------- K5a: sort each (image,level) run; decode level-space arrays ----------------
__global__ __launch_bounds__(256) void k_sortlvl(unsigned long long* keys,
                                                 const float* d0,const float* d1,const float* d2,const float* d3,const float* d4,
                                                 const float* anchors,
                                                 float4* lbox, float4* lobox, float* loarea, float* lskey){
  int grp = blockIdx.x; int n = grp/5, lvl = grp - n*5;
  __shared__ unsigned long long sk[1024];
  unsigned long long* kp = keys + (size_t)n*K_SEL + (size_t)lvl*PRE;
  for (int i = threadIdx.x; i < 1024; i += 256)
    sk[i] = (i < PRE) ? kp[i] : ~0ULL;
  __syncthreads();
  bitonic<1024>(sk);
  const float* dl = sel5(lvl,d0,d1,d2,d3,d4);
  for (int i = threadIdx.x; i < PRE; i += 256){
    unsigned long long key = sk[i];
    kp[i] = key;                          // sorted run back to global (k_rank reads it)
    int t = (int)(key & 0x7FFFFu);
    unsigned se = ~((unsigned)(key >> 22));
    BoxV b = decode_box(lvl, t, n, dl, anchors);
    size_t o = (size_t)grp*PRE + i;
    lbox[o] = make_float4(b.x1,b.y1,b.x2,b.y2);
    lskey[o] = s2f(se);                   // -inf if invalid
    float off = (float)lvl * 1345.0f;     // (IMG+1) batched-NMS offset
    float ox1 = __fadd_rn(b.x1, off), oy1 = __fadd_rn(b.y1, off);
    float ox2 = __fadd_rn(b.x2, off), oy2 = __fadd_rn(b.y2, off);
    lobox[o] = make_float4(ox1,oy1,ox2,oy2);
    loarea[o] = __fmul_rn(__fsub_rn(ox2,ox1), __fsub_rn(oy2,oy1));
  }
}

// ---------------- K5b: global rank of each level element (keys globally unique) ----------------
// rankinfo[rank] = p | (lvl<<10) | (valid<<13)
__global__ __launch_bounds__(256) void k_rank(const unsigned long long* keys, unsigned* rankinfo){
  int grp = blockIdx.x; int n = grp/5, lvl = grp - n*5;
  __shared__ unsigned long long sl[K_SEL];
  for (int i = threadIdx.x; i < K_SEL; i += 256) sl[i] = keys[(size_t)n*K_SEL + i];
  __syncthreads();
  for (int j = threadIdx.x; j < PRE; j += 256){
    unsigned long long k = sl[lvl*PRE + j];
    int rank = j;
    #pragma unroll
    for (int m = 0; m < 5; ++m){
      if (m == lvl) continue;
      const unsigned long long* s = sl + m*PRE;
      int lo = 0, hi = PRE;
      while (lo < hi){ int mid = (lo+hi) >> 1; if (s[mid] < k) lo = mid+1; else hi = mid; }
      rank += lo;
    }
    unsigned se = ~((unsigned)(k >> 22));
    unsigned info = (unsigned)j | ((unsigned)lvl << 10) | ((se != S_NEGINF) ? (1u<<13) : 0u);
    rankinfo[(size_t)n*K_SEL + rank] = info;   // exact permutation of [0,5000)
  }
}

// ---------------- K6a: suppression bit-matrix, ballot + column layout, 4 waves/block ----------------
__global__ __launch_bounds__(256) void k_ioumat_lvl(const float4* lobox, const float* loarea, unsigned* lmat){
  int grp = blockIdx.y;                  // n*5 + L
  int wblk = blockIdx.x;                 // j-block: j = wblk*64 + lane
  int tid = threadIdx.x;
  int lane = tid & 63, q = tid >> 6;
  __shared__ float sx1[PRE], sy1[PRE], sx2[PRE], sy2[PRE], sar[PRE];
  for (int i = tid; i < PRE; i += 256){
    float4 bb = lobox[(size_t)grp*PRE + i];
    sx1[i]=bb.x; sy1[i]=bb.y; sx2[i]=bb.z; sy2[i]=bb.w;
    sar[i]=loarea[(size_t)grp*PRE + i];
  }
  __syncthreads();
  int j = wblk*64 + lane;
  float jx1=0.f,jy1=0.f,jx2=0.f,jy2=0.f,ja=0.f;
  if (j < PRE){
    float4 bb = lobox[(size_t)grp*PRE + j];
    jx1=bb.x; jy1=bb.y; jx2=bb.z; jy2=bb.w; ja=loarea[(size_t)grp*PRE + j];
  }
  unsigned* mg = lmat + (size_t)grp*GRPW + (size_t)wblk*2*PRE;
  int pmax = min(PRE, wblk*64 + 63);     // rows p >= pmax: no j>p in this block
  int q0 = q*250, q1 = q0 + 250;
  int pm = min(q1, pmax);

#define IOU_HIT(P, OUT) { \
    float bx1=sx1[P], by1=sy1[P], bx2=sx2[P], by2=sy2[P], ba=sar[P]; \
    float ltx = fmaxf(bx1, jx1), lty = fmaxf(by1, jy1); \
    float rbx = fminf(bx2, jx2), rby = fminf(by2, jy2); \
    float ww = fmaxf(__fsub_rn(rbx,ltx), 0.0f); \
    float hh = fmaxf(__fsub_rn(rby,lty), 0.0f); \
    float inter = __fmul_rn(ww,hh); \
    float uni = __fsub_rn(__fadd_rn(ba, ja), inter); \
    OUT = (__fdiv_rn(inter,uni) > 0.7f) && (j > (P)) && (j < PRE); }

  int p = q0;
  for (; p + 4 <= pm; p += 4){
    bool h0,h1,h2,h3;
    IOU_HIT(p,   h0);
    IOU_HIT(p+1, h1);
    IOU_HIT(p+2, h2);
    IOU_HIT(p+3, h3);
    unsigned long long b0 = __ballot(h0), b1 = __ballot(h1);
    unsigned long long b2 = __ballot(h2), b3 = __ballot(h3);
    if ((lane & 31) == 0){
      int d = lane >> 5;
      mg[(p  )*2 + d] = (lane==0) ? (unsigned)b0 : (unsigned)(b0>>32);
      mg[(p+1)*2 + d] = (lane==0) ? (unsigned)b1 : (unsigned)(b1>>32);
      mg[(p+2)*2 + d] = (lane==0) ? (unsigned)b2 : (unsigned)(b2>>32);
      mg[(p+3)*2 + d] = (lane==0) ? (unsigned)b3 : (unsigned)(b3>>32);
    }
  }
  for (; p < pm; ++p){
    bool h; IOU_HIT(p, h);
    unsigned long long bal = __ballot(h);
    if ((lane & 31) == 0)
      mg[p*2 + (lane>>5)] = (lane==0) ? (unsigned)bal : (unsigned)(bal>>32);
  }
#undef IOU_HIT
  int zs = (pm > q0 ? pm : q0);
  for (int w = zs*2 + lane; w < q1*2; w += 64) mg[w] = 0u;   // contiguous zero-fill
}

// ---------------- K6b: tile-parallel greedy scan, latency-batched TPROC ----------------
__global__ __launch_bounds__(64) void k_scan_nms5(const unsigned* rankinfo, const unsigned* lmat,
                                                  const float4* lbox, const float* lskey, float* out){
  __shared__ unsigned lrows[64][36];     // row-major tile; stride 36 words
  __shared__ unsigned lsup[160];         // 5 levels x 32 words suppression state
  int n = blockIdx.x; int lane = threadIdx.x;
  int n5 = n*5;
  const unsigned* rin = rankinfo + (size_t)n*K_SEL;
  float* outn = out + (size_t)n*PRE*5;
  for (int i = lane; i < 160; i += 64) lsup[i] = 0u;
  int kept_total = 0;
  uint2 Pa,Pb,Pc,Pd,Pe,Pf,Pg,Ph,Pi,Pj,Pk,Pl,Pm,Pn,Po,Pp;  // 16x8B staging
  float4 boxP; float scP = 0.f;
  unsigned infoC, infoN;
  int rgrp = lane >> 4;                  // 0..3: row subgroup
  unsigned wboff = (unsigned)(lane & 15) * (2u*PRE);  // my wblk's column segment
  int wb2 = (lane & 15) << 1;            // word index within row

#define SLOAD(INFO) { \
    unsigned L_ = ((INFO)>>10)&7u; unsigned p_ = (INFO) & 1023u; \
    unsigned rowu_ = ((unsigned)n5 + L_)*GRPW + p_*2u; \
    unsigned rb_; \
    rb_ = __shfl(rowu_,  0 + rgrp); Pa = *(const uint2*)(lmat + rb_ + wboff); \
    rb_ = __shfl(rowu_,  4 + rgrp); Pb = *(const uint2*)(lmat + rb_ + wboff); \
    rb_ = __shfl(rowu_,  8 + rgrp); Pc = *(const uint2*)(lmat + rb_ + wboff); \
    rb_ = __shfl(rowu_, 12 + rgrp); Pd = *(const uint2*)(lmat + rb_ + wboff); \
    rb_ = __shfl(rowu_, 16 + rgrp); Pe = *(const uint2*)(lmat + rb_ + wboff); \
    rb_ = __shfl(rowu_, 20 + rgrp); Pf = *(const uint2*)(lmat + rb_ + wboff); \
    rb_ = __shfl(rowu_, 24 + rgrp); Pg = *(const uint2*)(lmat + rb_ + wboff); \
    rb_ = __shfl(rowu_, 28 + rgrp); Ph = *(const uint2*)(lmat + rb_ + wboff); \
    rb_ = __shfl(rowu_, 32 + rgrp); Pi = *(const uint2*)(lmat + rb_ + wboff); \
    rb_ = __shfl(rowu_, 36 + rgrp); Pj = *(const uint2*)(lmat + rb_ + wboff); \
    rb_ = __shfl(rowu_, 40 + rgrp); Pk = *(const uint2*)(lmat + rb_ + wboff); \
    rb_ = __shfl(rowu_, 44 + rgrp); Pl = *(const uint2*)(lmat + rb_ + wboff); \
    rb_ = __shfl(rowu_, 48 + rgrp); Pm = *(const uint2*)(lmat + rb_ + wboff); \
    rb_ = __shfl(rowu_, 52 + rgrp); Pn = *(const uint2*)(lmat + rb_ + wboff); \
    rb_ = __shfl(rowu_, 56 + rgrp); Po = *(const uint2*)(lmat + rb_ + wboff); \
    rb_ = __shfl(rowu_, 60 + rgrp); Pp = *(const uint2*)(lmat + rb_ + wboff); \
    size_t bi_ = (size_t)((unsigned)n5 + L_)*PRE + p_; \
    boxP = lbox[bi_]; scP = lskey[bi_]; }

#define SWRITE() { \
    *(uint2*)&lrows[ 0 + rgrp][wb2] = Pa; *(uint2*)&lrows[ 4 + rgrp][wb2] = Pb; \
    *(uint2*)&lrows[ 8 + rgrp][wb2] = Pc; *(uint2*)&lrows[12 + rgrp][wb2] = Pd; \
    *(uint2*)&lrows[16 + rgrp][wb2] = Pe; *(uint2*)&lrows[20 + rgrp][wb2] = Pf; \
    *(uint2*)&lrows[24 + rgrp][wb2] = Pg; *(uint2*)&lrows[28 + rgrp][wb2] = Ph; \
    *(uint2*)&lrows[32 + rgrp][wb2] = Pi; *(uint2*)&lrows[36 + rgrp][wb2] = Pj; \
    *(uint2*)&lrows[40 + rgrp][wb2] = Pk; *(uint2*)&lrows[44 + rgrp][wb2] = Pl; \
    *(uint2*)&lrows[48 + rgrp][wb2] = Pm; *(uint2*)&lrows[52 + rgrp][wb2] = Pn; \
    *(uint2*)&lrows[56 + rgrp][wb2] = Po; *(uint2*)&lrows[60 + rgrp][wb2] = Pp; }

#define GRP16(B, ACC, SH) { \
    unsigned q0_=lrows[(B)+ 0][idxw_], q1_=lrows[(B)+ 1][idxw_], \
             q2_=lrows[(B)+ 2][idxw_], q3_=lrows[(B)+ 3][idxw_], \
             q4_=lrows[(B)+ 4][idxw_], q5_=lrows[(B)+ 5][idxw_], \
             q6_=lrows[(B)+ 6][idxw_], q7_=lrows[(B)+ 7][idxw_], \
             q8_=lrows[(B)+ 8][idxw_], q9_=lrows[(B)+ 9][idxw_], \
             qa_=lrows[(B)+10][idxw_], qb_=lrows[(B)+11][idxw_], \
             qc_=lrows[(B)+12][idxw_], qd_=lrows[(B)+13][idxw_], \
             qe_=lrows[(B)+14][idxw_], qf_=lrows[(B)+15][idxw_]; \
    ACC |= (((q0_>>pb_)&1u)<<((SH)+ 0)) | (((q1_>>pb_)&1u)<<((SH)+ 1)) \
         | (((q2_>>pb_)&1u)<<((SH)+ 2)) | (((q3_>>pb_)&1u)<<((SH)+ 3)) \
         | (((q4_>>pb_)&1u)<<((SH)+ 4)) | (((q5_>>pb_)&1u)<<((SH)+ 5)) \
         | (((q6_>>pb_)&1u)<<((SH)+ 6)) | (((q7_>>pb_)&1u)<<((SH)+ 7)) \
         | (((q8_>>pb_)&1u)<<((SH)+ 8)) | (((q9_>>pb_)&1u)<<((SH)+ 9)) \
         | (((qa_>>pb_)&1u)<<((SH)+10)) | (((qb_>>pb_)&1u)<<((SH)+11)) \
         | (((qc_>>pb_)&1u)<<((SH)+12)) | (((qd_>>pb_)&1u)<<((SH)+13)) \
         | (((qe_>>pb_)&1u)<<((SH)+14)) | (((qf_>>pb_)&1u)<<((SH)+15)); }

#define TPROC(INFO, BOX, SC, baseexpr) { \
    int base_ = (baseexpr); \
    unsigned L_ = ((INFO)>>10)&7u; unsigned p_ = (INFO) & 1023u; \
    int idxw_ = (int)(p_ >> 5); unsigned pb_ = p_ & 31u; \
    unsigned long long lb0_=__ballot(L_==0u), lb1_=__ballot(L_==1u), \
                       lb2_=__ballot(L_==2u), lb3_=__ballot(L_==3u), lb4_=__ballot(L_==4u); \
    unsigned long long myLvl_ = (L_==0u)?lb0_:(L_==1u)?lb1_:(L_==2u)?lb2_:(L_==3u)?lb3_:lb4_; \
    unsigned sw_ = lsup[L_*32u + (unsigned)idxw_]; \
    bool ok_ = ((((INFO)>>13)&1u)!=0u) && (base_ + lane < K_SEL) && (((sw_>>pb_)&1u)==0u); \
    unsigned long long cand_ = __ballot(ok_); \
    unsigned alo_ = 0u, ahi_ = 0u; \
    GRP16( 0, alo_,  0); GRP16(16, alo_, 16); \
    GRP16(32, ahi_,  0); GRP16(48, ahi_, 16); \
    unsigned long long cm_ = ((((unsigned long long)ahi_)<<32)|(unsigned long long)alo_) & myLvl_; \
    unsigned long long keptM_ = 0ull; \
    while (cand_){ \
      bool safe_ = (((cand_>>lane)&1ull)!=0ull) && ((cm_ & cand_)==0ull); \
      unsigned long long nk_ = __ballot(safe_); \
      keptM_ |= nk_; \
      bool dead_ = (((cand_>>lane)&1ull)!=0ull) && ((cm_ & nk_)!=0ull); \
      cand_ &= ~(nk_ | __ballot(dead_)); \
    } \
    if (((keptM_>>lane)&1ull)!=0ull){ \
      unsigned sb_ = L_*32u; \
      _Pragma("unroll") \
      for (int k_ = 0; k_ < 32; ++k_){ \
        unsigned w_ = (unsigned)((k_+lane)&31); \
        atomicOr(&lsup[sb_+w_], lrows[lane][w_]); \
      } \
    } \
    int pos_ = kept_total + (int)__popcll(keptM_ & ((1ull<<lane)-1ull)); \
    if ((((keptM_>>lane)&1ull)!=0ull) && pos_ < PRE){ \
      float* orow_ = outn + (size_t)pos_*5; \
      orow_[0]=(BOX).x; orow_[1]=(BOX).y; orow_[2]=(BOX).z; orow_[3]=(BOX).w; orow_[4]=(SC); \
    } \
    kept_total += (int)__popcll(keptM_); \
    asm volatile("s_waitcnt lgkmcnt(0)" ::: "memory"); \
  }

  infoC = rin[lane];
  SLOAD(infoC);                          // tile 0 rows -> regs, box -> boxP
  SWRITE();                              // tile 0 rows -> LDS
  float4 boxC = boxP; float scC = scP;
  infoN = rin[64 + lane];

  for (int t = 0; t < TILES; ++t){
    if (t+1 < TILES) SLOAD(infoN);       // issue next tile's loads (rows + box)
    asm volatile("s_waitcnt lgkmcnt(0)" ::: "memory");   // lrows writes visible
    TPROC(infoC, boxC, scC, t*64);
    if (kept_total >= PRE) break;
    if (t+1 < TILES){
      SWRITE();                          // waits next tile's loads (covered by TPROC)
      boxC = boxP; scC = scP;
      infoC = infoN;
      if (t+2 < TILES){
        int nx = (t+2)*64 + lane; if (nx > K_SEL-1) nx = K_SEL-1;
        infoN = rin[nx];
      }
    }
  }
#undef SLOAD
#undef SWRITE
#undef GRP16
#undef TPROC
}

// ---------------- fallback path (ws too small): round-3 kernels ----------------
__global__ __launch_bounds__(256) void k_sortimg(const unsigned long long* keys,
                                                 const float* d0,const float* d1,const float* d2,const float* d3,const float* d4,
                                                 const float* anchors,
                                                 float4* sbox, float* sskey, int* slvl){
  int n = blockIdx.x;
  __shared__ unsigned long long sk[8192];
  for (int i = threadIdx.x; i < 8192; i += 256)
    sk[i] = (i < K_SEL) ? keys[(size_t)n*K_SEL + i] : ~0ULL;
  __syncthreads();
  bitonic<8192>(sk);
  for (int r = threadIdx.x; r < K_SEL; r += 256){
    unsigned long long key = sk[r];
    int t = (int)(key & 0x7FFFFu);
    int lvl = (int)((key >> 19) & 7u);
    unsigned se = ~((unsigned)(key >> 22));
    const float* dl = sel5(lvl,d0,d1,d2,d3,d4);
    BoxV b = decode_box(lvl, t, n, dl, anchors);
    sbox[(size_t)n*K_SEL + r] = make_float4(b.x1,b.y1,b.x2,b.y2);
    sskey[(size_t)n*K_SEL + r] = s2f(se);
    slvl[(size_t)n*K_SEL + r] = lvl;
  }
}

__global__ __launch_bounds__(256) void k_nms(const float4* sbox, const float* sskey, const int* slvl, float* out){
  int n = blockIdx.x, tid = threadIdx.x;
  __shared__ float kx1[PRE], ky1[PRE], kx2[PRE], ky2[PRE], kar[PRE];
  __shared__ int klv[PRE];
  __shared__ int nv_s, flag_s;
  for (int i = tid; i < PRE*5; i += 256) out[(size_t)n*PRE*5 + i] = 0.0f;
  if (tid == 0){ nv_s = 0; flag_s = 0; }
  __syncthreads();
  int c = 0;
  for (int i = tid; i < K_SEL; i += 256)
    if (sskey[(size_t)n*K_SEL + i] != -INFINITY) ++c;
  atomicAdd(&nv_s, c);
  __syncthreads();
  int nvalid = nv_s;
  int kept = 0;
  for (int i = 0; i < nvalid; ++i){
    float4 b = sbox[(size_t)n*K_SEL + i];
    int lv = slvl[(size_t)n*K_SEL + i];
    float off = (float)lv * 1345.0f;
    float ox1 = __fadd_rn(b.x, off), oy1 = __fadd_rn(b.y, off);
    float ox2 = __fadd_rn(b.z, off), oy2 = __fadd_rn(b.w, off);
    float area = __fmul_rn(__fsub_rn(ox2,ox1), __fsub_rn(oy2,oy1));
    bool hit = false;
    for (int j = tid; j < kept; j += 256){
      if (klv[j] == lv){
        float ltx = fmaxf(kx1[j], ox1), lty = fmaxf(ky1[j], oy1);
        float rbx = fminf(kx2[j], ox2), rby = fminf(ky2[j], oy2);
        float w = fmaxf(__fsub_rn(rbx,ltx), 0.0f);
        float h = fmaxf(__fsub_rn(rby,lty), 0.0f);
        float inter = __fmul_rn(w,h);
        float uni = __fsub_rn(__fadd_rn(kar[j], area), inter);
        if (__fdiv_rn(inter,uni) > 0.7f) hit = true;
      }
    }
    if (hit) flag_s = 1;
    __syncthreads();
    int sup = flag_s;
    __syncthreads();
    if (!sup){
      if (tid == 0){
        kx1[kept]=ox1; ky1[kept]=oy1; kx2[kept]=ox2; ky2[kept]=oy2; kar[kept]=area; klv[kept]=lv;
        float* orow = out + (size_t)n*PRE*5 + (size_t)kept*5;
        orow[0]=b.x; orow[1]=b.y; orow[2]=b.z; orow[3]=b.w;
        orow[4]=sskey[(size_t)n*K_SEL + i];
      }
      ++kept;
    }
    if (tid == 0) flag_s = 0;
    __syncthreads();
    if (kept == PRE) break;
  }
}

extern "C" void kernel_launch(void* const* d_in, const int* in_sizes, int n_in,
                              void* d_out, int out_size, void* d_ws, size_t ws_size,
                              hipStream_t stream) {
  bool interleaved = (in_sizes[1] == 4*in_sizes[0]);
  const float* obj[5]; const float* dlt[5];
  for (int i = 0; i < 5; ++i){
    if (interleaved){ obj[i] = (const float*)d_in[2*i]; dlt[i] = (const float*)d_in[2*i+1]; }
    else            { obj[i] = (const float*)d_in[i];   dlt[i] = (const float*)d_in[5+i]; }
  }
  const float* anchors = (const float*)d_in[10];

  char* ws = (char*)d_ws;
  unsigned* hist            = (unsigned*)(ws);                     // 655360
  unsigned* cnt_gt          = (unsigned*)(ws + 655360);            // 160
  unsigned* cnt_eq          = (unsigned*)(ws + 655520);            // 160
  unsigned* thi             = (unsigned*)(ws + 655680);            // 160 -> counters end 655840
  unsigned long long* cand  = (unsigned long long*)(ws + 655840);  // 1310720 -> 1966560
  unsigned long long* keys  = (unsigned long long*)(ws + 1966560); // 320000 -> 2286560
  float4* lbox              = (float4*)(ws + 2286560);             // 640000 -> 2926560
  float4* lobox             = (float4*)(ws + 2926560);             // 640000 -> 3566560
  float* loarea             = (float*)(ws + 3566560);              // 160000 -> 3726560
  float* lskey              = (float*)(ws + 3726560);              // 160000 -> 3886560
  unsigned* rankinfo        = (unsigned*)(ws + 3886560);           // 160000 -> 4046560
  unsigned* lmat            = (unsigned*)(ws + 4046560);           // 5120000 -> 9166560
  float4* sbox              = (float4*)(ws + 9166560);             // fallback: 640000 -> 9806560
  float* sskey              = (float*)(ws + 9806560);              // 160000 -> 9966560
  int* slvl                 = (int*)(ws + 9966560);                // 160000 -> 10126560
  const size_t NEED = 10126560;

  hipMemsetAsync(ws, 0, 655840, stream);   // hist + counters

  dim3 gChunk(42, 40);                   // 42 chunks x 8192 covers level-0's 338688
  k_hist<<<gChunk, 256, 0, stream>>>(obj[0],obj[1],obj[2],obj[3],obj[4], hist);
  k_scan<<<40, 256, 0, stream>>>(hist, thi);
  k_compact<<<gChunk, 256, 0, stream>>>(obj[0],obj[1],obj[2],obj[3],obj[4],
                                        dlt[0],dlt[1],dlt[2],dlt[3],dlt[4],
                                        anchors, thi, cnt_gt, cnt_eq, cand, keys);
  k_tiesel<<<40, 256, 0, stream>>>(dlt[0],dlt[1],dlt[2],dlt[3],dlt[4], anchors,
                                   cnt_gt, cnt_eq, cand, keys);
  if (ws_size >= NEED){
    k_sortlvl<<<40, 256, 0, stream>>>(keys, dlt[0],dlt[1],dlt[2],dlt[3],dlt[4], anchors,
                                      lbox, lobox, loarea, lskey);
    k_rank<<<40, 256, 0, stream>>>(keys, rankinfo);
    k_ioumat_lvl<<<dim3(16, 40), 256, 0, stream>>>(lobox, loarea, lmat);
    hipMemsetAsync(d_out, 0, (size_t)out_size*sizeof(float), stream);
    k_scan_nms5<<<8, 64, 0, stream>>>(rankinfo, lmat, lbox, lskey, (float*)d_out);
  } else {
    k_sortimg<<<8, 256, 0, stream>>>(keys, dlt[0],dlt[1],dlt[2],dlt[3],dlt[4], anchors,
                                     sbox, sskey, slvl);
    k_nms<<<8, 256, 0, stream>>>(sbox, sskey, slvl, (float*)d_out);
  }
}

// Round 13
// 267.094 us; speedup vs baseline: 2.4111x; 1.3485x over previous
//
#include <hip/hip_runtime.h>
#include <cmath>

#define N_IMG   8
#define PRE     1000
#define K_SEL   5000
#define NBIN    4096
#define TIE_CAP 4096
#define IMG_F   1344.0f
#define S_NEGINF 0x007FFFFFu
#define TILES   79             // ceil(5000/64)
#define GRPW    32000          // words per grp in lmat: 16 wblk x 1000 p x 2
#define CHUNK   8192           // elements per block in k_hist/k_compact

__constant__ int c_W[5]   = {336,168,84,42,21};
__constant__ int c_HW[5]  = {112896,28224,7056,1764,441};
__constant__ int c_OFF[5] = {0,338688,423360,444528,449820};

__device__ __forceinline__ unsigned f2s(float f){
  unsigned u = __float_as_uint(f);
  return (u & 0x80000000u) ? ~u : (u | 0x80000000u);
}
__device__ __forceinline__ float s2f(unsigned s){
  unsigned u = (s & 0x80000000u) ? (s & 0x7FFFFFFFu) : ~s;
  return __uint_as_float(u);
}
__device__ __forceinline__ const float* sel5(int l, const float* p0,const float* p1,const float* p2,const float* p3,const float* p4){
  switch(l){case 0:return p0;case 1:return p1;case 2:return p2;case 3:return p3;default:return p4;}
}

struct BoxV { float x1,y1,x2,y2; bool valid; };

// Bit-faithful torchvision BoxCoder.decode + clip + min-size validity.
__device__ BoxV decode_box(int lvl, int t, int n, const float* dl, const float* anchors){
  int HW = c_HW[lvl], W = c_W[lvl];
  int a = t % 3, pos = t / 3;          // t = (h*W+w)*3 + a
  int h = pos / W, w = pos - h*W;
  int g = c_OFF[lvl] + t;
  const float* an = anchors + (size_t)4*(size_t)g;
  float a0=an[0], a1=an[1], a2=an[2], a3=an[3];
  float aw = __fsub_rn(a2,a0), ah = __fsub_rn(a3,a1);
  float acx = __fadd_rn(a0, __fmul_rn(0.5f,aw));
  float acy = __fadd_rn(a1, __fmul_rn(0.5f,ah));
  const float* dp = dl + ((size_t)n*12 + (size_t)a*4)*(size_t)HW + (size_t)h*W + (size_t)w;
  float dx = dp[0], dy = dp[HW], dwv = dp[2*(size_t)HW], dhv = dp[3*(size_t)HW];
  const float CLAMP = (float)4.135166556742356;  // log(1000/16)
  dwv = fminf(dwv, CLAMP); dhv = fminf(dhv, CLAMP);
  float pcx = __fadd_rn(__fmul_rn(dx,aw), acx);
  float pcy = __fadd_rn(__fmul_rn(dy,ah), acy);
  float pw = __fmul_rn((float)::exp((double)dwv), aw);
  float ph = __fmul_rn((float)::exp((double)dhv), ah);
  float hx = __fmul_rn(0.5f,pw), hy = __fmul_rn(0.5f,ph);
  BoxV b;
  b.x1 = fminf(fmaxf(__fsub_rn(pcx,hx),0.0f),IMG_F);
  b.y1 = fminf(fmaxf(__fsub_rn(pcy,hy),0.0f),IMG_F);
  b.x2 = fminf(fmaxf(__fadd_rn(pcx,hx),0.0f),IMG_F);
  b.y2 = fminf(fmaxf(__fadd_rn(pcy,hy),0.0f),IMG_F);
  b.valid = (__fsub_rn(b.x2,b.x1) >= 1e-3f) && (__fsub_rn(b.y2,b.y1) >= 1e-3f);
  return b;
}

// key = (~s_eff)<<22 | lvl<<19 | t : ascending sort == (score desc, level asc, idx asc)
__device__ unsigned long long make_key(unsigned s, int lvl, int t, int n, const float* dl, const float* anchors){
  BoxV b = decode_box(lvl,t,n,dl,anchors);
  unsigned se = b.valid ? s : S_NEGINF;     // invalid -> skey = -inf
  return ((unsigned long long)(~se) << 22) | ((unsigned long long)(unsigned)lvl << 19) | (unsigned long long)(unsigned)t;
}

// ---------------- K1: per-(image,level) 12-bit score histogram (chunked grid) ----------------
__global__ __launch_bounds__(256) void k_hist(const float* o0,const float* o1,const float* o2,const float* o3,const float* o4,
                                              unsigned* hist){
  int grp = blockIdx.y; int n = grp/5, lvl = grp - n*5;
  int HW = c_HW[lvl], M = 3*HW;
  int base = blockIdx.x * CHUNK;
  if (base >= M) return;                 // idle block for short levels
  int end = min(base + CHUNK, M);
  const float* ob = sel5(lvl,o0,o1,o2,o3,o4) + (size_t)n*(size_t)M;
  __shared__ unsigned lh[NBIN];
  for (int b = threadIdx.x; b < NBIN; b += 256) lh[b] = 0;
  __syncthreads();
  for (int i = base + threadIdx.x; i < end; i += 256){
    unsigned s = f2s(ob[i]);
    atomicAdd(&lh[s >> 20], 1u);
  }
  __syncthreads();
  unsigned* gh = hist + (size_t)grp*NBIN;
  for (int b = threadIdx.x; b < NBIN; b += 256){ unsigned v = lh[b]; if (v) atomicAdd(&gh[b], v); }
}

// ---------------- K2: find bin containing the 1000th-largest score ----------------
__global__ __launch_bounds__(256) void k_scan(const unsigned* hist, unsigned* thi){
  int grp = blockIdx.x;
  const unsigned* gh = hist + (size_t)grp*NBIN;
  __shared__ unsigned part[256];
  unsigned ssum = 0;
  int base = threadIdx.x*16;
  for (int b = base; b < base+16; ++b) ssum += gh[b];
  part[threadIdx.x] = ssum;
  __syncthreads();
  if (threadIdx.x == 0){
    int k = PRE;
    int c = 255;
    while ((int)part[c] < k){ k -= (int)part[c]; --c; }
    int b = c*16 + 15;
    while ((int)gh[b] < k){ k -= (int)gh[b]; --b; }
    thi[grp] = (unsigned)b;
  }
}

// ---------------- K3: compact >bin elements (two-phase: LDS lists + block reservation) ----------------
// Phase 1 classifies into LDS index lists (LDS atomics). ONE global atomicAdd per list
// per block reserves output ranges (928 global atomics total vs ~100k same-line before —
// round-12's 111us was same-cache-line atomic serialization). Phase 2 decodes densely.
// keys' unordered prefix / cand order permuted only — both fully sorted downstream.
__global__ __launch_bounds__(256) void k_compact(const float* o0,const float* o1,const float* o2,const float* o3,const float* o4,
                                                 const float* d0,const float* d1,const float* d2,const float* d3,const float* d4,
                                                 const float* anchors, const unsigned* thi,
                                                 unsigned* cnt_gt, unsigned* cnt_eq,
                                                 unsigned long long* cand, unsigned long long* keys){
  int grp = blockIdx.y; int n = grp/5, lvl = grp - n*5;
  int HW = c_HW[lvl], M = 3*HW;
  int base = blockIdx.x * CHUNK;
  if (base >= M) return;
  int end = min(base + CHUNK, M);
  const float* ob = sel5(lvl,o0,o1,o2,o3,o4) + (size_t)n*(size_t)M;
  const float* dl = sel5(lvl,d0,d1,d2,d3,d4);
  unsigned T = thi[grp];
  __shared__ int lgt[1024];              // per-group gt total < 1000 -> block gt <= 999
  __shared__ int leq[TIE_CAP];
  __shared__ unsigned cgt_s, ceq_s, bgt_s, beq_s;
  if (threadIdx.x == 0){ cgt_s = 0u; ceq_s = 0u; }
  __syncthreads();
  for (int i = base + threadIdx.x; i < end; i += 256){
    unsigned s = f2s(ob[i]);
    unsigned sh = s >> 20;
    if (sh > T){
      unsigned k = atomicAdd(&cgt_s, 1u);
      if (k < 1024u) lgt[k] = i;
    } else if (sh == T){
      unsigned k = atomicAdd(&ceq_s, 1u);
      if (k < (unsigned)TIE_CAP) leq[k] = i;
    }
  }
  __syncthreads();
  if (threadIdx.x == 0){
    bgt_s = atomicAdd(&cnt_gt[grp], min(cgt_s, 1024u));
    beq_s = atomicAdd(&cnt_eq[grp], min(ceq_s, (unsigned)TIE_CAP));
  }
  __syncthreads();
  unsigned cg = min(cgt_s, 1024u), ce = min(ceq_s, (unsigned)TIE_CAP);
  unsigned bgt = bgt_s, beq = beq_s;
  unsigned long long* kout = keys + (size_t)n*K_SEL + (size_t)lvl*PRE;
  for (unsigned k = threadIdx.x; k < cg; k += 256){
    int i = lgt[k];
    unsigned s = f2s(ob[i]);
    int a = i / HW; int rem = i - a*HW; int t = rem*3 + a;
    kout[bgt + k] = make_key(s, lvl, t, n, dl, anchors);
  }
  for (unsigned k = threadIdx.x; k < ce; k += 256){
    unsigned e = beq + k;
    if (e < (unsigned)TIE_CAP){
      int i = leq[k];
      unsigned s = f2s(ob[i]);
      int a = i / HW; int rem = i - a*HW; int t = rem*3 + a;
      cand[(size_t)grp*TIE_CAP + e] = ((unsigned long long)(~s) << 19) | (unsigned long long)(unsigned)t;
    }
  }
}

template<int SZ>
__device__ void bitonic(unsigned long long* sk){
  for (int k = 2; k <= SZ; k <<= 1){
    for (int j = k >> 1; j > 0; j >>= 1){
      for (int i = threadIdx.x; i < SZ; i += blockDim.x){
        int ix = i ^ j;
        if (ix > i){
          unsigned long long va = sk[i], vb = sk[ix];
          if ((va > vb) == ((i & k) == 0)){ sk[i] = vb; sk[ix] = va; }
        }
      }
      __syncthreads();
    }
  }
}

// runtime-sized bitonic (SZ uniform across block, power of 2)
__device__ void bitonic_rt(unsigned long long* sk, int SZ){
  for (int k = 2; k <= SZ; k <<= 1){
    for (int j = k >> 1; j > 0; j >>= 1){
      for (int i = threadIdx.x; i < SZ; i += blockDim.x){
        int ix = i ^ j;
        if (ix > i){
          unsigned long long va = sk[i], vb = sk[ix];
          if ((va > vb) == ((i & k) == 0)){ sk[i] = vb; sk[ix] = va; }
        }
      }
      __syncthreads();
    }
  }
}

// ---------------- K4: exact boundary selection within the threshold bin ----------------
__global__ __launch_bounds__(256) void k_tiesel(const float* d0,const float* d1,const float* d2,const float* d3,const float* d4,
                                                const float* anchors,
                                                const unsigned* cnt_gt, const unsigned* cnt_eq,
                                                const unsigned long long* cand, unsigned long long* keys){
  int grp = blockIdx.x; int n = grp/5, lvl = grp - n*5;
  __shared__ unsigned long long sk[TIE_CAP];
  int ne = min((int)cnt_eq[grp], TIE_CAP);
  int SZ = 64; while (SZ < ne) SZ <<= 1;    // runtime pow2 >= ne (uniform)
  for (int i = threadIdx.x; i < SZ; i += 256)
    sk[i] = (i < ne) ? cand[(size_t)grp*TIE_CAP + i] : ~0ULL;
  __syncthreads();
  bitonic_rt(sk, SZ);                // ascending: (score desc, idx asc)
  int cg = (int)cnt_gt[grp];
  int need = PRE - cg;
  const float* dl = sel5(lvl,d0,d1,d2,d3,d4);
  unsigned long long* kout = keys + (size_t)n*K_SEL + (size_t)lvl*PRE + cg;
  for (int j = threadIdx.x; j < need; j += 256){
    if (j < ne){
      unsigned long long ck = sk[j];
      unsigned t = (unsigned)(ck & 0x7FFFFu);
      unsigned s = ~((unsigned)(ck >> 19));
      kout[j] = make_key(s, lvl, (int)t, n, dl, anchors);
    } else {
      kout[j] = ((unsigned long long)(~S_NEGINF) << 22); // pathological overflow: harmless invalid
    }
  }
}

// ---------------- K5a: sort each (image,level) run; decode level-space arrays ----------------
__global__ __launch_bounds__(256) void k_sortlvl(unsigned long long* keys,
                                                 const float* d0,const float* d1,const float* d2,const float* d3,const float* d4,
                                                 const float* anchors,
                                                 float4* lbox, float4* lobox, float* loarea, float* lskey){
  int grp = blockIdx.x; int n = grp/5, lvl = grp - n*5;
  __shared__ unsigned long long sk[1024];
  unsigned long long* kp = keys + (size_t)n*K_SEL + (size_t)lvl*PRE;
  for (int i = threadIdx.x; i < 1024; i += 256)
    sk[i] = (i < PRE) ? kp[i] : ~0ULL;
  __syncthreads();
  bitonic<1024>(sk);
  const float* dl = sel5(lvl,d0,d1,d2,d3,d4);
  for (int i = threadIdx.x; i < PRE; i += 256){
    unsigned long long key = sk[i];
    kp[i] = key;                          // sorted run back to global (k_rank reads it)
    int t = (int)(key & 0x7FFFFu);
    unsigned se = ~((unsigned)(key >> 22));
    BoxV b = decode_box(lvl, t, n, dl, anchors);
    size_t o = (size_t)grp*PRE + i;
    lbox[o] = make_float4(b.x1,b.y1,b.x2,b.y2);
    lskey[o] = s2f(se);                   // -inf if invalid
    float off = (float)lvl * 1345.0f;     // (IMG+1) batched-NMS offset
    float ox1 = __fadd_rn(b.x1, off), oy1 = __fadd_rn(b.y1, off);
    float ox2 = __fadd_rn(b.x2, off), oy2 = __fadd_rn(b.y2, off);
    lobox[o] = make_float4(ox1,oy1,ox2,oy2);
    loarea[o] = __fmul_rn(__fsub_rn(ox2,ox1), __fsub_rn(oy2,oy1));
  }
}

// ---------------- K5b: global rank of each level element (keys globally unique) ----------------
// rankinfo[rank] = p | (lvl<<10) | (valid<<13)
__global__ __launch_bounds__(256) void k_rank(const unsigned long long* keys, unsigned* rankinfo){
  int grp = blockIdx.x; int n = grp/5, lvl = grp - n*5;
  __shared__ unsigned long long sl[K_SEL];
  for (int i = threadIdx.x; i < K_SEL; i += 256) sl[i] = keys[(size_t)n*K_SEL + i];
  __syncthreads();
  for (int j = threadIdx.x; j < PRE; j += 256){
    unsigned long long k = sl[lvl*PRE + j];
    int rank = j;
    #pragma unroll
    for (int m = 0; m < 5; ++m){
      if (m == lvl) continue;
      const unsigned long long* s = sl + m*PRE;
      int lo = 0, hi = PRE;
      while (lo < hi){ int mid = (lo+hi) >> 1; if (s[mid] < k) lo = mid+1; else hi = mid; }
      rank += lo;
    }
    unsigned se = ~((unsigned)(k >> 22));
    unsigned info = (unsigned)j | ((unsigned)lvl << 10) | ((se != S_NEGINF) ? (1u<<13) : 0u);
    rankinfo[(size_t)n*K_SEL + rank] = info;   // exact permutation of [0,5000)
  }
}

// ---------------- K6a: suppression bit-matrix, ballot + column layout, 4 waves/block ----------------
__global__ __launch_bounds__(256) void k_ioumat_lvl(const float4* lobox, const float* loarea, unsigned* lmat){
  int grp = blockIdx.y;                  // n*5 + L
  int wblk = blockIdx.x;                 // j-block: j = wblk*64 + lane
  int tid = threadIdx.x;
  int lane = tid & 63, q = tid >> 6;
  __shared__ float sx1[PRE], sy1[PRE], sx2[PRE], sy2[PRE], sar[PRE];
  for (int i = tid; i < PRE; i += 256){
    float4 bb = lobox[(size_t)grp*PRE + i];
    sx1[i]=bb.x; sy1[i]=bb.y; sx2[i]=bb.z; sy2[i]=bb.w;
    sar[i]=loarea[(size_t)grp*PRE + i];
  }
  __syncthreads();
  int j = wblk*64 + lane;
  float jx1=0.f,jy1=0.f,jx2=0.f,jy2=0.f,ja=0.f;
  if (j < PRE){
    float4 bb = lobox[(size_t)grp*PRE + j];
    jx1=bb.x; jy1=bb.y; jx2=bb.z; jy2=bb.w; ja=loarea[(size_t)grp*PRE + j];
  }
  unsigned* mg = lmat + (size_t)grp*GRPW + (size_t)wblk*2*PRE;
  int pmax = min(PRE, wblk*64 + 63);     // rows p >= pmax: no j>p in this block
  int q0 = q*250, q1 = q0 + 250;
  int pm = min(q1, pmax);

#define IOU_HIT(P, OUT) { \
    float bx1=sx1[P], by1=sy1[P], bx2=sx2[P], by2=sy2[P], ba=sar[P]; \
    float ltx = fmaxf(bx1, jx1), lty = fmaxf(by1, jy1); \
    float rbx = fminf(bx2, jx2), rby = fminf(by2, jy2); \
    float ww = fmaxf(__fsub_rn(rbx,ltx), 0.0f); \
    float hh = fmaxf(__fsub_rn(rby,lty), 0.0f); \
    float inter = __fmul_rn(ww,hh); \
    float uni = __fsub_rn(__fadd_rn(ba, ja), inter); \
    OUT = (__fdiv_rn(inter,uni) > 0.7f) && (j > (P)) && (j < PRE); }

  int p = q0;
  for (; p + 4 <= pm; p += 4){
    bool h0,h1,h2,h3;
    IOU_HIT(p,   h0);
    IOU_HIT(p+1, h1);
    IOU_HIT(p+2, h2);
    IOU_HIT(p+3, h3);
    unsigned long long b0 = __ballot(h0), b1 = __ballot(h1);
    unsigned long long b2 = __ballot(h2), b3 = __ballot(h3);
    if ((lane & 31) == 0){
      int d = lane >> 5;
      mg[(p  )*2 + d] = (lane==0) ? (unsigned)b0 : (unsigned)(b0>>32);
      mg[(p+1)*2 + d] = (lane==0) ? (unsigned)b1 : (unsigned)(b1>>32);
      mg[(p+2)*2 + d] = (lane==0) ? (unsigned)b2 : (unsigned)(b2>>32);
      mg[(p+3)*2 + d] = (lane==0) ? (unsigned)b3 : (unsigned)(b3>>32);
    }
  }
  for (; p < pm; ++p){
    bool h; IOU_HIT(p, h);
    unsigned long long bal = __ballot(h);
    if ((lane & 31) == 0)
      mg[p*2 + (lane>>5)] = (lane==0) ? (unsigned)bal : (unsigned)(bal>>32);
  }
#undef IOU_HIT
  int zs = (pm > q0 ? pm : q0);
  for (int w = zs*2 + lane; w < q1*2; w += 64) mg[w] = 0u;   // contiguous zero-fill
}

// ---------------- K6b: tile-parallel greedy scan, latency-batched TPROC ----------------
__global__ __launch_bounds__(64) void k_scan_nms5(const unsigned* rankinfo, const unsigned* lmat,
                                                  const float4* lbox, const float* lskey, float* out){
  __shared__ unsigned lrows[64][36];     // row-major tile; stride 36 words
  __shared__ unsigned lsup[160];         // 5 levels x 32 words suppression state
  int n = blockIdx.x; int lane = threadIdx.x;
  int n5 = n*5;
  const unsigned* rin = rankinfo + (size_t)n*K_SEL;
  float* outn = out + (size_t)n*PRE*5;
  for (int i = lane; i < 160; i += 64) lsup[i] = 0u;
  int kept_total = 0;
  uint2 Pa,Pb,Pc,Pd,Pe,Pf,Pg,Ph,Pi,Pj,Pk,Pl,Pm,Pn,Po,Pp;  // 16x8B staging
  float4 boxP; float scP = 0.f;
  unsigned infoC, infoN;
  int rgrp = lane >> 4;                  // 0..3: row subgroup
  unsigned wboff = (unsigned)(lane & 15) * (2u*PRE);  // my wblk's column segment
  int wb2 = (lane & 15) << 1;            // word index within row

#define SLOAD(INFO) { \
    unsigned L_ = ((INFO)>>10)&7u; unsigned p_ = (INFO) & 1023u; \
    unsigned rowu_ = ((unsigned)n5 + L_)*GRPW + p_*2u; \
    unsigned rb_; \
    rb_ = __shfl(rowu_,  0 + rgrp); Pa = *(const uint2*)(lmat + rb_ + wboff); \
    rb_ = __shfl(rowu_,  4 + rgrp); Pb = *(const uint2*)(lmat + rb_ + wboff); \
    rb_ = __shfl(rowu_,  8 + rgrp); Pc = *(const uint2*)(lmat + rb_ + wboff); \
    rb_ = __shfl(rowu_, 12 + rgrp); Pd = *(const uint2*)(lmat + rb_ + wboff); \
    rb_ = __shfl(rowu_, 16 + rgrp); Pe = *(const uint2*)(lmat + rb_ + wboff); \
    rb_ = __shfl(rowu_, 20 + rgrp); Pf = *(const uint2*)(lmat + rb_ + wboff); \
    rb_ = __shfl(rowu_, 24 + rgrp); Pg = *(const uint2*)(lmat + rb_ + wboff); \
    rb_ = __shfl(rowu_, 28 + rgrp); Ph = *(const uint2*)(lmat + rb_ + wboff); \
    rb_ = __shfl(rowu_, 32 + rgrp); Pi = *(const uint2*)(lmat + rb_ + wboff); \
    rb_ = __shfl(rowu_, 36 + rgrp); Pj = *(const uint2*)(lmat + rb_ + wboff); \
    rb_ = __shfl(rowu_, 40 + rgrp); Pk = *(const uint2*)(lmat + rb_ + wboff); \
    rb_ = __shfl(rowu_, 44 + rgrp); Pl = *(const uint2*)(lmat + rb_ + wboff); \
    rb_ = __shfl(rowu_, 48 + rgrp); Pm = *(const uint2*)(lmat + rb_ + wboff); \
    rb_ = __shfl(rowu_, 52 + rgrp); Pn = *(const uint2*)(lmat + rb_ + wboff); \
    rb_ = __shfl(rowu_, 56 + rgrp); Po = *(const uint2*)(lmat + rb_ + wboff); \
    rb_ = __shfl(rowu_, 60 + rgrp); Pp = *(const uint2*)(lmat + rb_ + wboff); \
    size_t bi_ = (size_t)((unsigned)n5 + L_)*PRE + p_; \
    boxP = lbox[bi_]; scP = lskey[bi_]; }

#define SWRITE() { \
    *(uint2*)&lrows[ 0 + rgrp][wb2] = Pa; *(uint2*)&lrows[ 4 + rgrp][wb2] = Pb; \
    *(uint2*)&lrows[ 8 + rgrp][wb2] = Pc; *(uint2*)&lrows[12 + rgrp][wb2] = Pd; \
    *(uint2*)&lrows[16 + rgrp][wb2] = Pe; *(uint2*)&lrows[20 + rgrp][wb2] = Pf; \
    *(uint2*)&lrows[24 + rgrp][wb2] = Pg; *(uint2*)&lrows[28 + rgrp][wb2] = Ph; \
    *(uint2*)&lrows[32 + rgrp][wb2] = Pi; *(uint2*)&lrows[36 + rgrp][wb2] = Pj; \
    *(uint2*)&lrows[40 + rgrp][wb2] = Pk; *(uint2*)&lrows[44 + rgrp][wb2] = Pl; \
    *(uint2*)&lrows[48 + rgrp][wb2] = Pm; *(uint2*)&lrows[52 + rgrp][wb2] = Pn; \
    *(uint2*)&lrows[56 + rgrp][wb2] = Po; *(uint2*)&lrows[60 + rgrp][wb2] = Pp; }

#define GRP16(B, ACC, SH) { \
    unsigned q0_=lrows[(B)+ 0][idxw_], q1_=lrows[(B)+ 1][idxw_], \
             q2_=lrows[(B)+ 2][idxw_], q3_=lrows[(B)+ 3][idxw_], \
             q4_=lrows[(B)+ 4][idxw_], q5_=lrows[(B)+ 5][idxw_], \
             q6_=lrows[(B)+ 6][idxw_], q7_=lrows[(B)+ 7][idxw_], \
             q8_=lrows[(B)+ 8][idxw_], q9_=lrows[(B)+ 9][idxw_], \
             qa_=lrows[(B)+10][idxw_], qb_=lrows[(B)+11][idxw_], \
             qc_=lrows[(B)+12][idxw_], qd_=lrows[(B)+13][idxw_], \
             qe_=lrows[(B)+14][idxw_], qf_=lrows[(B)+15][idxw_]; \
    ACC |= (((q0_>>pb_)&1u)<<((SH)+ 0)) | (((q1_>>pb_)&1u)<<((SH)+ 1)) \
         | (((q2_>>pb_)&1u)<<((SH)+ 2)) | (((q3_>>pb_)&1u)<<((SH)+ 3)) \
         | (((q4_>>pb_)&1u)<<((SH)+ 4)) | (((q5_>>pb_)&1u)<<((SH)+ 5)) \
         | (((q6_>>pb_)&1u)<<((SH)+ 6)) | (((q7_>>pb_)&1u)<<((SH)+ 7)) \
         | (((q8_>>pb_)&1u)<<((SH)+ 8)) | (((q9_>>pb_)&1u)<<((SH)+ 9)) \
         | (((qa_>>pb_)&1u)<<((SH)+10)) | (((qb_>>pb_)&1u)<<((SH)+11)) \
         | (((qc_>>pb_)&1u)<<((SH)+12)) | (((qd_>>pb_)&1u)<<((SH)+13)) \
         | (((qe_>>pb_)&1u)<<((SH)+14)) | (((qf_>>pb_)&1u)<<((SH)+15)); }

#define TPROC(INFO, BOX, SC, baseexpr) { \
    int base_ = (baseexpr); \
    unsigned L_ = ((INFO)>>10)&7u; unsigned p_ = (INFO) & 1023u; \
    int idxw_ = (int)(p_ >> 5); unsigned pb_ = p_ & 31u; \
    unsigned long long lb0_=__ballot(L_==0u), lb1_=__ballot(L_==1u), \
                       lb2_=__ballot(L_==2u), lb3_=__ballot(L_==3u), lb4_=__ballot(L_==4u); \
    unsigned long long myLvl_ = (L_==0u)?lb0_:(L_==1u)?lb1_:(L_==2u)?lb2_:(L_==3u)?lb3_:lb4_; \
    unsigned sw_ = lsup[L_*32u + (unsigned)idxw_]; \
    bool ok_ = ((((INFO)>>13)&1u)!=0u) && (base_ + lane < K_SEL) && (((sw_>>pb_)&1u)==0u); \
    unsigned long long cand_ = __ballot(ok_); \
    unsigned alo_ = 0u, ahi_ = 0u; \
    GRP16( 0, alo_,  0); GRP16(16, alo_, 16); \
    GRP16(32, ahi_,  0); GRP16(48, ahi_, 16); \
    unsigned long long cm_ = ((((unsigned long long)ahi_)<<32)|(unsigned long long)alo_) & myLvl_; \
    unsigned long long keptM_ = 0ull; \
    while (cand_){ \
      bool safe_ = (((cand_>>lane)&1ull)!=0ull) && ((cm_ & cand_)==0ull); \
      unsigned long long nk_ = __ballot(safe_); \
      keptM_ |= nk_; \
      bool dead_ = (((cand_>>lane)&1ull)!=0ull) && ((cm_ & nk_)!=0ull); \
      cand_ &= ~(nk_ | __ballot(dead_)); \
    } \
    if (((keptM_>>lane)&1ull)!=0ull){ \
      unsigned sb_ = L_*32u; \
      _Pragma("unroll") \
      for (int k_ = 0; k_ < 32; ++k_){ \
        unsigned w_ = (unsigned)((k_+lane)&31); \
        atomicOr(&lsup[sb_+w_], lrows[lane][w_]); \
      } \
    } \
    int pos_ = kept_total + (int)__popcll(keptM_ & ((1ull<<lane)-1ull)); \
    if ((((keptM_>>lane)&1ull)!=0ull) && pos_ < PRE){ \
      float* orow_ = outn + (size_t)pos_*5; \
      orow_[0]=(BOX).x; orow_[1]=(BOX).y; orow_[2]=(BOX).z; orow_[3]=(BOX).w; orow_[4]=(SC); \
    } \
    kept_total += (int)__popcll(keptM_); \
    asm volatile("s_waitcnt lgkmcnt(0)" ::: "memory"); \
  }

  infoC = rin[lane];
  SLOAD(infoC);                          // tile 0 rows -> regs, box -> boxP
  SWRITE();                              // tile 0 rows -> LDS
  float4 boxC = boxP; float scC = scP;
  infoN = rin[64 + lane];

  for (int t = 0; t < TILES; ++t){
    if (t+1 < TILES) SLOAD(infoN);       // issue next tile's loads (rows + box)
    asm volatile("s_waitcnt lgkmcnt(0)" ::: "memory");   // lrows writes visible
    TPROC(infoC, boxC, scC, t*64);
    if (kept_total >= PRE) break;
    if (t+1 < TILES){
      SWRITE();                          // waits next tile's loads (covered by TPROC)
      boxC = boxP; scC = scP;
      infoC = infoN;
      if (t+2 < TILES){
        int nx = (t+2)*64 + lane; if (nx > K_SEL-1) nx = K_SEL-1;
        infoN = rin[nx];
      }
    }
  }
#undef SLOAD
#undef SWRITE
#undef GRP16
#undef TPROC
}

// ---------------- fallback path (ws too small): round-3 kernels ----------------
__global__ __launch_bounds__(256) void k_sortimg(const unsigned long long* keys,
                                                 const float* d0,const float* d1,const float* d2,const float* d3,const float* d4,
                                                 const float* anchors,
                                                 float4* sbox, float* sskey, int* slvl){
  int n = blockIdx.x;
  __shared__ unsigned long long sk[8192];
  for (int i = threadIdx.x; i < 8192; i += 256)
    sk[i] = (i < K_SEL) ? keys[(size_t)n*K_SEL + i] : ~0ULL;
  __syncthreads();
  bitonic<8192>(sk);
  for (int r = threadIdx.x; r < K_SEL; r += 256){
    unsigned long long key = sk[r];
    int t = (int)(key & 0x7FFFFu);
    int lvl = (int)((key >> 19) & 7u);
    unsigned se = ~((unsigned)(key >> 22));
    const float* dl = sel5(lvl,d0,d1,d2,d3,d4);
    BoxV b = decode_box(lvl, t, n, dl, anchors);
    sbox[(size_t)n*K_SEL + r] = make_float4(b.x1,b.y1,b.x2,b.y2);
    sskey[(size_t)n*K_SEL + r] = s2f(se);
    slvl[(size_t)n*K_SEL + r] = lvl;
  }
}

__global__ __launch_bounds__(256) void k_nms(const float4* sbox, const float* sskey, const int* slvl, float* out){
  int n = blockIdx.x, tid = threadIdx.x;
  __shared__ float kx1[PRE], ky1[PRE], kx2[PRE], ky2[PRE], kar[PRE];
  __shared__ int klv[PRE];
  __shared__ int nv_s, flag_s;
  for (int i = tid; i < PRE*5; i += 256) out[(size_t)n*PRE*5 + i] = 0.0f;
  if (tid == 0){ nv_s = 0; flag_s = 0; }
  __syncthreads();
  int c = 0;
  for (int i = tid; i < K_SEL; i += 256)
    if (sskey[(size_t)n*K_SEL + i] != -INFINITY) ++c;
  atomicAdd(&nv_s, c);
  __syncthreads();
  int nvalid = nv_s;
  int kept = 0;
  for (int i = 0; i < nvalid; ++i){
    float4 b = sbox[(size_t)n*K_SEL + i];
    int lv = slvl[(size_t)n*K_SEL + i];
    float off = (float)lv * 1345.0f;
    float ox1 = __fadd_rn(b.x, off), oy1 = __fadd_rn(b.y, off);
    float ox2 = __fadd_rn(b.z, off), oy2 = __fadd_rn(b.w, off);
    float area = __fmul_rn(__fsub_rn(ox2,ox1), __fsub_rn(oy2,oy1));
    bool hit = false;
    for (int j = tid; j < kept; j += 256){
      if (klv[j] == lv){
        float ltx = fmaxf(kx1[j], ox1), lty = fmaxf(ky1[j], oy1);
        float rbx = fminf(kx2[j], ox2), rby = fminf(ky2[j], oy2);
        float w = fmaxf(__fsub_rn(rbx,ltx), 0.0f);
        float h = fmaxf(__fsub_rn(rby,lty), 0.0f);
        float inter = __fmul_rn(w,h);
        float uni = __fsub_rn(__fadd_rn(kar[j], area), inter);
        if (__fdiv_rn(inter,uni) > 0.7f) hit = true;
      }
    }
    if (hit) flag_s = 1;
    __syncthreads();
    int sup = flag_s;
    __syncthreads();
    if (!sup){
      if (tid == 0){
        kx1[kept]=ox1; ky1[kept]=oy1; kx2[kept]=ox2; ky2[kept]=oy2; kar[kept]=area; klv[kept]=lv;
        float* orow = out + (size_t)n*PRE*5 + (size_t)kept*5;
        orow[0]=b.x; orow[1]=b.y; orow[2]=b.z; orow[3]=b.w;
        orow[4]=sskey[(size_t)n*K_SEL + i];
      }
      ++kept;
    }
    if (tid == 0) flag_s = 0;
    __syncthreads();
    if (kept == PRE) break;
  }
}

extern "C" void kernel_launch(void* const* d_in, const int* in_sizes, int n_in,
                              void* d_out, int out_size, void* d_ws, size_t ws_size,
                              hipStream_t stream) {
  bool interleaved = (in_sizes[1] == 4*in_sizes[0]);
  const float* obj[5]; const float* dlt[5];
  for (int i = 0; i < 5; ++i){
    if (interleaved){ obj[i] = (const float*)d_in[2*i]; dlt[i] = (const float*)d_in[2*i+1]; }
    else            { obj[i] = (const float*)d_in[i];   dlt[i] = (const float*)d_in[5+i]; }
  }
  const float* anchors = (const float*)d_in[10];

  char* ws = (char*)d_ws;
  unsigned* hist            = (unsigned*)(ws);                     // 655360
  unsigned* cnt_gt          = (unsigned*)(ws + 655360);            // 160
  unsigned* cnt_eq          = (unsigned*)(ws + 655520);            // 160
  unsigned* thi             = (unsigned*)(ws + 655680);            // 160 -> counters end 655840
  unsigned long long* cand  = (unsigned long long*)(ws + 655840);  // 1310720 -> 1966560
  unsigned long long* keys  = (unsigned long long*)(ws + 1966560); // 320000 -> 2286560
  float4* lbox              = (float4*)(ws + 2286560);             // 640000 -> 2926560
  float4* lobox             = (float4*)(ws + 2926560);             // 640000 -> 3566560
  float* loarea             = (float*)(ws + 3566560);              // 160000 -> 3726560
  float* lskey              = (float*)(ws + 3726560);              // 160000 -> 3886560
  unsigned* rankinfo        = (unsigned*)(ws + 3886560);           // 160000 -> 4046560
  unsigned* lmat            = (unsigned*)(ws + 4046560);           // 5120000 -> 9166560
  float4* sbox              = (float4*)(ws + 9166560);             // fallback: 640000 -> 9806560
  float* sskey              = (float*)(ws + 9806560);              // 160000 -> 9966560
  int* slvl                 = (int*)(ws + 9966560);                // 160000 -> 10126560
  const size_t NEED = 10126560;

  hipMemsetAsync(ws, 0, 655840, stream);   // hist + counters

  dim3 gChunk(42, 40);                   // 42 chunks x 8192 covers level-0's 338688
  k_hist<<<gChunk, 256, 0, stream>>>(obj[0],obj[1],obj[2],obj[3],obj[4], hist);
  k_scan<<<40, 256, 0, stream>>>(hist, thi);
  k_compact<<<gChunk, 256, 0, stream>>>(obj[0],obj[1],obj[2],obj[3],obj[4],
                                        dlt[0],dlt[1],dlt[2],dlt[3],dlt[4],
                                        anchors, thi, cnt_gt, cnt_eq, cand, keys);
  k_tiesel<<<40, 256, 0, stream>>>(dlt[0],dlt[1],dlt[2],dlt[3],dlt[4], anchors,
                                   cnt_gt, cnt_eq, cand, keys);
  if (ws_size >= NEED){
    k_sortlvl<<<40, 256, 0, stream>>>(keys, dlt[0],dlt[1],dlt[2],dlt[3],dlt[4], anchors,
                                      lbox, lobox, loarea, lskey);
    k_rank<<<40, 256, 0, stream>>>(keys, rankinfo);
    k_ioumat_lvl<<<dim3(16, 40), 256, 0, stream>>>(lobox, loarea, lmat);
    hipMemsetAsync(d_out, 0, (size_t)out_size*sizeof(float), stream);
    k_scan_nms5<<<8, 64, 0, stream>>>(rankinfo, lmat, lbox, lskey, (float*)d_out);
  } else {
    k_sortimg<<<8, 256, 0, stream>>>(keys, dlt[0],dlt[1],dlt[2],dlt[3],dlt[4], anchors,
                                     sbox, sskey, slvl);
    k_nms<<<8, 256, 0, stream>>>(sbox, sskey, slvl, (float*)d_out);
  }
}